// Round 7
// baseline (1615.147 us; speedup 1.0000x reference)
//
#include <hip/hip_runtime.h>

// ---------------------------------------------------------------------------
// types & helpers
// ---------------------------------------------------------------------------
using bf16x8 = __attribute__((ext_vector_type(8))) short;
using f32x4  = __attribute__((ext_vector_type(4))) float;
using u16x4  = __attribute__((ext_vector_type(4))) unsigned short;
using u16x8  = __attribute__((ext_vector_type(8))) unsigned short;
using as3_void  = __attribute__((address_space(3))) void;
using as1_cvoid = const __attribute__((address_space(1))) void;

__device__ __forceinline__ unsigned short f2bf(float x) {
    union { float f; unsigned u; } v; v.f = x;
    unsigned r = v.u + 0x7FFFu + ((v.u >> 16) & 1u);   // RNE
    return (unsigned short)(r >> 16);
}
__device__ __forceinline__ float bf2f(unsigned short h) {
    union { unsigned u; float f; } v; v.u = ((unsigned)h) << 16;
    return v.f;
}

// ---------------------------------------------------------------------------
// GEMM tile body: BM x 128, BK=64, 4 waves (2x2). LDS XOR-swizzle applied on
// the GLOBAL source (global_load_lds needs linear dest); ds_read re-applies it.
// ---------------------------------------------------------------------------
#define GEMM_BODY(BM, A, Bt, K, KBEG, KEND)                                          \
    constexpr int WROWS = (BM) / 2;                                                  \
    constexpr int MI = WROWS / 16;                                                   \
    __shared__ __align__(16) unsigned short As[(BM) * 64];                           \
    __shared__ __align__(16) unsigned short Bs[128 * 64];                            \
    const int tid  = threadIdx.x;                                                    \
    const int lane = tid & 63, wave = tid >> 6;                                      \
    const int wr = wave >> 1, wc = wave & 1;                                         \
    const int rl = lane & 15, kg = lane >> 4;                                        \
    f32x4 acc[MI][4] = {};                                                           \
    for (int kt = (KBEG); kt < (KEND); kt += 64) {                                   \
        _Pragma("unroll")                                                            \
        for (int it = 0; it < (BM) / 32; ++it) {                                     \
            int slot = it * 256 + tid;                                               \
            int r = slot >> 3, c = slot & 7;                                         \
            int cg = c ^ (r & 7);                                                    \
            const unsigned short* ga = (A) + (size_t)(m0 + r) * (K) + (kt + cg * 8); \
            __builtin_amdgcn_global_load_lds((as1_cvoid*)ga, (as3_void*)(As + slot * 8), 16, 0, 0); \
        }                                                                            \
        _Pragma("unroll")                                                            \
        for (int it = 0; it < 4; ++it) {                                             \
            int slot = it * 256 + tid;                                               \
            int r = slot >> 3, c = slot & 7;                                         \
            int cg = c ^ (r & 7);                                                    \
            const unsigned short* gb = (Bt) + (size_t)(n0 + r) * (K) + (kt + cg * 8);\
            __builtin_amdgcn_global_load_lds((as1_cvoid*)gb, (as3_void*)(Bs + slot * 8), 16, 0, 0); \
        }                                                                            \
        __syncthreads();                                                             \
        _Pragma("unroll")                                                            \
        for (int kh = 0; kh < 2; ++kh) {                                             \
            bf16x8 a_[MI], b_[4];                                                    \
            _Pragma("unroll")                                                        \
            for (int i = 0; i < MI; ++i) {                                           \
                int ra = wr * WROWS + i * 16 + rl;                                   \
                int ca = (kh * 4 + kg) ^ (ra & 7);                                   \
                a_[i] = *reinterpret_cast<const bf16x8*>(&As[ra * 64 + ca * 8]);     \
            }                                                                        \
            _Pragma("unroll")                                                        \
            for (int j = 0; j < 4; ++j) {                                            \
                int rb = wc * 64 + j * 16 + rl;                                      \
                int cb = (kh * 4 + kg) ^ (rb & 7);                                   \
                b_[j] = *reinterpret_cast<const bf16x8*>(&Bs[rb * 64 + cb * 8]);     \
            }                                                                        \
            _Pragma("unroll")                                                        \
            for (int i = 0; i < MI; ++i)                                             \
                _Pragma("unroll")                                                    \
                for (int j = 0; j < 4; ++j)                                          \
                    acc[i][j] = __builtin_amdgcn_mfma_f32_16x16x32_bf16(a_[i], b_[j], acc[i][j], 0, 0, 0); \
        }                                                                            \
        __syncthreads();                                                             \
    }

// ---------------------------------------------------------------------------
// dual-job GEMM (BM=64): blockIdx.x < nb0 -> job0, else job1. bf16 out,
// optional fused BN column stats (sum/sumsq atomicAdd into statp[1024]).
// ---------------------------------------------------------------------------
__global__ __launch_bounds__(256) void gemm_dual(
    int nb0,
    const unsigned short* __restrict__ A0, const unsigned short* __restrict__ B0,
    int K0, unsigned short* __restrict__ C0, float* __restrict__ st0,
    const unsigned short* __restrict__ A1, const unsigned short* __restrict__ B1,
    int K1, unsigned short* __restrict__ C1, float* __restrict__ st1)
{
    int bx = blockIdx.x;
    const unsigned short *A, *Bt; unsigned short* Cb; float* statp;
    int K;
    if (bx < nb0) { A = A0; Bt = B0; K = K0; Cb = C0; statp = st0; }
    else { bx -= nb0; A = A1; Bt = B1; K = K1; Cb = C1; statp = st1; }
    const int m0 = bx * 64, n0 = blockIdx.y * 128;

    GEMM_BODY(64, A, Bt, K, 0, K)

#pragma unroll
    for (int i = 0; i < MI; ++i)
#pragma unroll
        for (int j = 0; j < 4; ++j)
#pragma unroll
            for (int e = 0; e < 4; ++e) {
                int rr = m0 + wr * WROWS + i * 16 + kg * 4 + e;
                int cc = n0 + wc * 64 + j * 16 + rl;
                Cb[(size_t)rr * 512 + cc] = f2bf(acc[i][j][e]);
            }
    if (statp) {
#pragma unroll
        for (int j = 0; j < 4; ++j) {
            float s = 0.f, q = 0.f;
#pragma unroll
            for (int i = 0; i < MI; ++i)
#pragma unroll
                for (int e = 0; e < 4; ++e) {
                    float x = acc[i][j][e];
                    s += x; q += x * x;
                }
            s += __shfl_xor(s, 16); s += __shfl_xor(s, 32);
            q += __shfl_xor(q, 16); q += __shfl_xor(q, 32);
            if (kg == 0) {
                int cc = n0 + wc * 64 + j * 16 + rl;
                atomicAdd(&statp[cc], s);
                atomicAdd(&statp[512 + cc], q);
            }
        }
    }
}

// ---------------------------------------------------------------------------
// fusion GEMM (BM=128), split-K over grid.z: f32 partials
// ---------------------------------------------------------------------------
__global__ __launch_bounds__(256) void gemm_splitk(
    const unsigned short* __restrict__ A, const unsigned short* __restrict__ Bt,
    int M, int N, int K, float* __restrict__ Cp)
{
    const int m0 = blockIdx.x * 128, n0 = blockIdx.y * 128;
    const int kn = K / gridDim.z, kbeg = blockIdx.z * kn;

    GEMM_BODY(128, A, Bt, K, kbeg, kbeg + kn)

    float* dst = Cp + (size_t)blockIdx.z * M * N;
#pragma unroll
    for (int i = 0; i < MI; ++i)
#pragma unroll
        for (int j = 0; j < 4; ++j)
#pragma unroll
            for (int e = 0; e < 4; ++e) {
                int rr = m0 + wr * WROWS + i * 16 + kg * 4 + e;
                int cc = n0 + wc * 64 + j * 16 + rl;
                dst[(size_t)rr * N + cc] = acc[i][j][e];
            }
}

// ---------------------------------------------------------------------------
// CSR build
// ---------------------------------------------------------------------------
__global__ void csr_count2(const int* __restrict__ e1, int E1, int* __restrict__ c1,
                           const int* __restrict__ e2, int E2, int* __restrict__ c2) {
    int i = blockIdx.x * 256 + threadIdx.x;
    if (i < E1) atomicAdd(&c1[e1[i]], 1);
    else if (i < E1 + E2) atomicAdd(&c2[e2[i - E1]], 1);
}

__global__ void csr_scan2(const int* __restrict__ cnt1, int n1, int* __restrict__ offs1, int* __restrict__ cur1,
                          const int* __restrict__ cnt2, int n2, int* __restrict__ offs2, int* __restrict__ cur2) {
    const int* cnt = blockIdx.x ? cnt2 : cnt1;
    int n           = blockIdx.x ? n2 : n1;
    int* offs       = blockIdx.x ? offs2 : offs1;
    int* cursor     = blockIdx.x ? cur2 : cur1;
    __shared__ int part[1024];
    int t = threadIdx.x;
    int per = n >> 10;
    int base = t * per;
    int loc[8];
    int s = 0;
    for (int j = 0; j < per; ++j) { loc[j] = s; s += cnt[base + j]; }
    part[t] = s;
    __syncthreads();
    for (int o = 1; o < 1024; o <<= 1) {
        int v = (t >= o) ? part[t - o] : 0;
        __syncthreads();
        part[t] += v;
        __syncthreads();
    }
    int excl = (t == 0) ? 0 : part[t - 1];
    for (int j = 0; j < per; ++j) {
        int v = excl + loc[j];
        offs[base + j] = v;
        cursor[base + j] = v;
    }
    if (t == 1023) offs[n] = part[1023];
}

__global__ void csr_fill2(const int* __restrict__ e1, int E1, int* __restrict__ cur1, int* __restrict__ s1,
                          const int* __restrict__ e2, int E2, int* __restrict__ cur2, int* __restrict__ s2) {
    int i = blockIdx.x * 256 + threadIdx.x;
    if (i < E1) {
        int d = e1[i], s = e1[E1 + i];
        s1[atomicAdd(&cur1[d], 1)] = s;
    } else if (i < E1 + E2) {
        int e = i - E1;
        int d = e2[e], s = e2[E2 + e];
        s2[atomicAdd(&cur2[d], 1)] = s;
    }
}

// ---------------------------------------------------------------------------
// gather for BOTH branches + hierarchical BN stats: one block per row;
// row sum/sumsq atomically added into 64-way partial slots ssp[64][1024]
// (slot = blockIdx & 63). Partials pre-zeroed once at launch.
// ---------------------------------------------------------------------------
__global__ __launch_bounds__(128) void gather2_bf16(
    const u16x4* __restrict__ Y1, const int* __restrict__ offs1, const int* __restrict__ srcs1,
    u16x4* __restrict__ T1, int n1, float* __restrict__ ssp1,
    const u16x4* __restrict__ Y2, const int* __restrict__ offs2, const int* __restrict__ srcs2,
    u16x4* __restrict__ T2, float* __restrict__ ssp2,
    const float* __restrict__ epsv, int l)
{
    int i = blockIdx.x;
    const u16x4* Y; u16x4* T; const int *offs, *srcs; float* ssp;
    if (i < n1) { Y = Y1; T = T1; offs = offs1; srcs = srcs1; ssp = ssp1; }
    else        { i -= n1; Y = Y2; T = T2; offs = offs2; srcs = srcs2; ssp = ssp2; }
    int c = threadIdx.x;
    float e = 1.0f + epsv[l];
    int lo = offs[i], hi = offs[i + 1];
    u16x4 hv = Y[(size_t)i * 128 + c];
    f32x4 a0, a1 = {}, a2 = {}, a3 = {};
#pragma unroll
    for (int j = 0; j < 4; ++j) a0[j] = e * bf2f(hv[j]);
    int k = lo;
    for (; k + 4 <= hi; k += 4) {
        int s0 = srcs[k], s1 = srcs[k + 1], s2 = srcs[k + 2], s3 = srcs[k + 3];
        u16x4 v0 = Y[(size_t)s0 * 128 + c];
        u16x4 v1 = Y[(size_t)s1 * 128 + c];
        u16x4 v2 = Y[(size_t)s2 * 128 + c];
        u16x4 v3 = Y[(size_t)s3 * 128 + c];
#pragma unroll
        for (int j = 0; j < 4; ++j) {
            a0[j] += bf2f(v0[j]); a1[j] += bf2f(v1[j]);
            a2[j] += bf2f(v2[j]); a3[j] += bf2f(v3[j]);
        }
    }
    for (; k < hi; ++k) {
        u16x4 v = Y[(size_t)srcs[k] * 128 + c];
#pragma unroll
        for (int j = 0; j < 4; ++j) a0[j] += bf2f(v[j]);
    }
    f32x4 acc = (a0 + a1) + (a2 + a3);
    u16x4 o;
    f32x4 f;
#pragma unroll
    for (int j = 0; j < 4; ++j) { o[j] = f2bf(acc[j]); f[j] = bf2f(o[j]); }
    T[(size_t)i * 128 + c] = o;
    float* sp = ssp + (size_t)(blockIdx.x & 63) * 1024;
#pragma unroll
    for (int j = 0; j < 4; ++j) {
        atomicAdd(&sp[c * 4 + j], f[j]);
        atomicAdd(&sp[512 + c * 4 + j], f[j] * f[j]);
    }
}

// ---------------------------------------------------------------------------
// dual mid BN apply (reduces 64-way partial stats inline) -> U buffers
// ---------------------------------------------------------------------------
__global__ __launch_bounds__(128) void bn_apply_mid(
    int nb0,
    const u16x4* __restrict__ X0, int M0, const float* __restrict__ ssp0,
    const float* __restrict__ g0, const float* __restrict__ b0, unsigned short* __restrict__ o0,
    const u16x4* __restrict__ X1, int M1, const float* __restrict__ ssp1,
    const float* __restrict__ g1, const float* __restrict__ b1, unsigned short* __restrict__ o1)
{
    int bx = blockIdx.x;
    const u16x4* X; const float *ssp, *g, *b; unsigned short* out; int M;
    if (bx < nb0) { X = X0; M = M0; ssp = ssp0; g = g0; b = b0; out = o0; }
    else { bx -= nb0; X = X1; M = M1; ssp = ssp1; g = g1; b = b1; out = o1; }
    int c = threadIdx.x;
    f32x4 s = {}, q = {};
#pragma unroll 8
    for (int p = 0; p < 64; ++p) {
        s += *reinterpret_cast<const f32x4*>(ssp + (size_t)p * 1024 + c * 4);
        q += *reinterpret_cast<const f32x4*>(ssp + (size_t)p * 1024 + 512 + c * 4);
    }
    float inv = 1.0f / (float)M;
    float al[4], be[4];
#pragma unroll
    for (int i = 0; i < 4; ++i) {
        float mean = s[i] * inv;
        float var  = q[i] * inv - mean * mean;
        al[i] = g[c * 4 + i] * rsqrtf(var + 1e-5f);
        be[i] = b[c * 4 + i] - mean * al[i];
    }
    int r0 = bx * 8;
    for (int r = 0; r < 8; ++r) {
        u16x4 v = X[(size_t)(r0 + r) * 128 + c];
        u16x4 h;
#pragma unroll
        for (int i = 0; i < 4; ++i)
            h[i] = f2bf(fmaxf(al[i] * bf2f(v[i]) + be[i], 0.f));
        *reinterpret_cast<u16x4*>(out + (size_t)(r0 + r) * 512 + c * 4) = h;
    }
}

// ---------------------------------------------------------------------------
// branch-2 final BN apply -> H2b [4096][512] AND H2t [512][4096] (fused
// transpose: 8 rows/block => one 16B store per column)
// ---------------------------------------------------------------------------
__global__ __launch_bounds__(128) void bn_apply_b2t(
    const u16x4* __restrict__ X, int M, const float* __restrict__ ss,
    const float* __restrict__ g, const float* __restrict__ b,
    unsigned short* __restrict__ out, unsigned short* __restrict__ outT)
{
    int c = threadIdx.x;
    float inv = 1.0f / (float)M;
    float al[4], be[4];
#pragma unroll
    for (int i = 0; i < 4; ++i) {
        float mean = ss[c * 4 + i] * inv;
        float var  = ss[512 + c * 4 + i] * inv - mean * mean;
        al[i] = g[c * 4 + i] * rsqrtf(var + 1e-5f);
        be[i] = b[c * 4 + i] - mean * al[i];
    }
    int r0 = blockIdx.x * 8;
    u16x8 t8[4];
#pragma unroll
    for (int r = 0; r < 8; ++r) {
        u16x4 v = X[(size_t)(r0 + r) * 128 + c];
        u16x4 h;
#pragma unroll
        for (int i = 0; i < 4; ++i) {
            h[i] = f2bf(fmaxf(al[i] * bf2f(v[i]) + be[i], 0.f));
            t8[i][r] = h[i];
        }
        *reinterpret_cast<u16x4*>(out + (size_t)(r0 + r) * 512 + c * 4) = h;
    }
#pragma unroll
    for (int i = 0; i < 4; ++i)
        *reinterpret_cast<u16x8*>(outT + (size_t)(c * 4 + i) * 4096 + r0) = t8[i];
}

// ---------------------------------------------------------------------------
// finale: job0 (blocks < nb0) = branch-1 final BN apply * a0 -> H1b[:, :512]
//         + JK pool; job1 = sum KS split-K partials * a1 -> H1b[:, 512:]
//         + JK pool. gid sorted; pool pre-zeroed.
// ---------------------------------------------------------------------------
__global__ __launch_bounds__(128) void finale(
    int nb0, const int* __restrict__ gid, const float* __restrict__ aDev,
    float* __restrict__ pool, unsigned short* __restrict__ H1,
    const u16x4* __restrict__ X, const float* __restrict__ ss,
    const float* __restrict__ g, const float* __restrict__ b,
    const f32x4* __restrict__ P, int ks)
{
    int bx = blockIdx.x;
    int c = threadIdx.x;
    int job = bx >= nb0;
    if (job) bx -= nb0;
    int r0 = bx * 8;
    int ooff = job ? 512 : 0;
    float al[4], be[4];
    float sc;
    if (!job) {
        sc = aDev[0];
        float inv = 1.0f / 8192.0f;
#pragma unroll
        for (int i = 0; i < 4; ++i) {
            float mean = ss[c * 4 + i] * inv;
            float var  = ss[512 + c * 4 + i] * inv - mean * mean;
            al[i] = g[c * 4 + i] * rsqrtf(var + 1e-5f);
            be[i] = b[c * 4 + i] - mean * al[i];
        }
    } else {
        sc = aDev[1];
    }
    const int total4 = 8192 * 128;
    int curg = gid[r0];
    f32x4 pacc = {};
    for (int r = 0; r < 8; ++r) {
        int row = r0 + r;
        u16x4 h;
        f32x4 f;
        if (!job) {
            u16x4 v = X[(size_t)row * 128 + c];
#pragma unroll
            for (int i = 0; i < 4; ++i) {
                h[i] = f2bf(fmaxf(al[i] * bf2f(v[i]) + be[i], 0.f) * sc);
                f[i] = bf2f(h[i]);
            }
        } else {
            f32x4 s = P[(size_t)row * 128 + c];
            for (int z = 1; z < ks; ++z) s += P[(size_t)z * total4 + (size_t)row * 128 + c];
#pragma unroll
            for (int i = 0; i < 4; ++i) { h[i] = f2bf(s[i] * sc); f[i] = bf2f(h[i]); }
        }
        *reinterpret_cast<u16x4*>(H1 + (size_t)row * 1024 + ooff + c * 4) = h;
        int gg = gid[row];
        if (gg != curg) {
#pragma unroll
            for (int j = 0; j < 4; ++j)
                atomicAdd(&pool[(size_t)curg * 1024 + ooff + c * 4 + j], pacc[j]);
            pacc = {}; curg = gg;
        }
        pacc += f;
    }
#pragma unroll
    for (int j = 0; j < 4; ++j)
        atomicAdd(&pool[(size_t)curg * 1024 + ooff + c * 4 + j], pacc[j]);
}

// contiguous f32 -> bf16 convert, two tensors in one dispatch
__global__ void cvt2_bf16(const f32x4* __restrict__ X0, u16x4* __restrict__ O0, int n0,
                          const f32x4* __restrict__ X1, u16x4* __restrict__ O1, int n1) {
    for (int i = blockIdx.x * blockDim.x + threadIdx.x; i < n0 + n1; i += gridDim.x * blockDim.x) {
        const f32x4* X; u16x4* O; int k;
        if (i < n0) { X = X0; O = O0; k = i; }
        else { X = X1; O = O1; k = i - n0; }
        f32x4 v = X[k];
        u16x4 h;
#pragma unroll
        for (int j = 0; j < 4; ++j) h[j] = f2bf(v[j]);
        O[k] = h;
    }
}

// ---------------------------------------------------------------------------
// motif transpose: S f32 [4096][8192] -> D bf16 [8192][4096], 64x64 tiles
// ---------------------------------------------------------------------------
__global__ __launch_bounds__(256) void motif_transpose(const float* __restrict__ S,
                                                       unsigned short* __restrict__ D) {
    __shared__ unsigned short tile[64][66];
    int m0 = blockIdx.x * 64;
    int k0 = blockIdx.y * 64;
    int t = threadIdx.x;
    int r = t >> 4, cq = t & 15;
#pragma unroll
    for (int p = 0; p < 4; ++p) {
        int row = r + p * 16;
        f32x4 v = *reinterpret_cast<const f32x4*>(S + (size_t)(k0 + row) * 8192 + m0 + cq * 4);
        u16x4 h;
#pragma unroll
        for (int j = 0; j < 4; ++j) h[j] = f2bf(v[j]);
        *reinterpret_cast<u16x4*>(&tile[row][cq * 4]) = h;
    }
    __syncthreads();
#pragma unroll
    for (int p = 0; p < 4; ++p) {
        int col = r + p * 16;
        u16x4 h;
#pragma unroll
        for (int i = 0; i < 4; ++i) h[i] = tile[cq * 4 + i][col];
        *reinterpret_cast<u16x4*>(D + (size_t)(m0 + col) * 4096 + k0 + cq * 4) = h;
    }
}

// ---------------------------------------------------------------------------
// small transposes (weights), batched
// ---------------------------------------------------------------------------
__global__ void transpose_cvt_b(const float* __restrict__ S, unsigned short* __restrict__ D,
                                int rows, int cols, size_t sstride, size_t dstride) {
    S += blockIdx.z * sstride; D += blockIdx.z * dstride;
    __shared__ unsigned short tile[32][33];
    int x0 = blockIdx.x * 32, y0 = blockIdx.y * 32;
    for (int j = threadIdx.y; j < 32; j += blockDim.y)
        tile[j][threadIdx.x] = f2bf(S[(size_t)(y0 + j) * cols + x0 + threadIdx.x]);
    __syncthreads();
    for (int j = threadIdx.y; j < 32; j += blockDim.y)
        D[(size_t)(x0 + j) * rows + y0 + threadIdx.x] = tile[threadIdx.x][j];
}

// 11 square 512x512 weights in one launch
__global__ void transpose_cvt11(const float* __restrict__ A, unsigned short* __restrict__ Ad,
                                const float* __restrict__ B, unsigned short* __restrict__ Bd,
                                const float* __restrict__ Cs, unsigned short* __restrict__ Cd) {
    int z = blockIdx.z;
    const float* S; unsigned short* D;
    if (z < 4)      { S = A  + (size_t)z * 262144;       D = Ad + (size_t)z * 262144; }
    else if (z < 7) { S = B  + (size_t)(z - 4) * 262144; D = Bd + (size_t)(z - 4) * 262144; }
    else            { S = Cs + (size_t)(z - 7) * 262144; D = Cd + (size_t)(z - 7) * 262144; }
    __shared__ unsigned short tile[32][33];
    int x0 = blockIdx.x * 32, y0 = blockIdx.y * 32;
    for (int j = threadIdx.y; j < 32; j += blockDim.y)
        tile[j][threadIdx.x] = f2bf(S[(size_t)(y0 + j) * 512 + x0 + threadIdx.x]);
    __syncthreads();
    for (int j = threadIdx.y; j < 32; j += blockDim.y)
        D[(size_t)(x0 + j) * 512 + y0 + threadIdx.x] = tile[threadIdx.x][j];
}

// ---------------------------------------------------------------------------
// x1 graph pooling (f32, 128 cols), row-chunked, atomics into pre-zeroed P0
// ---------------------------------------------------------------------------
__device__ __forceinline__ int lbound(const int* __restrict__ a, int n, int v) {
    int lo = 0, hi = n;
    while (lo < hi) { int m = (lo + hi) >> 1; if (a[m] < v) lo = m + 1; else hi = m; }
    return lo;
}

__global__ void pool_f32_at(const float* __restrict__ Hm, const int* __restrict__ gid,
                            int n, float* __restrict__ P) {
    int g = blockIdx.x;
    int lo = lbound(gid, n, g), hi = lbound(gid, n, g + 1);
    int cnt = hi - lo;
    int per = (cnt + 3) >> 2;
    int s = lo + blockIdx.y * per;
    int e = min(s + per, hi);
    if (s >= e) return;
    int c = threadIdx.x;
    f32x4 acc = {};
    for (int i = s; i < e; ++i)
        acc += *reinterpret_cast<const f32x4*>(Hm + (size_t)i * 128 + c * 4);
#pragma unroll
    for (int j = 0; j < 4; ++j)
        atomicAdd(&P[(size_t)g * 128 + c * 4 + j], acc[j]);
}

__global__ void softmax2(const float* __restrict__ atts, float* __restrict__ a) {
    if (threadIdx.x == 0) {
        float m = fmaxf(atts[0], atts[1]);
        float e0 = expf(atts[0] - m), e1 = expf(atts[1] - m);
        float inv = 1.0f / (e0 + e1);
        a[0] = e0 * inv; a[1] = e1 * inv;
    }
}

// score[g,o] = P0[g]@W0 + b0 + sum_l PL[l][g]@W[l] + b[l]
__global__ __launch_bounds__(256) void score_kernel(
    const float* __restrict__ P0, const float* __restrict__ PL,
    const float* __restrict__ W0, const float* __restrict__ b0,
    const float* __restrict__ W, const float* __restrict__ bb,
    float* __restrict__ out)
{
    int g = blockIdx.x;
    int t = threadIdx.x;
    float part[10];
#pragma unroll
    for (int o = 0; o < 10; ++o) part[o] = 0.f;
    if (t < 128) {
        float p = P0[g * 128 + t];
#pragma unroll
        for (int o = 0; o < 10; ++o) part[o] += p * W0[t * 10 + o];
    }
    for (int l = 0; l < 4; ++l) {
        const float* p = PL + (size_t)l * 65536 + (size_t)g * 1024;
        const float* w = W + (size_t)l * 10240;
        for (int k = t; k < 1024; k += 256) {
            float pv = p[k];
#pragma unroll
            for (int o = 0; o < 10; ++o) part[o] += pv * w[k * 10 + o];
        }
    }
    __shared__ float red[4][10];
#pragma unroll
    for (int o = 0; o < 10; ++o) {
        float v = part[o];
        for (int off = 32; off; off >>= 1) v += __shfl_down(v, off, 64);
        if ((t & 63) == 0) red[t >> 6][o] = v;
    }
    __syncthreads();
    if (t < 10) {
        float s = b0[t] + red[0][t] + red[1][t] + red[2][t] + red[3][t];
#pragma unroll
        for (int l = 0; l < 4; ++l) s += bb[l * 10 + t];
        out[g * 10 + t] = s;
    }
}

// ---------------------------------------------------------------------------
// host orchestration
// ---------------------------------------------------------------------------
extern "C" void kernel_launch(void* const* d_in, const int* in_sizes, int n_in,
                              void* d_out, int out_size, void* d_ws, size_t ws_size,
                              hipStream_t stream) {
    const float* x1    = (const float*)d_in[0];
    const float* x2    = (const float*)d_in[1];
    const float* motif = (const float*)d_in[2];
    const int*   edge1 = (const int*)d_in[3];
    const int*   edge2 = (const int*)d_in[4];
    const int*   gid   = (const int*)d_in[5];
    const float* epsv  = (const float*)d_in[6];
    const float* atts  = (const float*)d_in[7];
    const float* m1W10 = (const float*)d_in[8];
    const float* m1W1r = (const float*)d_in[9];
    const float* m1bng = (const float*)d_in[11];
    const float* m1bnb = (const float*)d_in[12];
    const float* m1W2  = (const float*)d_in[13];
    const float* bn1g  = (const float*)d_in[15];
    const float* bn1b  = (const float*)d_in[16];
    const float* m2W10 = (const float*)d_in[17];
    const float* m2W1r = (const float*)d_in[18];
    const float* m2bng = (const float*)d_in[20];
    const float* m2bnb = (const float*)d_in[21];
    const float* m2W2  = (const float*)d_in[22];
    const float* bn2g  = (const float*)d_in[24];
    const float* bn2b  = (const float*)d_in[25];
    const float* pW0   = (const float*)d_in[26];
    const float* pb0   = (const float*)d_in[27];
    const float* pW    = (const float*)d_in[28];
    const float* pb    = (const float*)d_in[29];
    float* out = (float*)d_out;

    constexpr int N1 = 8192, N2 = 4096, E1 = 262144, E2 = 65536;

    char* base = (char*)d_ws;
    size_t off = 0;
    auto alloc = [&](size_t bytes) -> void* {
        void* p = base + off;
        off = (off + bytes + 255) & ~(size_t)255;
        return p;
    };

    // bf16 buffers
    unsigned short* motifT  = (unsigned short*)alloc((size_t)8192 * 4096 * 2);
    unsigned short* w1t1_0  = (unsigned short*)alloc((size_t)512 * 128 * 2);
    unsigned short* w1t1_r  = (unsigned short*)alloc((size_t)3 * 512 * 1024 * 2);
    unsigned short* w2t1    = (unsigned short*)alloc((size_t)4 * 512 * 512 * 2);
    unsigned short* w1t2_0  = (unsigned short*)alloc((size_t)512 * 64 * 2);
    unsigned short* w1t2_r  = (unsigned short*)alloc((size_t)3 * 512 * 512 * 2);
    unsigned short* w2t2    = (unsigned short*)alloc((size_t)4 * 512 * 512 * 2);
    unsigned short* x1b     = (unsigned short*)alloc((size_t)N1 * 128 * 2);
    unsigned short* x2b     = (unsigned short*)alloc((size_t)N2 * 64 * 2);
    unsigned short* H1b     = (unsigned short*)alloc((size_t)N1 * 1024 * 2);
    unsigned short* H2b     = (unsigned short*)alloc((size_t)N2 * 512 * 2);
    unsigned short* H2t     = (unsigned short*)alloc((size_t)512 * 4096 * 2);
    unsigned short* U1b     = (unsigned short*)alloc((size_t)N1 * 512 * 2);
    unsigned short* U2b     = (unsigned short*)alloc((size_t)N2 * 512 * 2);
    unsigned short* Y1b     = (unsigned short*)alloc((size_t)N1 * 512 * 2);
    unsigned short* T1b     = (unsigned short*)alloc((size_t)N1 * 512 * 2);
    unsigned short* Y2b     = (unsigned short*)alloc((size_t)N2 * 512 * 2);
    unsigned short* T2b     = (unsigned short*)alloc((size_t)N2 * 512 * 2);
    // zero-together region: cnt1 | cnt2 | ss | PL | P0 | ssp1 | ssp2
    int*   cnt1 = (int*)alloc((size_t)N1 * 4);
    int*   cnt2 = (int*)alloc((size_t)N2 * 4);
    float* ss   = (float*)alloc((size_t)16 * 1024 * 4);
    float* PL   = (float*)alloc((size_t)4 * 64 * 1024 * 4);
    float* P0   = (float*)alloc((size_t)64 * 128 * 4);
    float* ssp1 = (float*)alloc((size_t)4 * 64 * 1024 * 4);
    float* ssp2 = (float*)alloc((size_t)4 * 64 * 1024 * 4);
    const size_t zero_bytes = (size_t)N1 * 4 + N2 * 4 + 16 * 1024 * 4 + 4 * 64 * 1024 * 4
                            + 64 * 128 * 4 + 2 * (size_t)4 * 64 * 1024 * 4;
    int*   offs1 = (int*)alloc((size_t)(N1 + 1) * 4);
    int*   offs2 = (int*)alloc((size_t)(N2 + 1) * 4);
    int*   cur1  = (int*)alloc((size_t)N1 * 4);
    int*   cur2  = (int*)alloc((size_t)N2 * 4);
    int*   srcs1 = (int*)alloc((size_t)E1 * 4);
    int*   srcs2 = (int*)alloc((size_t)E2 * 4);
    float* aDev  = (float*)alloc(256);

    if (off > ws_size) return;

    // split-K partials for the fusion GEMM
    const size_t part_elems = (size_t)N1 * 512;
    size_t rem = ws_size - off;
    int KS = (rem >= 4 * part_elems * 4) ? 4 : (rem >= 2 * part_elems * 4) ? 2 : 1;
    float* Cpart = (float*)(base + off);

    // ---- setup ----
    hipMemsetAsync(cnt1, 0, zero_bytes, stream);
    softmax2<<<1, 64, 0, stream>>>(atts, aDev);
    cvt2_bf16<<<512, 256, 0, stream>>>((const f32x4*)x1, (u16x4*)x1b, N1 * 128 / 4,
                                       (const f32x4*)x2, (u16x4*)x2b, N2 * 64 / 4);
    motif_transpose<<<dim3(128, 64), 256, 0, stream>>>(motif, motifT);
    transpose_cvt_b<<<dim3(16, 4, 1), dim3(32, 8), 0, stream>>>(m1W10, w1t1_0, 128, 512, 0, 0);
    transpose_cvt_b<<<dim3(16, 32, 3), dim3(32, 8), 0, stream>>>(m1W1r, w1t1_r, 1024, 512,
                                                                 (size_t)1024 * 512, (size_t)512 * 1024);
    transpose_cvt_b<<<dim3(16, 2, 1), dim3(32, 8), 0, stream>>>(m2W10, w1t2_0, 64, 512, 0, 0);
    transpose_cvt11<<<dim3(16, 16, 11), dim3(32, 8), 0, stream>>>(m1W2, w2t1, m2W1r, w1t2_r, m2W2, w2t2);
    csr_count2<<<(E1 + E2) / 256, 256, 0, stream>>>(edge1, E1, cnt1, edge2, E2, cnt2);
    csr_scan2<<<2, 1024, 0, stream>>>(cnt1, N1, offs1, cur1, cnt2, N2, offs2, cur2);
    csr_fill2<<<(E1 + E2) / 256, 256, 0, stream>>>(edge1, E1, cur1, srcs1, edge2, E2, cur2, srcs2);
    pool_f32_at<<<dim3(64, 4), 32, 0, stream>>>(x1, gid, N1, P0);

    // ---- layers ----
    for (int l = 0; l < 4; ++l) {
        float* ssl   = ss + (size_t)l * 4096;     // slots: [1]=b1 W2 stats, [3]=b2 W2 stats
        float* PLl   = PL + (size_t)l * 65536;
        float* ssp1l = ssp1 + (size_t)l * 65536;  // 64 x 1024 partials (gather b1)
        float* ssp2l = ssp2 + (size_t)l * 65536;  // 64 x 1024 partials (gather b2)
        // W1 GEMMs, both branches, one dispatch
        gemm_dual<<<dim3(192, 4), 256, 0, stream>>>(
            128,
            l ? H1b : x1b, l ? w1t1_r + (size_t)(l - 1) * 512 * 1024 : w1t1_0,
            l ? 1024 : 128, Y1b, nullptr,
            l ? H2b : x2b, l ? w1t2_r + (size_t)(l - 1) * 512 * 512 : w1t2_0,
            l ? 512 : 64, Y2b, nullptr);
        // gathers + hierarchical BN stats, one dispatch
        gather2_bf16<<<N1 + N2, 128, 0, stream>>>(
            (const u16x4*)Y1b, offs1, srcs1, (u16x4*)T1b, N1, ssp1l,
            (const u16x4*)Y2b, offs2, srcs2, (u16x4*)T2b, ssp2l, epsv, l);
        // mid BN apply (partial-stat reduce inline), both branches
        bn_apply_mid<<<1536, 128, 0, stream>>>(
            1024,
            (const u16x4*)T1b, N1, ssp1l, m1bng + l * 512, m1bnb + l * 512, U1b,
            (const u16x4*)T2b, N2, ssp2l, m2bng + l * 512, m2bnb + l * 512, U2b);
        // W2 GEMMs with fused column stats, both branches
        gemm_dual<<<dim3(192, 4), 256, 0, stream>>>(
            128,
            U1b, w2t1 + (size_t)l * 512 * 512, 512, Y1b, ssl + 1 * 1024,
            U2b, w2t2 + (size_t)l * 512 * 512, 512, Y2b, ssl + 3 * 1024);
        // branch-2 final apply -> H2b + fused-transposed H2t
        bn_apply_b2t<<<512, 128, 0, stream>>>(
            (const u16x4*)Y2b, N2, ssl + 3 * 1024, bn2g + l * 512, bn2b + l * 512, H2b, H2t);
        // fusion: h2A = motif2A^T @ h2 (split-K partials)
        gemm_splitk<<<dim3(64, 4, KS), 256, 0, stream>>>(motifT, H2t, N1, 512, 4096, Cpart);
        // finale: branch-1 apply*a0 + pool (job0) || sumk*a1 + pool (job1)
        finale<<<2048, 128, 0, stream>>>(
            1024, gid, aDev, PLl, H1b,
            (const u16x4*)Y1b, ssl + 1 * 1024, bn1g + l * 512, bn1b + l * 512,
            (const f32x4*)Cpart, KS);
    }

    score_kernel<<<64, 256, 0, stream>>>(P0, PL, pW0, pb0, pW, pb, out);
}

// Round 8
// 992.021 us; speedup vs baseline: 1.6281x; 1.6281x over previous
//
#include <hip/hip_runtime.h>

// ---------------------------------------------------------------------------
// types & helpers
// ---------------------------------------------------------------------------
using bf16x8 = __attribute__((ext_vector_type(8))) short;
using f32x4  = __attribute__((ext_vector_type(4))) float;
using u16x4  = __attribute__((ext_vector_type(4))) unsigned short;
using u16x8  = __attribute__((ext_vector_type(8))) unsigned short;
using as3_void  = __attribute__((address_space(3))) void;
using as1_cvoid = const __attribute__((address_space(1))) void;

__device__ __forceinline__ unsigned short f2bf(float x) {
    union { float f; unsigned u; } v; v.f = x;
    unsigned r = v.u + 0x7FFFu + ((v.u >> 16) & 1u);   // RNE
    return (unsigned short)(r >> 16);
}
__device__ __forceinline__ float bf2f(unsigned short h) {
    union { unsigned u; float f; } v; v.u = ((unsigned)h) << 16;
    return v.f;
}

// ---------------------------------------------------------------------------
// GEMM tile body: BM x 128, BK=64, 4 waves (2x2). LDS XOR-swizzle applied on
// the GLOBAL source (global_load_lds needs linear dest); ds_read re-applies it.
// ---------------------------------------------------------------------------
#define GEMM_BODY(BM, A, Bt, K, KBEG, KEND)                                          \
    constexpr int WROWS = (BM) / 2;                                                  \
    constexpr int MI = WROWS / 16;                                                   \
    __shared__ __align__(16) unsigned short As[(BM) * 64];                           \
    __shared__ __align__(16) unsigned short Bs[128 * 64];                            \
    const int tid  = threadIdx.x;                                                    \
    const int lane = tid & 63, wave = tid >> 6;                                      \
    const int wr = wave >> 1, wc = wave & 1;                                         \
    const int rl = lane & 15, kg = lane >> 4;                                        \
    f32x4 acc[MI][4] = {};                                                           \
    for (int kt = (KBEG); kt < (KEND); kt += 64) {                                   \
        _Pragma("unroll")                                                            \
        for (int it = 0; it < (BM) / 32; ++it) {                                     \
            int slot = it * 256 + tid;                                               \
            int r = slot >> 3, c = slot & 7;                                         \
            int cg = c ^ (r & 7);                                                    \
            const unsigned short* ga = (A) + (size_t)(m0 + r) * (K) + (kt + cg * 8); \
            __builtin_amdgcn_global_load_lds((as1_cvoid*)ga, (as3_void*)(As + slot * 8), 16, 0, 0); \
        }                                                                            \
        _Pragma("unroll")                                                            \
        for (int it = 0; it < 4; ++it) {                                             \
            int slot = it * 256 + tid;                                               \
            int r = slot >> 3, c = slot & 7;                                         \
            int cg = c ^ (r & 7);                                                    \
            const unsigned short* gb = (Bt) + (size_t)(n0 + r) * (K) + (kt + cg * 8);\
            __builtin_amdgcn_global_load_lds((as1_cvoid*)gb, (as3_void*)(Bs + slot * 8), 16, 0, 0); \
        }                                                                            \
        __syncthreads();                                                             \
        _Pragma("unroll")                                                            \
        for (int kh = 0; kh < 2; ++kh) {                                             \
            bf16x8 a_[MI], b_[4];                                                    \
            _Pragma("unroll")                                                        \
            for (int i = 0; i < MI; ++i) {                                           \
                int ra = wr * WROWS + i * 16 + rl;                                   \
                int ca = (kh * 4 + kg) ^ (ra & 7);                                   \
                a_[i] = *reinterpret_cast<const bf16x8*>(&As[ra * 64 + ca * 8]);     \
            }                                                                        \
            _Pragma("unroll")                                                        \
            for (int j = 0; j < 4; ++j) {                                            \
                int rb = wc * 64 + j * 16 + rl;                                      \
                int cb = (kh * 4 + kg) ^ (rb & 7);                                   \
                b_[j] = *reinterpret_cast<const bf16x8*>(&Bs[rb * 64 + cb * 8]);     \
            }                                                                        \
            _Pragma("unroll")                                                        \
            for (int i = 0; i < MI; ++i)                                             \
                _Pragma("unroll")                                                    \
                for (int j = 0; j < 4; ++j)                                          \
                    acc[i][j] = __builtin_amdgcn_mfma_f32_16x16x32_bf16(a_[i], b_[j], acc[i][j], 0, 0, 0); \
        }                                                                            \
        __syncthreads();                                                             \
    }

// ---------------------------------------------------------------------------
// dual-job GEMM (BM=64): blockIdx.x < nb0 -> job0, else job1. bf16 out,
// optional fused BN column stats (sum/sumsq atomicAdd into statp[1024]).
// ---------------------------------------------------------------------------
__global__ __launch_bounds__(256) void gemm_dual(
    int nb0,
    const unsigned short* __restrict__ A0, const unsigned short* __restrict__ B0,
    int K0, unsigned short* __restrict__ C0, float* __restrict__ st0,
    const unsigned short* __restrict__ A1, const unsigned short* __restrict__ B1,
    int K1, unsigned short* __restrict__ C1, float* __restrict__ st1)
{
    int bx = blockIdx.x;
    const unsigned short *A, *Bt; unsigned short* Cb; float* statp;
    int K;
    if (bx < nb0) { A = A0; Bt = B0; K = K0; Cb = C0; statp = st0; }
    else { bx -= nb0; A = A1; Bt = B1; K = K1; Cb = C1; statp = st1; }
    const int m0 = bx * 64, n0 = blockIdx.y * 128;

    GEMM_BODY(64, A, Bt, K, 0, K)

#pragma unroll
    for (int i = 0; i < MI; ++i)
#pragma unroll
        for (int j = 0; j < 4; ++j)
#pragma unroll
            for (int e = 0; e < 4; ++e) {
                int rr = m0 + wr * WROWS + i * 16 + kg * 4 + e;
                int cc = n0 + wc * 64 + j * 16 + rl;
                Cb[(size_t)rr * 512 + cc] = f2bf(acc[i][j][e]);
            }
    if (statp) {
#pragma unroll
        for (int j = 0; j < 4; ++j) {
            float s = 0.f, q = 0.f;
#pragma unroll
            for (int i = 0; i < MI; ++i)
#pragma unroll
                for (int e = 0; e < 4; ++e) {
                    float x = acc[i][j][e];
                    s += x; q += x * x;
                }
            s += __shfl_xor(s, 16); s += __shfl_xor(s, 32);
            q += __shfl_xor(q, 16); q += __shfl_xor(q, 32);
            if (kg == 0) {
                int cc = n0 + wc * 64 + j * 16 + rl;
                atomicAdd(&statp[cc], s);
                atomicAdd(&statp[512 + cc], q);
            }
        }
    }
}

// ---------------------------------------------------------------------------
// fusion GEMM (BM=128), split-K over grid.z: f32 partials
// ---------------------------------------------------------------------------
__global__ __launch_bounds__(256) void gemm_splitk(
    const unsigned short* __restrict__ A, const unsigned short* __restrict__ Bt,
    int M, int N, int K, float* __restrict__ Cp)
{
    const int m0 = blockIdx.x * 128, n0 = blockIdx.y * 128;
    const int kn = K / gridDim.z, kbeg = blockIdx.z * kn;

    GEMM_BODY(128, A, Bt, K, kbeg, kbeg + kn)

    float* dst = Cp + (size_t)blockIdx.z * M * N;
#pragma unroll
    for (int i = 0; i < MI; ++i)
#pragma unroll
        for (int j = 0; j < 4; ++j)
#pragma unroll
            for (int e = 0; e < 4; ++e) {
                int rr = m0 + wr * WROWS + i * 16 + kg * 4 + e;
                int cc = n0 + wc * 64 + j * 16 + rl;
                dst[(size_t)rr * N + cc] = acc[i][j][e];
            }
}

// ---------------------------------------------------------------------------
// CSR build
// ---------------------------------------------------------------------------
__global__ void csr_count2(const int* __restrict__ e1, int E1, int* __restrict__ c1,
                           const int* __restrict__ e2, int E2, int* __restrict__ c2) {
    int i = blockIdx.x * 256 + threadIdx.x;
    if (i < E1) atomicAdd(&c1[e1[i]], 1);
    else if (i < E1 + E2) atomicAdd(&c2[e2[i - E1]], 1);
}

__global__ void csr_scan2(const int* __restrict__ cnt1, int n1, int* __restrict__ offs1, int* __restrict__ cur1,
                          const int* __restrict__ cnt2, int n2, int* __restrict__ offs2, int* __restrict__ cur2) {
    const int* cnt = blockIdx.x ? cnt2 : cnt1;
    int n           = blockIdx.x ? n2 : n1;
    int* offs       = blockIdx.x ? offs2 : offs1;
    int* cursor     = blockIdx.x ? cur2 : cur1;
    __shared__ int part[1024];
    int t = threadIdx.x;
    int per = n >> 10;
    int base = t * per;
    int loc[8];
    int s = 0;
    for (int j = 0; j < per; ++j) { loc[j] = s; s += cnt[base + j]; }
    part[t] = s;
    __syncthreads();
    for (int o = 1; o < 1024; o <<= 1) {
        int v = (t >= o) ? part[t - o] : 0;
        __syncthreads();
        part[t] += v;
        __syncthreads();
    }
    int excl = (t == 0) ? 0 : part[t - 1];
    for (int j = 0; j < per; ++j) {
        int v = excl + loc[j];
        offs[base + j] = v;
        cursor[base + j] = v;
    }
    if (t == 1023) offs[n] = part[1023];
}

__global__ void csr_fill2(const int* __restrict__ e1, int E1, int* __restrict__ cur1, int* __restrict__ s1,
                          const int* __restrict__ e2, int E2, int* __restrict__ cur2, int* __restrict__ s2) {
    int i = blockIdx.x * 256 + threadIdx.x;
    if (i < E1) {
        int d = e1[i], s = e1[E1 + i];
        s1[atomicAdd(&cur1[d], 1)] = s;
    } else if (i < E1 + E2) {
        int e = i - E1;
        int d = e2[e], s = e2[E2 + e];
        s2[atomicAdd(&cur2[d], 1)] = s;
    }
}

// ---------------------------------------------------------------------------
// gather for BOTH branches in one dispatch (512 cols, one block per row).
// NO fused stats: 12.6M global atomics cost 170 us/dispatch (round-7 lesson).
// ---------------------------------------------------------------------------
__global__ __launch_bounds__(128) void gather2_bf16(
    const u16x4* __restrict__ Y1, const int* __restrict__ offs1, const int* __restrict__ srcs1,
    u16x4* __restrict__ T1, int n1,
    const u16x4* __restrict__ Y2, const int* __restrict__ offs2, const int* __restrict__ srcs2,
    u16x4* __restrict__ T2,
    const float* __restrict__ epsv, int l)
{
    int i = blockIdx.x;
    const u16x4* Y; u16x4* T; const int *offs, *srcs;
    if (i < n1) { Y = Y1; T = T1; offs = offs1; srcs = srcs1; }
    else        { i -= n1; Y = Y2; T = T2; offs = offs2; srcs = srcs2; }
    int c = threadIdx.x;
    float e = 1.0f + epsv[l];
    int lo = offs[i], hi = offs[i + 1];
    u16x4 hv = Y[(size_t)i * 128 + c];
    f32x4 a0, a1 = {}, a2 = {}, a3 = {};
#pragma unroll
    for (int j = 0; j < 4; ++j) a0[j] = e * bf2f(hv[j]);
    int k = lo;
    for (; k + 4 <= hi; k += 4) {
        int s0 = srcs[k], s1 = srcs[k + 1], s2 = srcs[k + 2], s3 = srcs[k + 3];
        u16x4 v0 = Y[(size_t)s0 * 128 + c];
        u16x4 v1 = Y[(size_t)s1 * 128 + c];
        u16x4 v2 = Y[(size_t)s2 * 128 + c];
        u16x4 v3 = Y[(size_t)s3 * 128 + c];
#pragma unroll
        for (int j = 0; j < 4; ++j) {
            a0[j] += bf2f(v0[j]); a1[j] += bf2f(v1[j]);
            a2[j] += bf2f(v2[j]); a3[j] += bf2f(v3[j]);
        }
    }
    for (; k < hi; ++k) {
        u16x4 v = Y[(size_t)srcs[k] * 128 + c];
#pragma unroll
        for (int j = 0; j < 4; ++j) a0[j] += bf2f(v[j]);
    }
    f32x4 acc = (a0 + a1) + (a2 + a3);
    u16x4 o;
#pragma unroll
    for (int j = 0; j < 4; ++j) o[j] = f2bf(acc[j]);
    T[(size_t)i * 128 + c] = o;
}

// ---------------------------------------------------------------------------
// dual column sum/sumsq over bf16 [M][512]: job0 = 512 blocks x16 rows,
// job1 = 256 blocks x16 rows. ~786K atomics total - cheap (round-6 evidence).
// ---------------------------------------------------------------------------
__global__ void bn_stats2(int nb0,
                          const u16x4* __restrict__ X0, float* __restrict__ ss0,
                          const u16x4* __restrict__ X1, float* __restrict__ ss1) {
    int bx = blockIdx.x;
    const u16x4* X; float* ss;
    if (bx < nb0) { X = X0; ss = ss0; }
    else { bx -= nb0; X = X1; ss = ss1; }
    int c = threadIdx.x;
    int r0 = bx * 16;
    f32x4 s = {}, q = {};
    for (int r = 0; r < 16; ++r) {
        u16x4 v = X[(size_t)(r0 + r) * 128 + c];
        f32x4 f;
#pragma unroll
        for (int j = 0; j < 4; ++j) f[j] = bf2f(v[j]);
        s += f; q += f * f;
    }
#pragma unroll
    for (int j = 0; j < 4; ++j) {
        atomicAdd(&ss[c * 4 + j], s[j]);
        atomicAdd(&ss[512 + c * 4 + j], q[j]);
    }
}

// ---------------------------------------------------------------------------
// dual mid BN apply -> U buffers
// ---------------------------------------------------------------------------
__global__ __launch_bounds__(128) void bn_apply_mid(
    int nb0,
    const u16x4* __restrict__ X0, int M0, const float* __restrict__ ss0,
    const float* __restrict__ g0, const float* __restrict__ b0, unsigned short* __restrict__ o0,
    const u16x4* __restrict__ X1, int M1, const float* __restrict__ ss1,
    const float* __restrict__ g1, const float* __restrict__ b1, unsigned short* __restrict__ o1)
{
    int bx = blockIdx.x;
    const u16x4* X; const float *ss, *g, *b; unsigned short* out; int M;
    if (bx < nb0) { X = X0; M = M0; ss = ss0; g = g0; b = b0; out = o0; }
    else { bx -= nb0; X = X1; M = M1; ss = ss1; g = g1; b = b1; out = o1; }
    int c = threadIdx.x;
    float inv = 1.0f / (float)M;
    float al[4], be[4];
#pragma unroll
    for (int i = 0; i < 4; ++i) {
        float mean = ss[c * 4 + i] * inv;
        float var  = ss[512 + c * 4 + i] * inv - mean * mean;
        al[i] = g[c * 4 + i] * rsqrtf(var + 1e-5f);
        be[i] = b[c * 4 + i] - mean * al[i];
    }
    int r0 = bx * 8;
    for (int r = 0; r < 8; ++r) {
        u16x4 v = X[(size_t)(r0 + r) * 128 + c];
        u16x4 h;
#pragma unroll
        for (int i = 0; i < 4; ++i)
            h[i] = f2bf(fmaxf(al[i] * bf2f(v[i]) + be[i], 0.f));
        *reinterpret_cast<u16x4*>(out + (size_t)(r0 + r) * 512 + c * 4) = h;
    }
}

// ---------------------------------------------------------------------------
// branch-2 final BN apply -> H2b [4096][512] AND H2t [512][4096] (fused
// transpose: 8 rows/block => one 16B store per column)
// ---------------------------------------------------------------------------
__global__ __launch_bounds__(128) void bn_apply_b2t(
    const u16x4* __restrict__ X, int M, const float* __restrict__ ss,
    const float* __restrict__ g, const float* __restrict__ b,
    unsigned short* __restrict__ out, unsigned short* __restrict__ outT)
{
    int c = threadIdx.x;
    float inv = 1.0f / (float)M;
    float al[4], be[4];
#pragma unroll
    for (int i = 0; i < 4; ++i) {
        float mean = ss[c * 4 + i] * inv;
        float var  = ss[512 + c * 4 + i] * inv - mean * mean;
        al[i] = g[c * 4 + i] * rsqrtf(var + 1e-5f);
        be[i] = b[c * 4 + i] - mean * al[i];
    }
    int r0 = blockIdx.x * 8;
    u16x8 t8[4];
#pragma unroll
    for (int r = 0; r < 8; ++r) {
        u16x4 v = X[(size_t)(r0 + r) * 128 + c];
        u16x4 h;
#pragma unroll
        for (int i = 0; i < 4; ++i) {
            h[i] = f2bf(fmaxf(al[i] * bf2f(v[i]) + be[i], 0.f));
            t8[i][r] = h[i];
        }
        *reinterpret_cast<u16x4*>(out + (size_t)(r0 + r) * 512 + c * 4) = h;
    }
#pragma unroll
    for (int i = 0; i < 4; ++i)
        *reinterpret_cast<u16x8*>(outT + (size_t)(c * 4 + i) * 4096 + r0) = t8[i];
}

// ---------------------------------------------------------------------------
// finale: job0 (blocks < nb0) = branch-1 final BN apply * a0 -> H1b[:, :512]
//         + JK pool; job1 = sum KS split-K partials * a1 -> H1b[:, 512:]
//         + JK pool. gid sorted; pool pre-zeroed.
// ---------------------------------------------------------------------------
__global__ __launch_bounds__(128) void finale(
    int nb0, const int* __restrict__ gid, const float* __restrict__ aDev,
    float* __restrict__ pool, unsigned short* __restrict__ H1,
    const u16x4* __restrict__ X, const float* __restrict__ ss,
    const float* __restrict__ g, const float* __restrict__ b,
    const f32x4* __restrict__ P, int ks)
{
    int bx = blockIdx.x;
    int c = threadIdx.x;
    int job = bx >= nb0;
    if (job) bx -= nb0;
    int r0 = bx * 8;
    int ooff = job ? 512 : 0;
    float al[4], be[4];
    float sc;
    if (!job) {
        sc = aDev[0];
        float inv = 1.0f / 8192.0f;
#pragma unroll
        for (int i = 0; i < 4; ++i) {
            float mean = ss[c * 4 + i] * inv;
            float var  = ss[512 + c * 4 + i] * inv - mean * mean;
            al[i] = g[c * 4 + i] * rsqrtf(var + 1e-5f);
            be[i] = b[c * 4 + i] - mean * al[i];
        }
    } else {
        sc = aDev[1];
    }
    const int total4 = 8192 * 128;
    int curg = gid[r0];
    f32x4 pacc = {};
    for (int r = 0; r < 8; ++r) {
        int row = r0 + r;
        u16x4 h;
        f32x4 f;
        if (!job) {
            u16x4 v = X[(size_t)row * 128 + c];
#pragma unroll
            for (int i = 0; i < 4; ++i) {
                h[i] = f2bf(fmaxf(al[i] * bf2f(v[i]) + be[i], 0.f) * sc);
                f[i] = bf2f(h[i]);
            }
        } else {
            f32x4 s = P[(size_t)row * 128 + c];
            for (int z = 1; z < ks; ++z) s += P[(size_t)z * total4 + (size_t)row * 128 + c];
#pragma unroll
            for (int i = 0; i < 4; ++i) { h[i] = f2bf(s[i] * sc); f[i] = bf2f(h[i]); }
        }
        *reinterpret_cast<u16x4*>(H1 + (size_t)row * 1024 + ooff + c * 4) = h;
        int gg = gid[row];
        if (gg != curg) {
#pragma unroll
            for (int j = 0; j < 4; ++j)
                atomicAdd(&pool[(size_t)curg * 1024 + ooff + c * 4 + j], pacc[j]);
            pacc = {}; curg = gg;
        }
        pacc += f;
    }
#pragma unroll
    for (int j = 0; j < 4; ++j)
        atomicAdd(&pool[(size_t)curg * 1024 + ooff + c * 4 + j], pacc[j]);
}

// contiguous f32 -> bf16 convert, two tensors in one dispatch
__global__ void cvt2_bf16(const f32x4* __restrict__ X0, u16x4* __restrict__ O0, int n0,
                          const f32x4* __restrict__ X1, u16x4* __restrict__ O1, int n1) {
    for (int i = blockIdx.x * blockDim.x + threadIdx.x; i < n0 + n1; i += gridDim.x * blockDim.x) {
        const f32x4* X; u16x4* O; int k;
        if (i < n0) { X = X0; O = O0; k = i; }
        else { X = X1; O = O1; k = i - n0; }
        f32x4 v = X[k];
        u16x4 h;
#pragma unroll
        for (int j = 0; j < 4; ++j) h[j] = f2bf(v[j]);
        O[k] = h;
    }
}

// ---------------------------------------------------------------------------
// motif transpose: S f32 [4096][8192] -> D bf16 [8192][4096], 64x64 tiles
// ---------------------------------------------------------------------------
__global__ __launch_bounds__(256) void motif_transpose(const float* __restrict__ S,
                                                       unsigned short* __restrict__ D) {
    __shared__ unsigned short tile[64][66];
    int m0 = blockIdx.x * 64;
    int k0 = blockIdx.y * 64;
    int t = threadIdx.x;
    int r = t >> 4, cq = t & 15;
#pragma unroll
    for (int p = 0; p < 4; ++p) {
        int row = r + p * 16;
        f32x4 v = *reinterpret_cast<const f32x4*>(S + (size_t)(k0 + row) * 8192 + m0 + cq * 4);
        u16x4 h;
#pragma unroll
        for (int j = 0; j < 4; ++j) h[j] = f2bf(v[j]);
        *reinterpret_cast<u16x4*>(&tile[row][cq * 4]) = h;
    }
    __syncthreads();
#pragma unroll
    for (int p = 0; p < 4; ++p) {
        int col = r + p * 16;
        u16x4 h;
#pragma unroll
        for (int i = 0; i < 4; ++i) h[i] = tile[cq * 4 + i][col];
        *reinterpret_cast<u16x4*>(D + (size_t)(m0 + col) * 4096 + k0 + cq * 4) = h;
    }
}

// ---------------------------------------------------------------------------
// small transposes (weights), batched
// ---------------------------------------------------------------------------
__global__ void transpose_cvt_b(const float* __restrict__ S, unsigned short* __restrict__ D,
                                int rows, int cols, size_t sstride, size_t dstride) {
    S += blockIdx.z * sstride; D += blockIdx.z * dstride;
    __shared__ unsigned short tile[32][33];
    int x0 = blockIdx.x * 32, y0 = blockIdx.y * 32;
    for (int j = threadIdx.y; j < 32; j += blockDim.y)
        tile[j][threadIdx.x] = f2bf(S[(size_t)(y0 + j) * cols + x0 + threadIdx.x]);
    __syncthreads();
    for (int j = threadIdx.y; j < 32; j += blockDim.y)
        D[(size_t)(x0 + j) * rows + y0 + threadIdx.x] = tile[threadIdx.x][j];
}

// 11 square 512x512 weights in one launch
__global__ void transpose_cvt11(const float* __restrict__ A, unsigned short* __restrict__ Ad,
                                const float* __restrict__ B, unsigned short* __restrict__ Bd,
                                const float* __restrict__ Cs, unsigned short* __restrict__ Cd) {
    int z = blockIdx.z;
    const float* S; unsigned short* D;
    if (z < 4)      { S = A  + (size_t)z * 262144;       D = Ad + (size_t)z * 262144; }
    else if (z < 7) { S = B  + (size_t)(z - 4) * 262144; D = Bd + (size_t)(z - 4) * 262144; }
    else            { S = Cs + (size_t)(z - 7) * 262144; D = Cd + (size_t)(z - 7) * 262144; }
    __shared__ unsigned short tile[32][33];
    int x0 = blockIdx.x * 32, y0 = blockIdx.y * 32;
    for (int j = threadIdx.y; j < 32; j += blockDim.y)
        tile[j][threadIdx.x] = f2bf(S[(size_t)(y0 + j) * 512 + x0 + threadIdx.x]);
    __syncthreads();
    for (int j = threadIdx.y; j < 32; j += blockDim.y)
        D[(size_t)(x0 + j) * 512 + y0 + threadIdx.x] = tile[threadIdx.x][j];
}

// ---------------------------------------------------------------------------
// x1 graph pooling (f32, 128 cols), row-chunked, atomics into pre-zeroed P0
// ---------------------------------------------------------------------------
__device__ __forceinline__ int lbound(const int* __restrict__ a, int n, int v) {
    int lo = 0, hi = n;
    while (lo < hi) { int m = (lo + hi) >> 1; if (a[m] < v) lo = m + 1; else hi = m; }
    return lo;
}

__global__ void pool_f32_at(const float* __restrict__ Hm, const int* __restrict__ gid,
                            int n, float* __restrict__ P) {
    int g = blockIdx.x;
    int lo = lbound(gid, n, g), hi = lbound(gid, n, g + 1);
    int cnt = hi - lo;
    int per = (cnt + 3) >> 2;
    int s = lo + blockIdx.y * per;
    int e = min(s + per, hi);
    if (s >= e) return;
    int c = threadIdx.x;
    f32x4 acc = {};
    for (int i = s; i < e; ++i)
        acc += *reinterpret_cast<const f32x4*>(Hm + (size_t)i * 128 + c * 4);
#pragma unroll
    for (int j = 0; j < 4; ++j)
        atomicAdd(&P[(size_t)g * 128 + c * 4 + j], acc[j]);
}

__global__ void softmax2(const float* __restrict__ atts, float* __restrict__ a) {
    if (threadIdx.x == 0) {
        float m = fmaxf(atts[0], atts[1]);
        float e0 = expf(atts[0] - m), e1 = expf(atts[1] - m);
        float inv = 1.0f / (e0 + e1);
        a[0] = e0 * inv; a[1] = e1 * inv;
    }
}

// score[g,o] = P0[g]@W0 + b0 + sum_l PL[l][g]@W[l] + b[l]
__global__ __launch_bounds__(256) void score_kernel(
    const float* __restrict__ P0, const float* __restrict__ PL,
    const float* __restrict__ W0, const float* __restrict__ b0,
    const float* __restrict__ W, const float* __restrict__ bb,
    float* __restrict__ out)
{
    int g = blockIdx.x;
    int t = threadIdx.x;
    float part[10];
#pragma unroll
    for (int o = 0; o < 10; ++o) part[o] = 0.f;
    if (t < 128) {
        float p = P0[g * 128 + t];
#pragma unroll
        for (int o = 0; o < 10; ++o) part[o] += p * W0[t * 10 + o];
    }
    for (int l = 0; l < 4; ++l) {
        const float* p = PL + (size_t)l * 65536 + (size_t)g * 1024;
        const float* w = W + (size_t)l * 10240;
        for (int k = t; k < 1024; k += 256) {
            float pv = p[k];
#pragma unroll
            for (int o = 0; o < 10; ++o) part[o] += pv * w[k * 10 + o];
        }
    }
    __shared__ float red[4][10];
#pragma unroll
    for (int o = 0; o < 10; ++o) {
        float v = part[o];
        for (int off = 32; off; off >>= 1) v += __shfl_down(v, off, 64);
        if ((t & 63) == 0) red[t >> 6][o] = v;
    }
    __syncthreads();
    if (t < 10) {
        float s = b0[t] + red[0][t] + red[1][t] + red[2][t] + red[3][t];
#pragma unroll
        for (int l = 0; l < 4; ++l) s += bb[l * 10 + t];
        out[g * 10 + t] = s;
    }
}

// ---------------------------------------------------------------------------
// host orchestration
// ---------------------------------------------------------------------------
extern "C" void kernel_launch(void* const* d_in, const int* in_sizes, int n_in,
                              void* d_out, int out_size, void* d_ws, size_t ws_size,
                              hipStream_t stream) {
    const float* x1    = (const float*)d_in[0];
    const float* x2    = (const float*)d_in[1];
    const float* motif = (const float*)d_in[2];
    const int*   edge1 = (const int*)d_in[3];
    const int*   edge2 = (const int*)d_in[4];
    const int*   gid   = (const int*)d_in[5];
    const float* epsv  = (const float*)d_in[6];
    const float* atts  = (const float*)d_in[7];
    const float* m1W10 = (const float*)d_in[8];
    const float* m1W1r = (const float*)d_in[9];
    const float* m1bng = (const float*)d_in[11];
    const float* m1bnb = (const float*)d_in[12];
    const float* m1W2  = (const float*)d_in[13];
    const float* bn1g  = (const float*)d_in[15];
    const float* bn1b  = (const float*)d_in[16];
    const float* m2W10 = (const float*)d_in[17];
    const float* m2W1r = (const float*)d_in[18];
    const float* m2bng = (const float*)d_in[20];
    const float* m2bnb = (const float*)d_in[21];
    const float* m2W2  = (const float*)d_in[22];
    const float* bn2g  = (const float*)d_in[24];
    const float* bn2b  = (const float*)d_in[25];
    const float* pW0   = (const float*)d_in[26];
    const float* pb0   = (const float*)d_in[27];
    const float* pW    = (const float*)d_in[28];
    const float* pb    = (const float*)d_in[29];
    float* out = (float*)d_out;

    constexpr int N1 = 8192, N2 = 4096, E1 = 262144, E2 = 65536;

    char* base = (char*)d_ws;
    size_t off = 0;
    auto alloc = [&](size_t bytes) -> void* {
        void* p = base + off;
        off = (off + bytes + 255) & ~(size_t)255;
        return p;
    };

    // bf16 buffers
    unsigned short* motifT  = (unsigned short*)alloc((size_t)8192 * 4096 * 2);
    unsigned short* w1t1_0  = (unsigned short*)alloc((size_t)512 * 128 * 2);
    unsigned short* w1t1_r  = (unsigned short*)alloc((size_t)3 * 512 * 1024 * 2);
    unsigned short* w2t1    = (unsigned short*)alloc((size_t)4 * 512 * 512 * 2);
    unsigned short* w1t2_0  = (unsigned short*)alloc((size_t)512 * 64 * 2);
    unsigned short* w1t2_r  = (unsigned short*)alloc((size_t)3 * 512 * 512 * 2);
    unsigned short* w2t2    = (unsigned short*)alloc((size_t)4 * 512 * 512 * 2);
    unsigned short* x1b     = (unsigned short*)alloc((size_t)N1 * 128 * 2);
    unsigned short* x2b     = (unsigned short*)alloc((size_t)N2 * 64 * 2);
    unsigned short* H1b     = (unsigned short*)alloc((size_t)N1 * 1024 * 2);
    unsigned short* H2b     = (unsigned short*)alloc((size_t)N2 * 512 * 2);
    unsigned short* H2t     = (unsigned short*)alloc((size_t)512 * 4096 * 2);
    unsigned short* U1b     = (unsigned short*)alloc((size_t)N1 * 512 * 2);
    unsigned short* U2b     = (unsigned short*)alloc((size_t)N2 * 512 * 2);
    unsigned short* Y1b     = (unsigned short*)alloc((size_t)N1 * 512 * 2);
    unsigned short* T1b     = (unsigned short*)alloc((size_t)N1 * 512 * 2);
    unsigned short* Y2b     = (unsigned short*)alloc((size_t)N2 * 512 * 2);
    unsigned short* T2b     = (unsigned short*)alloc((size_t)N2 * 512 * 2);
    // zero-together region: cnt1 | cnt2 | ss | PL | P0
    int*   cnt1 = (int*)alloc((size_t)N1 * 4);
    int*   cnt2 = (int*)alloc((size_t)N2 * 4);
    float* ss   = (float*)alloc((size_t)16 * 1024 * 4);
    float* PL   = (float*)alloc((size_t)4 * 64 * 1024 * 4);
    float* P0   = (float*)alloc((size_t)64 * 128 * 4);
    const size_t zero_bytes = (size_t)N1 * 4 + N2 * 4 + 16 * 1024 * 4 + 4 * 64 * 1024 * 4
                            + 64 * 128 * 4;
    int*   offs1 = (int*)alloc((size_t)(N1 + 1) * 4);
    int*   offs2 = (int*)alloc((size_t)(N2 + 1) * 4);
    int*   cur1  = (int*)alloc((size_t)N1 * 4);
    int*   cur2  = (int*)alloc((size_t)N2 * 4);
    int*   srcs1 = (int*)alloc((size_t)E1 * 4);
    int*   srcs2 = (int*)alloc((size_t)E2 * 4);
    float* aDev  = (float*)alloc(256);

    if (off > ws_size) return;

    // split-K partials for the fusion GEMM
    const size_t part_elems = (size_t)N1 * 512;
    size_t rem = ws_size - off;
    int KS = (rem >= 4 * part_elems * 4) ? 4 : (rem >= 2 * part_elems * 4) ? 2 : 1;
    float* Cpart = (float*)(base + off);

    // ---- setup ----
    hipMemsetAsync(cnt1, 0, zero_bytes, stream);
    softmax2<<<1, 64, 0, stream>>>(atts, aDev);
    cvt2_bf16<<<512, 256, 0, stream>>>((const f32x4*)x1, (u16x4*)x1b, N1 * 128 / 4,
                                       (const f32x4*)x2, (u16x4*)x2b, N2 * 64 / 4);
    motif_transpose<<<dim3(128, 64), 256, 0, stream>>>(motif, motifT);
    transpose_cvt_b<<<dim3(16, 4, 1), dim3(32, 8), 0, stream>>>(m1W10, w1t1_0, 128, 512, 0, 0);
    transpose_cvt_b<<<dim3(16, 32, 3), dim3(32, 8), 0, stream>>>(m1W1r, w1t1_r, 1024, 512,
                                                                 (size_t)1024 * 512, (size_t)512 * 1024);
    transpose_cvt_b<<<dim3(16, 2, 1), dim3(32, 8), 0, stream>>>(m2W10, w1t2_0, 64, 512, 0, 0);
    transpose_cvt11<<<dim3(16, 16, 11), dim3(32, 8), 0, stream>>>(m1W2, w2t1, m2W1r, w1t2_r, m2W2, w2t2);
    csr_count2<<<(E1 + E2) / 256, 256, 0, stream>>>(edge1, E1, cnt1, edge2, E2, cnt2);
    csr_scan2<<<2, 1024, 0, stream>>>(cnt1, N1, offs1, cur1, cnt2, N2, offs2, cur2);
    csr_fill2<<<(E1 + E2) / 256, 256, 0, stream>>>(edge1, E1, cur1, srcs1, edge2, E2, cur2, srcs2);
    pool_f32_at<<<dim3(64, 4), 32, 0, stream>>>(x1, gid, N1, P0);

    // ---- layers ----
    for (int l = 0; l < 4; ++l) {
        float* ssl = ss + (size_t)l * 4096;   // [0]=b1 gather, [1]=b1 W2, [2]=b2 gather, [3]=b2 W2
        float* PLl = PL + (size_t)l * 65536;
        // W1 GEMMs, both branches, one dispatch
        gemm_dual<<<dim3(192, 4), 256, 0, stream>>>(
            128,
            l ? H1b : x1b, l ? w1t1_r + (size_t)(l - 1) * 512 * 1024 : w1t1_0,
            l ? 1024 : 128, Y1b, nullptr,
            l ? H2b : x2b, l ? w1t2_r + (size_t)(l - 1) * 512 * 512 : w1t2_0,
            l ? 512 : 64, Y2b, nullptr);
        // both gathers in one dispatch (no stats fusion - round-7 lesson)
        gather2_bf16<<<N1 + N2, 128, 0, stream>>>(
            (const u16x4*)Y1b, offs1, srcs1, (u16x4*)T1b, N1,
            (const u16x4*)Y2b, offs2, srcs2, (u16x4*)T2b, epsv, l);
        // BN stats for both gather outputs
        bn_stats2<<<768, 128, 0, stream>>>(512, (const u16x4*)T1b, ssl + 0 * 1024,
                                           (const u16x4*)T2b, ssl + 2 * 1024);
        // mid BN apply, both branches
        bn_apply_mid<<<1536, 128, 0, stream>>>(
            1024,
            (const u16x4*)T1b, N1, ssl + 0 * 1024, m1bng + l * 512, m1bnb + l * 512, U1b,
            (const u16x4*)T2b, N2, ssl + 2 * 1024, m2bng + l * 512, m2bnb + l * 512, U2b);
        // W2 GEMMs with fused column stats, both branches
        gemm_dual<<<dim3(192, 4), 256, 0, stream>>>(
            128,
            U1b, w2t1 + (size_t)l * 512 * 512, 512, Y1b, ssl + 1 * 1024,
            U2b, w2t2 + (size_t)l * 512 * 512, 512, Y2b, ssl + 3 * 1024);
        // branch-2 final apply -> H2b + fused-transposed H2t
        bn_apply_b2t<<<512, 128, 0, stream>>>(
            (const u16x4*)Y2b, N2, ssl + 3 * 1024, bn2g + l * 512, bn2b + l * 512, H2b, H2t);
        // fusion: h2A = motif2A^T @ h2 (split-K partials)
        gemm_splitk<<<dim3(64, 4, KS), 256, 0, stream>>>(motifT, H2t, N1, 512, 4096, Cpart);
        // finale: branch-1 apply*a0 + pool (job0) || sumk*a1 + pool (job1)
        finale<<<2048, 128, 0, stream>>>(
            1024, gid, aDev, PLl, H1b,
            (const u16x4*)Y1b, ssl + 1 * 1024, bn1g + l * 512, bn1b + l * 512,
            (const f32x4*)Cpart, KS);
    }

    score_kernel<<<64, 256, 0, stream>>>(P0, PL, pW0, pb0, pW, pb, out);
}

// Round 9
// 916.449 us; speedup vs baseline: 1.7624x; 1.0825x over previous
//
#include <hip/hip_runtime.h>

// ---------------------------------------------------------------------------
// types & helpers
// ---------------------------------------------------------------------------
using bf16x8 = __attribute__((ext_vector_type(8))) short;
using f32x4  = __attribute__((ext_vector_type(4))) float;
using u16x4  = __attribute__((ext_vector_type(4))) unsigned short;
using u16x8  = __attribute__((ext_vector_type(8))) unsigned short;
using as3_void  = __attribute__((address_space(3))) void;
using as1_cvoid = const __attribute__((address_space(1))) void;

__device__ __forceinline__ unsigned short f2bf(float x) {
    union { float f; unsigned u; } v; v.f = x;
    unsigned r = v.u + 0x7FFFu + ((v.u >> 16) & 1u);   // RNE
    return (unsigned short)(r >> 16);
}
__device__ __forceinline__ float bf2f(unsigned short h) {
    union { unsigned u; float f; } v; v.u = ((unsigned)h) << 16;
    return v.f;
}

// XCD swizzle: consecutive HW ids round-robin the 8 XCDs; remap so each XCD
// owns contiguous row-panels with the 4 col-blocks adjacent (A-panel L2 reuse).
// Requires total % 8 == 0 (768 and 256 here). col = swz & 3 (4 col-blocks).
__device__ __forceinline__ void xcd_remap(int& bx, int& n0) {
    int flat  = blockIdx.x + gridDim.x * blockIdx.y;
    int total = gridDim.x * gridDim.y;
    int swz   = (flat & 7) * (total >> 3) + (flat >> 3);
    bx = swz >> 2;
    n0 = (swz & 3) * 128;
}

// ---------------------------------------------------------------------------
// GEMM tile body: BM x 128, BK=64, 4 waves (2x2). LDS XOR-swizzle applied on
// the GLOBAL source (global_load_lds needs linear dest); ds_read re-applies it.
// ---------------------------------------------------------------------------
#define GEMM_BODY(BM, A, Bt, K, KBEG, KEND)                                          \
    constexpr int WROWS = (BM) / 2;                                                  \
    constexpr int MI = WROWS / 16;                                                   \
    __shared__ __align__(16) unsigned short As[(BM) * 64];                           \
    __shared__ __align__(16) unsigned short Bs[128 * 64];                            \
    const int tid  = threadIdx.x;                                                    \
    const int lane = tid & 63, wave = tid >> 6;                                      \
    const int wr = wave >> 1, wc = wave & 1;                                         \
    const int rl = lane & 15, kg = lane >> 4;                                        \
    f32x4 acc[MI][4] = {};                                                           \
    for (int kt = (KBEG); kt < (KEND); kt += 64) {                                   \
        _Pragma("unroll")                                                            \
        for (int it = 0; it < (BM) / 32; ++it) {                                     \
            int slot = it * 256 + tid;                                               \
            int r = slot >> 3, c = slot & 7;                                         \
            int cg = c ^ (r & 7);                                                    \
            const unsigned short* ga = (A) + (size_t)(m0 + r) * (K) + (kt + cg * 8); \
            __builtin_amdgcn_global_load_lds((as1_cvoid*)ga, (as3_void*)(As + slot * 8), 16, 0, 0); \
        }                                                                            \
        _Pragma("unroll")                                                            \
        for (int it = 0; it < 4; ++it) {                                             \
            int slot = it * 256 + tid;                                               \
            int r = slot >> 3, c = slot & 7;                                         \
            int cg = c ^ (r & 7);                                                    \
            const unsigned short* gb = (Bt) + (size_t)(n0 + r) * (K) + (kt + cg * 8);\
            __builtin_amdgcn_global_load_lds((as1_cvoid*)gb, (as3_void*)(Bs + slot * 8), 16, 0, 0); \
        }                                                                            \
        __syncthreads();                                                             \
        _Pragma("unroll")                                                            \
        for (int kh = 0; kh < 2; ++kh) {                                             \
            bf16x8 a_[MI], b_[4];                                                    \
            _Pragma("unroll")                                                        \
            for (int i = 0; i < MI; ++i) {                                           \
                int ra = wr * WROWS + i * 16 + rl;                                   \
                int ca = (kh * 4 + kg) ^ (ra & 7);                                   \
                a_[i] = *reinterpret_cast<const bf16x8*>(&As[ra * 64 + ca * 8]);     \
            }                                                                        \
            _Pragma("unroll")                                                        \
            for (int j = 0; j < 4; ++j) {                                            \
                int rb = wc * 64 + j * 16 + rl;                                      \
                int cb = (kh * 4 + kg) ^ (rb & 7);                                   \
                b_[j] = *reinterpret_cast<const bf16x8*>(&Bs[rb * 64 + cb * 8]);     \
            }                                                                        \
            _Pragma("unroll")                                                        \
            for (int i = 0; i < MI; ++i)                                             \
                _Pragma("unroll")                                                    \
                for (int j = 0; j < 4; ++j)                                          \
                    acc[i][j] = __builtin_amdgcn_mfma_f32_16x16x32_bf16(a_[i], b_[j], acc[i][j], 0, 0, 0); \
        }                                                                            \
        __syncthreads();                                                             \
    }

// ---------------------------------------------------------------------------
// dual-job GEMM (BM=64): job-split over row-blocks after XCD remap. bf16 out,
// optional fused BN column stats (sum/sumsq atomicAdd into statp[1024]).
// ---------------------------------------------------------------------------
__global__ __launch_bounds__(256) void gemm_dual(
    int nb0,
    const unsigned short* __restrict__ A0, const unsigned short* __restrict__ B0,
    int K0, unsigned short* __restrict__ C0, float* __restrict__ st0,
    const unsigned short* __restrict__ A1, const unsigned short* __restrict__ B1,
    int K1, unsigned short* __restrict__ C1, float* __restrict__ st1)
{
    int bx, n0;
    xcd_remap(bx, n0);
    const unsigned short *A, *Bt; unsigned short* Cb; float* statp;
    int K;
    if (bx < nb0) { A = A0; Bt = B0; K = K0; Cb = C0; statp = st0; }
    else { bx -= nb0; A = A1; Bt = B1; K = K1; Cb = C1; statp = st1; }
    const int m0 = bx * 64;

    GEMM_BODY(64, A, Bt, K, 0, K)

#pragma unroll
    for (int i = 0; i < MI; ++i)
#pragma unroll
        for (int j = 0; j < 4; ++j)
#pragma unroll
            for (int e = 0; e < 4; ++e) {
                int rr = m0 + wr * WROWS + i * 16 + kg * 4 + e;
                int cc = n0 + wc * 64 + j * 16 + rl;
                Cb[(size_t)rr * 512 + cc] = f2bf(acc[i][j][e]);
            }
    if (statp) {
#pragma unroll
        for (int j = 0; j < 4; ++j) {
            float s = 0.f, q = 0.f;
#pragma unroll
            for (int i = 0; i < MI; ++i)
#pragma unroll
                for (int e = 0; e < 4; ++e) {
                    float x = acc[i][j][e];
                    s += x; q += x * x;
                }
            s += __shfl_xor(s, 16); s += __shfl_xor(s, 32);
            q += __shfl_xor(q, 16); q += __shfl_xor(q, 32);
            if (kg == 0) {
                int cc = n0 + wc * 64 + j * 16 + rl;
                atomicAdd(&statp[cc], s);
                atomicAdd(&statp[512 + cc], q);
            }
        }
    }
}

// ---------------------------------------------------------------------------
// fusion GEMM (BM=128), split-K over grid.z: f32 partials. XCD remap gives
// A-panel L2 reuse across the 4 column blocks (A = 64 MB motifT).
// ---------------------------------------------------------------------------
__global__ __launch_bounds__(256) void gemm_splitk(
    const unsigned short* __restrict__ A, const unsigned short* __restrict__ Bt,
    int M, int N, int K, float* __restrict__ Cp)
{
    int bx, n0;
    xcd_remap(bx, n0);
    const int m0 = bx * 128;
    const int kn = K / gridDim.z, kbeg = blockIdx.z * kn;

    GEMM_BODY(128, A, Bt, K, kbeg, kbeg + kn)

    float* dst = Cp + (size_t)blockIdx.z * M * N;
#pragma unroll
    for (int i = 0; i < MI; ++i)
#pragma unroll
        for (int j = 0; j < 4; ++j)
#pragma unroll
            for (int e = 0; e < 4; ++e) {
                int rr = m0 + wr * WROWS + i * 16 + kg * 4 + e;
                int cc = n0 + wc * 64 + j * 16 + rl;
                dst[(size_t)rr * N + cc] = acc[i][j][e];
            }
}

// ---------------------------------------------------------------------------
// CSR build
// ---------------------------------------------------------------------------
__global__ void csr_count2(const int* __restrict__ e1, int E1, int* __restrict__ c1,
                           const int* __restrict__ e2, int E2, int* __restrict__ c2) {
    int i = blockIdx.x * 256 + threadIdx.x;
    if (i < E1) atomicAdd(&c1[e1[i]], 1);
    else if (i < E1 + E2) atomicAdd(&c2[e2[i - E1]], 1);
}

__global__ void csr_scan2(const int* __restrict__ cnt1, int n1, int* __restrict__ offs1, int* __restrict__ cur1,
                          const int* __restrict__ cnt2, int n2, int* __restrict__ offs2, int* __restrict__ cur2) {
    const int* cnt = blockIdx.x ? cnt2 : cnt1;
    int n           = blockIdx.x ? n2 : n1;
    int* offs       = blockIdx.x ? offs2 : offs1;
    int* cursor     = blockIdx.x ? cur2 : cur1;
    __shared__ int part[1024];
    int t = threadIdx.x;
    int per = n >> 10;
    int base = t * per;
    int loc[8];
    int s = 0;
    for (int j = 0; j < per; ++j) { loc[j] = s; s += cnt[base + j]; }
    part[t] = s;
    __syncthreads();
    for (int o = 1; o < 1024; o <<= 1) {
        int v = (t >= o) ? part[t - o] : 0;
        __syncthreads();
        part[t] += v;
        __syncthreads();
    }
    int excl = (t == 0) ? 0 : part[t - 1];
    for (int j = 0; j < per; ++j) {
        int v = excl + loc[j];
        offs[base + j] = v;
        cursor[base + j] = v;
    }
    if (t == 1023) offs[n] = part[1023];
}

__global__ void csr_fill2(const int* __restrict__ e1, int E1, int* __restrict__ cur1, int* __restrict__ s1,
                          const int* __restrict__ e2, int E2, int* __restrict__ cur2, int* __restrict__ s2) {
    int i = blockIdx.x * 256 + threadIdx.x;
    if (i < E1) {
        int d = e1[i], s = e1[E1 + i];
        s1[atomicAdd(&cur1[d], 1)] = s;
    } else if (i < E1 + E2) {
        int e = i - E1;
        int d = e2[e], s = e2[E2 + e];
        s2[atomicAdd(&cur2[d], 1)] = s;
    }
}

// ---------------------------------------------------------------------------
// gather for BOTH branches in one dispatch (512 cols, one block per row).
// NO fused stats: 12.6M global atomics cost 170 us/dispatch (round-7 lesson).
// ---------------------------------------------------------------------------
__global__ __launch_bounds__(128) void gather2_bf16(
    const u16x4* __restrict__ Y1, const int* __restrict__ offs1, const int* __restrict__ srcs1,
    u16x4* __restrict__ T1, int n1,
    const u16x4* __restrict__ Y2, const int* __restrict__ offs2, const int* __restrict__ srcs2,
    u16x4* __restrict__ T2,
    const float* __restrict__ epsv, int l)
{
    int i = blockIdx.x;
    const u16x4* Y; u16x4* T; const int *offs, *srcs;
    if (i < n1) { Y = Y1; T = T1; offs = offs1; srcs = srcs1; }
    else        { i -= n1; Y = Y2; T = T2; offs = offs2; srcs = srcs2; }
    int c = threadIdx.x;
    float e = 1.0f + epsv[l];
    int lo = offs[i], hi = offs[i + 1];
    u16x4 hv = Y[(size_t)i * 128 + c];
    f32x4 a0, a1 = {}, a2 = {}, a3 = {};
#pragma unroll
    for (int j = 0; j < 4; ++j) a0[j] = e * bf2f(hv[j]);
    int k = lo;
    for (; k + 4 <= hi; k += 4) {
        int s0 = srcs[k], s1 = srcs[k + 1], s2 = srcs[k + 2], s3 = srcs[k + 3];
        u16x4 v0 = Y[(size_t)s0 * 128 + c];
        u16x4 v1 = Y[(size_t)s1 * 128 + c];
        u16x4 v2 = Y[(size_t)s2 * 128 + c];
        u16x4 v3 = Y[(size_t)s3 * 128 + c];
#pragma unroll
        for (int j = 0; j < 4; ++j) {
            a0[j] += bf2f(v0[j]); a1[j] += bf2f(v1[j]);
            a2[j] += bf2f(v2[j]); a3[j] += bf2f(v3[j]);
        }
    }
    for (; k < hi; ++k) {
        u16x4 v = Y[(size_t)srcs[k] * 128 + c];
#pragma unroll
        for (int j = 0; j < 4; ++j) a0[j] += bf2f(v[j]);
    }
    f32x4 acc = (a0 + a1) + (a2 + a3);
    u16x4 o;
#pragma unroll
    for (int j = 0; j < 4; ++j) o[j] = f2bf(acc[j]);
    T[(size_t)i * 128 + c] = o;
}

// ---------------------------------------------------------------------------
// layer-0 gather on the NARROW inputs (branch1: 128 cols, branch2: 64 cols).
// By linearity A@(X@W1) == (A@X)@W1, so gathering before the W1 GEMM cuts
// gather traffic 4x at layer 0. One wave per row.
// ---------------------------------------------------------------------------
__global__ __launch_bounds__(64) void gather2_l0(
    const u16x4* __restrict__ X1, const int* __restrict__ offs1, const int* __restrict__ srcs1,
    u16x4* __restrict__ T1, int n1,
    const u16x4* __restrict__ X2, const int* __restrict__ offs2, const int* __restrict__ srcs2,
    u16x4* __restrict__ T2,
    const float* __restrict__ epsv)
{
    int i = blockIdx.x;
    const u16x4* X; u16x4* T; const int *offs, *srcs; int nc4;
    if (i < n1) { X = X1; T = T1; offs = offs1; srcs = srcs1; nc4 = 32; }
    else        { i -= n1; X = X2; T = T2; offs = offs2; srcs = srcs2; nc4 = 16; }
    int c = threadIdx.x;
    if (c >= nc4) return;
    float e = 1.0f + epsv[0];
    int lo = offs[i], hi = offs[i + 1];
    u16x4 hv = X[(size_t)i * nc4 + c];
    f32x4 a0, a1 = {}, a2 = {}, a3 = {};
#pragma unroll
    for (int j = 0; j < 4; ++j) a0[j] = e * bf2f(hv[j]);
    int k = lo;
    for (; k + 4 <= hi; k += 4) {
        int s0 = srcs[k], s1 = srcs[k + 1], s2 = srcs[k + 2], s3 = srcs[k + 3];
        u16x4 v0 = X[(size_t)s0 * nc4 + c];
        u16x4 v1 = X[(size_t)s1 * nc4 + c];
        u16x4 v2 = X[(size_t)s2 * nc4 + c];
        u16x4 v3 = X[(size_t)s3 * nc4 + c];
#pragma unroll
        for (int j = 0; j < 4; ++j) {
            a0[j] += bf2f(v0[j]); a1[j] += bf2f(v1[j]);
            a2[j] += bf2f(v2[j]); a3[j] += bf2f(v3[j]);
        }
    }
    for (; k < hi; ++k) {
        u16x4 v = X[(size_t)srcs[k] * nc4 + c];
#pragma unroll
        for (int j = 0; j < 4; ++j) a0[j] += bf2f(v[j]);
    }
    f32x4 acc = (a0 + a1) + (a2 + a3);
    u16x4 o;
#pragma unroll
    for (int j = 0; j < 4; ++j) o[j] = f2bf(acc[j]);
    T[(size_t)i * nc4 + c] = o;
}

// ---------------------------------------------------------------------------
// dual column sum/sumsq over bf16 [M][512]: job0 = 512 blocks x16 rows,
// job1 = 256 blocks x16 rows. ~786K atomics total - cheap (round-6 evidence).
// ---------------------------------------------------------------------------
__global__ void bn_stats2(int nb0,
                          const u16x4* __restrict__ X0, float* __restrict__ ss0,
                          const u16x4* __restrict__ X1, float* __restrict__ ss1) {
    int bx = blockIdx.x;
    const u16x4* X; float* ss;
    if (bx < nb0) { X = X0; ss = ss0; }
    else { bx -= nb0; X = X1; ss = ss1; }
    int c = threadIdx.x;
    int r0 = bx * 16;
    f32x4 s = {}, q = {};
    for (int r = 0; r < 16; ++r) {
        u16x4 v = X[(size_t)(r0 + r) * 128 + c];
        f32x4 f;
#pragma unroll
        for (int j = 0; j < 4; ++j) f[j] = bf2f(v[j]);
        s += f; q += f * f;
    }
#pragma unroll
    for (int j = 0; j < 4; ++j) {
        atomicAdd(&ss[c * 4 + j], s[j]);
        atomicAdd(&ss[512 + c * 4 + j], q[j]);
    }
}

// ---------------------------------------------------------------------------
// dual mid BN apply -> U buffers
// ---------------------------------------------------------------------------
__global__ __launch_bounds__(128) void bn_apply_mid(
    int nb0,
    const u16x4* __restrict__ X0, int M0, const float* __restrict__ ss0,
    const float* __restrict__ g0, const float* __restrict__ b0, unsigned short* __restrict__ o0,
    const u16x4* __restrict__ X1, int M1, const float* __restrict__ ss1,
    const float* __restrict__ g1, const float* __restrict__ b1, unsigned short* __restrict__ o1)
{
    int bx = blockIdx.x;
    const u16x4* X; const float *ss, *g, *b; unsigned short* out; int M;
    if (bx < nb0) { X = X0; M = M0; ss = ss0; g = g0; b = b0; out = o0; }
    else { bx -= nb0; X = X1; M = M1; ss = ss1; g = g1; b = b1; out = o1; }
    int c = threadIdx.x;
    float inv = 1.0f / (float)M;
    float al[4], be[4];
#pragma unroll
    for (int i = 0; i < 4; ++i) {
        float mean = ss[c * 4 + i] * inv;
        float var  = ss[512 + c * 4 + i] * inv - mean * mean;
        al[i] = g[c * 4 + i] * rsqrtf(var + 1e-5f);
        be[i] = b[c * 4 + i] - mean * al[i];
    }
    int r0 = bx * 8;
    for (int r = 0; r < 8; ++r) {
        u16x4 v = X[(size_t)(r0 + r) * 128 + c];
        u16x4 h;
#pragma unroll
        for (int i = 0; i < 4; ++i)
            h[i] = f2bf(fmaxf(al[i] * bf2f(v[i]) + be[i], 0.f));
        *reinterpret_cast<u16x4*>(out + (size_t)(r0 + r) * 512 + c * 4) = h;
    }
}

// ---------------------------------------------------------------------------
// branch-2 final BN apply -> H2b [4096][512] AND H2t [512][4096] (fused
// transpose: 8 rows/block => one 16B store per column)
// ---------------------------------------------------------------------------
__global__ __launch_bounds__(128) void bn_apply_b2t(
    const u16x4* __restrict__ X, int M, const float* __restrict__ ss,
    const float* __restrict__ g, const float* __restrict__ b,
    unsigned short* __restrict__ out, unsigned short* __restrict__ outT)
{
    int c = threadIdx.x;
    float inv = 1.0f / (float)M;
    float al[4], be[4];
#pragma unroll
    for (int i = 0; i < 4; ++i) {
        float mean = ss[c * 4 + i] * inv;
        float var  = ss[512 + c * 4 + i] * inv - mean * mean;
        al[i] = g[c * 4 + i] * rsqrtf(var + 1e-5f);
        be[i] = b[c * 4 + i] - mean * al[i];
    }
    int r0 = blockIdx.x * 8;
    u16x8 t8[4];
#pragma unroll
    for (int r = 0; r < 8; ++r) {
        u16x4 v = X[(size_t)(r0 + r) * 128 + c];
        u16x4 h;
#pragma unroll
        for (int i = 0; i < 4; ++i) {
            h[i] = f2bf(fmaxf(al[i] * bf2f(v[i]) + be[i], 0.f));
            t8[i][r] = h[i];
        }
        *reinterpret_cast<u16x4*>(out + (size_t)(r0 + r) * 512 + c * 4) = h;
    }
#pragma unroll
    for (int i = 0; i < 4; ++i)
        *reinterpret_cast<u16x8*>(outT + (size_t)(c * 4 + i) * 4096 + r0) = t8[i];
}

// ---------------------------------------------------------------------------
// finale: job0 (blocks < nb0) = branch-1 final BN apply * a0 -> H1b[:, :512]
//         + JK pool; job1 = sum KS split-K partials * a1 -> H1b[:, 512:]
//         + JK pool. gid sorted; pool pre-zeroed.
// ---------------------------------------------------------------------------
__global__ __launch_bounds__(128) void finale(
    int nb0, const int* __restrict__ gid, const float* __restrict__ aDev,
    float* __restrict__ pool, unsigned short* __restrict__ H1,
    const u16x4* __restrict__ X, const float* __restrict__ ss,
    const float* __restrict__ g, const float* __restrict__ b,
    const f32x4* __restrict__ P, int ks)
{
    int bx = blockIdx.x;
    int c = threadIdx.x;
    int job = bx >= nb0;
    if (job) bx -= nb0;
    int r0 = bx * 8;
    int ooff = job ? 512 : 0;
    float al[4], be[4];
    float sc;
    if (!job) {
        sc = aDev[0];
        float inv = 1.0f / 8192.0f;
#pragma unroll
        for (int i = 0; i < 4; ++i) {
            float mean = ss[c * 4 + i] * inv;
            float var  = ss[512 + c * 4 + i] * inv - mean * mean;
            al[i] = g[c * 4 + i] * rsqrtf(var + 1e-5f);
            be[i] = b[c * 4 + i] - mean * al[i];
        }
    } else {
        sc = aDev[1];
    }
    const int total4 = 8192 * 128;
    int curg = gid[r0];
    f32x4 pacc = {};
    for (int r = 0; r < 8; ++r) {
        int row = r0 + r;
        u16x4 h;
        f32x4 f;
        if (!job) {
            u16x4 v = X[(size_t)row * 128 + c];
#pragma unroll
            for (int i = 0; i < 4; ++i) {
                h[i] = f2bf(fmaxf(al[i] * bf2f(v[i]) + be[i], 0.f) * sc);
                f[i] = bf2f(h[i]);
            }
        } else {
            f32x4 s = P[(size_t)row * 128 + c];
            for (int z = 1; z < ks; ++z) s += P[(size_t)z * total4 + (size_t)row * 128 + c];
#pragma unroll
            for (int i = 0; i < 4; ++i) { h[i] = f2bf(s[i] * sc); f[i] = bf2f(h[i]); }
        }
        *reinterpret_cast<u16x4*>(H1 + (size_t)row * 1024 + ooff + c * 4) = h;
        int gg = gid[row];
        if (gg != curg) {
#pragma unroll
            for (int j = 0; j < 4; ++j)
                atomicAdd(&pool[(size_t)curg * 1024 + ooff + c * 4 + j], pacc[j]);
            pacc = {}; curg = gg;
        }
        pacc += f;
    }
#pragma unroll
    for (int j = 0; j < 4; ++j)
        atomicAdd(&pool[(size_t)curg * 1024 + ooff + c * 4 + j], pacc[j]);
}

// contiguous f32 -> bf16 convert, two tensors in one dispatch
__global__ void cvt2_bf16(const f32x4* __restrict__ X0, u16x4* __restrict__ O0, int n0,
                          const f32x4* __restrict__ X1, u16x4* __restrict__ O1, int n1) {
    for (int i = blockIdx.x * blockDim.x + threadIdx.x; i < n0 + n1; i += gridDim.x * blockDim.x) {
        const f32x4* X; u16x4* O; int k;
        if (i < n0) { X = X0; O = O0; k = i; }
        else { X = X1; O = O1; k = i - n0; }
        f32x4 v = X[k];
        u16x4 h;
#pragma unroll
        for (int j = 0; j < 4; ++j) h[j] = f2bf(v[j]);
        O[k] = h;
    }
}

// ---------------------------------------------------------------------------
// motif transpose: S f32 [4096][8192] -> D bf16 [8192][4096], 64x64 tiles
// ---------------------------------------------------------------------------
__global__ __launch_bounds__(256) void motif_transpose(const float* __restrict__ S,
                                                       unsigned short* __restrict__ D) {
    __shared__ unsigned short tile[64][66];
    int m0 = blockIdx.x * 64;
    int k0 = blockIdx.y * 64;
    int t = threadIdx.x;
    int r = t >> 4, cq = t & 15;
#pragma unroll
    for (int p = 0; p < 4; ++p) {
        int row = r + p * 16;
        f32x4 v = *reinterpret_cast<const f32x4*>(S + (size_t)(k0 + row) * 8192 + m0 + cq * 4);
        u16x4 h;
#pragma unroll
        for (int j = 0; j < 4; ++j) h[j] = f2bf(v[j]);
        *reinterpret_cast<u16x4*>(&tile[row][cq * 4]) = h;
    }
    __syncthreads();
#pragma unroll
    for (int p = 0; p < 4; ++p) {
        int col = r + p * 16;
        u16x4 h;
#pragma unroll
        for (int i = 0; i < 4; ++i) h[i] = tile[cq * 4 + i][col];
        *reinterpret_cast<u16x4*>(D + (size_t)(m0 + col) * 4096 + k0 + cq * 4) = h;
    }
}

// ---------------------------------------------------------------------------
// small transposes (weights), batched
// ---------------------------------------------------------------------------
__global__ void transpose_cvt_b(const float* __restrict__ S, unsigned short* __restrict__ D,
                                int rows, int cols, size_t sstride, size_t dstride) {
    S += blockIdx.z * sstride; D += blockIdx.z * dstride;
    __shared__ unsigned short tile[32][33];
    int x0 = blockIdx.x * 32, y0 = blockIdx.y * 32;
    for (int j = threadIdx.y; j < 32; j += blockDim.y)
        tile[j][threadIdx.x] = f2bf(S[(size_t)(y0 + j) * cols + x0 + threadIdx.x]);
    __syncthreads();
    for (int j = threadIdx.y; j < 32; j += blockDim.y)
        D[(size_t)(x0 + j) * rows + y0 + threadIdx.x] = tile[threadIdx.x][j];
}

// 11 square 512x512 weights in one launch
__global__ void transpose_cvt11(const float* __restrict__ A, unsigned short* __restrict__ Ad,
                                const float* __restrict__ B, unsigned short* __restrict__ Bd,
                                const float* __restrict__ Cs, unsigned short* __restrict__ Cd) {
    int z = blockIdx.z;
    const float* S; unsigned short* D;
    if (z < 4)      { S = A  + (size_t)z * 262144;       D = Ad + (size_t)z * 262144; }
    else if (z < 7) { S = B  + (size_t)(z - 4) * 262144; D = Bd + (size_t)(z - 4) * 262144; }
    else            { S = Cs + (size_t)(z - 7) * 262144; D = Cd + (size_t)(z - 7) * 262144; }
    __shared__ unsigned short tile[32][33];
    int x0 = blockIdx.x * 32, y0 = blockIdx.y * 32;
    for (int j = threadIdx.y; j < 32; j += blockDim.y)
        tile[j][threadIdx.x] = f2bf(S[(size_t)(y0 + j) * 512 + x0 + threadIdx.x]);
    __syncthreads();
    for (int j = threadIdx.y; j < 32; j += blockDim.y)
        D[(size_t)(x0 + j) * 512 + y0 + threadIdx.x] = tile[threadIdx.x][j];
}

// ---------------------------------------------------------------------------
// x1 graph pooling (f32, 128 cols), row-chunked, atomics into pre-zeroed P0
// ---------------------------------------------------------------------------
__device__ __forceinline__ int lbound(const int* __restrict__ a, int n, int v) {
    int lo = 0, hi = n;
    while (lo < hi) { int m = (lo + hi) >> 1; if (a[m] < v) lo = m + 1; else hi = m; }
    return lo;
}

__global__ void pool_f32_at(const float* __restrict__ Hm, const int* __restrict__ gid,
                            int n, float* __restrict__ P) {
    int g = blockIdx.x;
    int lo = lbound(gid, n, g), hi = lbound(gid, n, g + 1);
    int cnt = hi - lo;
    int per = (cnt + 3) >> 2;
    int s = lo + blockIdx.y * per;
    int e = min(s + per, hi);
    if (s >= e) return;
    int c = threadIdx.x;
    f32x4 acc = {};
    for (int i = s; i < e; ++i)
        acc += *reinterpret_cast<const f32x4*>(Hm + (size_t)i * 128 + c * 4);
#pragma unroll
    for (int j = 0; j < 4; ++j)
        atomicAdd(&P[(size_t)g * 128 + c * 4 + j], acc[j]);
}

__global__ void softmax2(const float* __restrict__ atts, float* __restrict__ a) {
    if (threadIdx.x == 0) {
        float m = fmaxf(atts[0], atts[1]);
        float e0 = expf(atts[0] - m), e1 = expf(atts[1] - m);
        float inv = 1.0f / (e0 + e1);
        a[0] = e0 * inv; a[1] = e1 * inv;
    }
}

// score[g,o] = P0[g]@W0 + b0 + sum_l PL[l][g]@W[l] + b[l]
__global__ __launch_bounds__(256) void score_kernel(
    const float* __restrict__ P0, const float* __restrict__ PL,
    const float* __restrict__ W0, const float* __restrict__ b0,
    const float* __restrict__ W, const float* __restrict__ bb,
    float* __restrict__ out)
{
    int g = blockIdx.x;
    int t = threadIdx.x;
    float part[10];
#pragma unroll
    for (int o = 0; o < 10; ++o) part[o] = 0.f;
    if (t < 128) {
        float p = P0[g * 128 + t];
#pragma unroll
        for (int o = 0; o < 10; ++o) part[o] += p * W0[t * 10 + o];
    }
    for (int l = 0; l < 4; ++l) {
        const float* p = PL + (size_t)l * 65536 + (size_t)g * 1024;
        const float* w = W + (size_t)l * 10240;
        for (int k = t; k < 1024; k += 256) {
            float pv = p[k];
#pragma unroll
            for (int o = 0; o < 10; ++o) part[o] += pv * w[k * 10 + o];
        }
    }
    __shared__ float red[4][10];
#pragma unroll
    for (int o = 0; o < 10; ++o) {
        float v = part[o];
        for (int off = 32; off; off >>= 1) v += __shfl_down(v, off, 64);
        if ((t & 63) == 0) red[t >> 6][o] = v;
    }
    __syncthreads();
    if (t < 10) {
        float s = b0[t] + red[0][t] + red[1][t] + red[2][t] + red[3][t];
#pragma unroll
        for (int l = 0; l < 4; ++l) s += bb[l * 10 + t];
        out[g * 10 + t] = s;
    }
}

// ---------------------------------------------------------------------------
// host orchestration
// ---------------------------------------------------------------------------
extern "C" void kernel_launch(void* const* d_in, const int* in_sizes, int n_in,
                              void* d_out, int out_size, void* d_ws, size_t ws_size,
                              hipStream_t stream) {
    const float* x1    = (const float*)d_in[0];
    const float* x2    = (const float*)d_in[1];
    const float* motif = (const float*)d_in[2];
    const int*   edge1 = (const int*)d_in[3];
    const int*   edge2 = (const int*)d_in[4];
    const int*   gid   = (const int*)d_in[5];
    const float* epsv  = (const float*)d_in[6];
    const float* atts  = (const float*)d_in[7];
    const float* m1W10 = (const float*)d_in[8];
    const float* m1W1r = (const float*)d_in[9];
    const float* m1bng = (const float*)d_in[11];
    const float* m1bnb = (const float*)d_in[12];
    const float* m1W2  = (const float*)d_in[13];
    const float* bn1g  = (const float*)d_in[15];
    const float* bn1b  = (const float*)d_in[16];
    const float* m2W10 = (const float*)d_in[17];
    const float* m2W1r = (const float*)d_in[18];
    const float* m2bng = (const float*)d_in[20];
    const float* m2bnb = (const float*)d_in[21];
    const float* m2W2  = (const float*)d_in[22];
    const float* bn2g  = (const float*)d_in[24];
    const float* bn2b  = (const float*)d_in[25];
    const float* pW0   = (const float*)d_in[26];
    const float* pb0   = (const float*)d_in[27];
    const float* pW    = (const float*)d_in[28];
    const float* pb    = (const float*)d_in[29];
    float* out = (float*)d_out;

    constexpr int N1 = 8192, N2 = 4096, E1 = 262144, E2 = 65536;

    char* base = (char*)d_ws;
    size_t off = 0;
    auto alloc = [&](size_t bytes) -> void* {
        void* p = base + off;
        off = (off + bytes + 255) & ~(size_t)255;
        return p;
    };

    // bf16 buffers
    unsigned short* motifT  = (unsigned short*)alloc((size_t)8192 * 4096 * 2);
    unsigned short* w1t1_0  = (unsigned short*)alloc((size_t)512 * 128 * 2);
    unsigned short* w1t1_r  = (unsigned short*)alloc((size_t)3 * 512 * 1024 * 2);
    unsigned short* w2t1    = (unsigned short*)alloc((size_t)4 * 512 * 512 * 2);
    unsigned short* w1t2_0  = (unsigned short*)alloc((size_t)512 * 64 * 2);
    unsigned short* w1t2_r  = (unsigned short*)alloc((size_t)3 * 512 * 512 * 2);
    unsigned short* w2t2    = (unsigned short*)alloc((size_t)4 * 512 * 512 * 2);
    unsigned short* x1b     = (unsigned short*)alloc((size_t)N1 * 128 * 2);
    unsigned short* x2b     = (unsigned short*)alloc((size_t)N2 * 64 * 2);
    unsigned short* Tx1     = (unsigned short*)alloc((size_t)N1 * 128 * 2);
    unsigned short* Tx2     = (unsigned short*)alloc((size_t)N2 * 64 * 2);
    unsigned short* H1b     = (unsigned short*)alloc((size_t)N1 * 1024 * 2);
    unsigned short* H2b     = (unsigned short*)alloc((size_t)N2 * 512 * 2);
    unsigned short* H2t     = (unsigned short*)alloc((size_t)512 * 4096 * 2);
    unsigned short* U1b     = (unsigned short*)alloc((size_t)N1 * 512 * 2);
    unsigned short* U2b     = (unsigned short*)alloc((size_t)N2 * 512 * 2);
    unsigned short* Y1b     = (unsigned short*)alloc((size_t)N1 * 512 * 2);
    unsigned short* T1b     = (unsigned short*)alloc((size_t)N1 * 512 * 2);
    unsigned short* Y2b     = (unsigned short*)alloc((size_t)N2 * 512 * 2);
    unsigned short* T2b     = (unsigned short*)alloc((size_t)N2 * 512 * 2);
    // zero-together region: cnt1 | cnt2 | ss | PL | P0
    int*   cnt1 = (int*)alloc((size_t)N1 * 4);
    int*   cnt2 = (int*)alloc((size_t)N2 * 4);
    float* ss   = (float*)alloc((size_t)16 * 1024 * 4);
    float* PL   = (float*)alloc((size_t)4 * 64 * 1024 * 4);
    float* P0   = (float*)alloc((size_t)64 * 128 * 4);
    const size_t zero_bytes = (size_t)N1 * 4 + N2 * 4 + 16 * 1024 * 4 + 4 * 64 * 1024 * 4
                            + 64 * 128 * 4;
    int*   offs1 = (int*)alloc((size_t)(N1 + 1) * 4);
    int*   offs2 = (int*)alloc((size_t)(N2 + 1) * 4);
    int*   cur1  = (int*)alloc((size_t)N1 * 4);
    int*   cur2  = (int*)alloc((size_t)N2 * 4);
    int*   srcs1 = (int*)alloc((size_t)E1 * 4);
    int*   srcs2 = (int*)alloc((size_t)E2 * 4);
    float* aDev  = (float*)alloc(256);

    if (off > ws_size) return;

    // split-K partials for the fusion GEMM
    const size_t part_elems = (size_t)N1 * 512;
    size_t rem = ws_size - off;
    int KS = (rem >= 4 * part_elems * 4) ? 4 : (rem >= 2 * part_elems * 4) ? 2 : 1;
    float* Cpart = (float*)(base + off);

    // ---- setup ----
    hipMemsetAsync(cnt1, 0, zero_bytes, stream);
    softmax2<<<1, 64, 0, stream>>>(atts, aDev);
    cvt2_bf16<<<512, 256, 0, stream>>>((const f32x4*)x1, (u16x4*)x1b, N1 * 128 / 4,
                                       (const f32x4*)x2, (u16x4*)x2b, N2 * 64 / 4);
    motif_transpose<<<dim3(128, 64), 256, 0, stream>>>(motif, motifT);
    transpose_cvt_b<<<dim3(16, 4, 1), dim3(32, 8), 0, stream>>>(m1W10, w1t1_0, 128, 512, 0, 0);
    transpose_cvt_b<<<dim3(16, 32, 3), dim3(32, 8), 0, stream>>>(m1W1r, w1t1_r, 1024, 512,
                                                                 (size_t)1024 * 512, (size_t)512 * 1024);
    transpose_cvt_b<<<dim3(16, 2, 1), dim3(32, 8), 0, stream>>>(m2W10, w1t2_0, 64, 512, 0, 0);
    transpose_cvt11<<<dim3(16, 16, 11), dim3(32, 8), 0, stream>>>(m1W2, w2t1, m2W1r, w1t2_r, m2W2, w2t2);
    csr_count2<<<(E1 + E2) / 256, 256, 0, stream>>>(edge1, E1, cnt1, edge2, E2, cnt2);
    csr_scan2<<<2, 1024, 0, stream>>>(cnt1, N1, offs1, cur1, cnt2, N2, offs2, cur2);
    csr_fill2<<<(E1 + E2) / 256, 256, 0, stream>>>(edge1, E1, cur1, srcs1, edge2, E2, cur2, srcs2);
    pool_f32_at<<<dim3(64, 4), 32, 0, stream>>>(x1, gid, N1, P0);

    // ---- layers ----
    for (int l = 0; l < 4; ++l) {
        float* ssl = ss + (size_t)l * 4096;   // [0]=b1 gather, [1]=b1 W2, [2]=b2 gather, [3]=b2 W2
        float* PLl = PL + (size_t)l * 65536;
        if (l == 0) {
            // layer 0: gather on the narrow inputs first (A@(X@W1) == (A@X)@W1),
            // then W1 GEMM with fused BN stats (replaces gather-on-Y + bn_stats2)
            gather2_l0<<<N1 + N2, 64, 0, stream>>>(
                (const u16x4*)x1b, offs1, srcs1, (u16x4*)Tx1, N1,
                (const u16x4*)x2b, offs2, srcs2, (u16x4*)Tx2, epsv);
            gemm_dual<<<dim3(192, 4), 256, 0, stream>>>(
                128,
                Tx1, w1t1_0, 128, T1b, ssl + 0 * 1024,
                Tx2, w1t2_0, 64,  T2b, ssl + 2 * 1024);
        } else {
            // W1 GEMMs, both branches, one dispatch
            gemm_dual<<<dim3(192, 4), 256, 0, stream>>>(
                128,
                H1b, w1t1_r + (size_t)(l - 1) * 512 * 1024, 1024, Y1b, nullptr,
                H2b, w1t2_r + (size_t)(l - 1) * 512 * 512,  512,  Y2b, nullptr);
            // both gathers in one dispatch (no stats fusion - round-7 lesson)
            gather2_bf16<<<N1 + N2, 128, 0, stream>>>(
                (const u16x4*)Y1b, offs1, srcs1, (u16x4*)T1b, N1,
                (const u16x4*)Y2b, offs2, srcs2, (u16x4*)T2b, epsv, l);
            // BN stats for both gather outputs
            bn_stats2<<<768, 128, 0, stream>>>(512, (const u16x4*)T1b, ssl + 0 * 1024,
                                               (const u16x4*)T2b, ssl + 2 * 1024);
        }
        // mid BN apply, both branches
        bn_apply_mid<<<1536, 128, 0, stream>>>(
            1024,
            (const u16x4*)T1b, N1, ssl + 0 * 1024, m1bng + l * 512, m1bnb + l * 512, U1b,
            (const u16x4*)T2b, N2, ssl + 2 * 1024, m2bng + l * 512, m2bnb + l * 512, U2b);
        // W2 GEMMs with fused column stats, both branches
        gemm_dual<<<dim3(192, 4), 256, 0, stream>>>(
            128,
            U1b, w2t1 + (size_t)l * 512 * 512, 512, Y1b, ssl + 1 * 1024,
            U2b, w2t2 + (size_t)l * 512 * 512, 512, Y2b, ssl + 3 * 1024);
        // branch-2 final apply -> H2b + fused-transposed H2t
        bn_apply_b2t<<<512, 128, 0, stream>>>(
            (const u16x4*)Y2b, N2, ssl + 3 * 1024, bn2g + l * 512, bn2b + l * 512, H2b, H2t);
        // fusion: h2A = motif2A^T @ h2 (split-K partials, XCD-L2-swizzled)
        gemm_splitk<<<dim3(64, 4, KS), 256, 0, stream>>>(motifT, H2t, N1, 512, 4096, Cpart);
        // finale: branch-1 apply*a0 + pool (job0) || sumk*a1 + pool (job1)
        finale<<<2048, 128, 0, stream>>>(
            1024, gid, aDev, PLl, H1b,
            (const u16x4*)Y1b, ssl + 1 * 1024, bn1g + l * 512, bn1b + l * 512,
            (const f32x4*)Cpart, KS);
    }

    score_kernel<<<64, 256, 0, stream>>>(P0, PL, pW0, pb0, pW, pb, out);
}

// Round 10
// 902.761 us; speedup vs baseline: 1.7891x; 1.0152x over previous
//
#include <hip/hip_runtime.h>

// ---------------------------------------------------------------------------
// types & helpers
// ---------------------------------------------------------------------------
using bf16x8 = __attribute__((ext_vector_type(8))) short;
using f32x4  = __attribute__((ext_vector_type(4))) float;
using u16x4  = __attribute__((ext_vector_type(4))) unsigned short;
using u16x8  = __attribute__((ext_vector_type(8))) unsigned short;
using as3_void  = __attribute__((address_space(3))) void;
using as1_cvoid = const __attribute__((address_space(1))) void;

__device__ __forceinline__ unsigned short f2bf(float x) {
    union { float f; unsigned u; } v; v.f = x;
    unsigned r = v.u + 0x7FFFu + ((v.u >> 16) & 1u);   // RNE
    return (unsigned short)(r >> 16);
}
__device__ __forceinline__ float bf2f(unsigned short h) {
    union { unsigned u; float f; } v; v.u = ((unsigned)h) << 16;
    return v.f;
}

// XCD swizzle: consecutive HW ids round-robin the 8 XCDs; remap so each XCD
// owns contiguous row-panels with the 4 col-blocks adjacent (A-panel L2 reuse).
// Requires total % 8 == 0 (768 and 256 here). col = swz & 3 (4 col-blocks).
__device__ __forceinline__ void xcd_remap(int& bx, int& n0) {
    int flat  = blockIdx.x + gridDim.x * blockIdx.y;
    int total = gridDim.x * gridDim.y;
    int swz   = (flat & 7) * (total >> 3) + (flat >> 3);
    bx = swz >> 2;
    n0 = (swz & 3) * 128;
}

// ---------------------------------------------------------------------------
// GEMM tile body: BM x 128, BK=64, 4 waves (2x2). LDS XOR-swizzle applied on
// the GLOBAL source (global_load_lds needs linear dest); ds_read re-applies it.
// ---------------------------------------------------------------------------
#define GEMM_BODY(BM, A, Bt, K, KBEG, KEND)                                          \
    constexpr int WROWS = (BM) / 2;                                                  \
    constexpr int MI = WROWS / 16;                                                   \
    __shared__ __align__(16) unsigned short As[(BM) * 64];                           \
    __shared__ __align__(16) unsigned short Bs[128 * 64];                            \
    const int tid  = threadIdx.x;                                                    \
    const int lane = tid & 63, wave = tid >> 6;                                      \
    const int wr = wave >> 1, wc = wave & 1;                                         \
    const int rl = lane & 15, kg = lane >> 4;                                        \
    f32x4 acc[MI][4] = {};                                                           \
    for (int kt = (KBEG); kt < (KEND); kt += 64) {                                   \
        _Pragma("unroll")                                                            \
        for (int it = 0; it < (BM) / 32; ++it) {                                     \
            int slot = it * 256 + tid;                                               \
            int r = slot >> 3, c = slot & 7;                                         \
            int cg = c ^ (r & 7);                                                    \
            const unsigned short* ga = (A) + (size_t)(m0 + r) * (K) + (kt + cg * 8); \
            __builtin_amdgcn_global_load_lds((as1_cvoid*)ga, (as3_void*)(As + slot * 8), 16, 0, 0); \
        }                                                                            \
        _Pragma("unroll")                                                            \
        for (int it = 0; it < 4; ++it) {                                             \
            int slot = it * 256 + tid;                                               \
            int r = slot >> 3, c = slot & 7;                                         \
            int cg = c ^ (r & 7);                                                    \
            const unsigned short* gb = (Bt) + (size_t)(n0 + r) * (K) + (kt + cg * 8);\
            __builtin_amdgcn_global_load_lds((as1_cvoid*)gb, (as3_void*)(Bs + slot * 8), 16, 0, 0); \
        }                                                                            \
        __syncthreads();                                                             \
        _Pragma("unroll")                                                            \
        for (int kh = 0; kh < 2; ++kh) {                                             \
            bf16x8 a_[MI], b_[4];                                                    \
            _Pragma("unroll")                                                        \
            for (int i = 0; i < MI; ++i) {                                           \
                int ra = wr * WROWS + i * 16 + rl;                                   \
                int ca = (kh * 4 + kg) ^ (ra & 7);                                   \
                a_[i] = *reinterpret_cast<const bf16x8*>(&As[ra * 64 + ca * 8]);     \
            }                                                                        \
            _Pragma("unroll")                                                        \
            for (int j = 0; j < 4; ++j) {                                            \
                int rb = wc * 64 + j * 16 + rl;                                      \
                int cb = (kh * 4 + kg) ^ (rb & 7);                                   \
                b_[j] = *reinterpret_cast<const bf16x8*>(&Bs[rb * 64 + cb * 8]);     \
            }                                                                        \
            _Pragma("unroll")                                                        \
            for (int i = 0; i < MI; ++i)                                             \
                _Pragma("unroll")                                                    \
                for (int j = 0; j < 4; ++j)                                          \
                    acc[i][j] = __builtin_amdgcn_mfma_f32_16x16x32_bf16(a_[i], b_[j], acc[i][j], 0, 0, 0); \
        }                                                                            \
        __syncthreads();                                                             \
    }

// ---------------------------------------------------------------------------
// dual-job GEMM (BM=64): job-split over row-blocks after XCD remap. bf16 out,
// optional fused BN column stats (sum/sumsq atomicAdd into statp[1024]).
// ---------------------------------------------------------------------------
__global__ __launch_bounds__(256) void gemm_dual(
    int nb0,
    const unsigned short* __restrict__ A0, const unsigned short* __restrict__ B0,
    int K0, unsigned short* __restrict__ C0, float* __restrict__ st0,
    const unsigned short* __restrict__ A1, const unsigned short* __restrict__ B1,
    int K1, unsigned short* __restrict__ C1, float* __restrict__ st1)
{
    int bx, n0;
    xcd_remap(bx, n0);
    const unsigned short *A, *Bt; unsigned short* Cb; float* statp;
    int K;
    if (bx < nb0) { A = A0; Bt = B0; K = K0; Cb = C0; statp = st0; }
    else { bx -= nb0; A = A1; Bt = B1; K = K1; Cb = C1; statp = st1; }
    const int m0 = bx * 64;

    GEMM_BODY(64, A, Bt, K, 0, K)

#pragma unroll
    for (int i = 0; i < MI; ++i)
#pragma unroll
        for (int j = 0; j < 4; ++j)
#pragma unroll
            for (int e = 0; e < 4; ++e) {
                int rr = m0 + wr * WROWS + i * 16 + kg * 4 + e;
                int cc = n0 + wc * 64 + j * 16 + rl;
                Cb[(size_t)rr * 512 + cc] = f2bf(acc[i][j][e]);
            }
    if (statp) {
#pragma unroll
        for (int j = 0; j < 4; ++j) {
            float s = 0.f, q = 0.f;
#pragma unroll
            for (int i = 0; i < MI; ++i)
#pragma unroll
                for (int e = 0; e < 4; ++e) {
                    float x = acc[i][j][e];
                    s += x; q += x * x;
                }
            s += __shfl_xor(s, 16); s += __shfl_xor(s, 32);
            q += __shfl_xor(q, 16); q += __shfl_xor(q, 32);
            if (kg == 0) {
                int cc = n0 + wc * 64 + j * 16 + rl;
                atomicAdd(&statp[cc], s);
                atomicAdd(&statp[512 + cc], q);
            }
        }
    }
}

// ---------------------------------------------------------------------------
// fusion GEMM (BM=128), split-K over grid.z: f32 partials. XCD remap gives
// A-panel L2 reuse across the 4 column blocks (A = 64 MB motifT).
// ---------------------------------------------------------------------------
__global__ __launch_bounds__(256) void gemm_splitk(
    const unsigned short* __restrict__ A, const unsigned short* __restrict__ Bt,
    int M, int N, int K, float* __restrict__ Cp)
{
    int bx, n0;
    xcd_remap(bx, n0);
    const int m0 = bx * 128;
    const int kn = K / gridDim.z, kbeg = blockIdx.z * kn;

    GEMM_BODY(128, A, Bt, K, kbeg, kbeg + kn)

    float* dst = Cp + (size_t)blockIdx.z * M * N;
#pragma unroll
    for (int i = 0; i < MI; ++i)
#pragma unroll
        for (int j = 0; j < 4; ++j)
#pragma unroll
            for (int e = 0; e < 4; ++e) {
                int rr = m0 + wr * WROWS + i * 16 + kg * 4 + e;
                int cc = n0 + wc * 64 + j * 16 + rl;
                dst[(size_t)rr * N + cc] = acc[i][j][e];
            }
}

// ---------------------------------------------------------------------------
// CSR build
// ---------------------------------------------------------------------------
__global__ void csr_count2(const int* __restrict__ e1, int E1, int* __restrict__ c1,
                           const int* __restrict__ e2, int E2, int* __restrict__ c2) {
    int i = blockIdx.x * 256 + threadIdx.x;
    if (i < E1) atomicAdd(&c1[e1[i]], 1);
    else if (i < E1 + E2) atomicAdd(&c2[e2[i - E1]], 1);
}

__global__ void csr_scan2(const int* __restrict__ cnt1, int n1, int* __restrict__ offs1, int* __restrict__ cur1,
                          const int* __restrict__ cnt2, int n2, int* __restrict__ offs2, int* __restrict__ cur2) {
    const int* cnt = blockIdx.x ? cnt2 : cnt1;
    int n           = blockIdx.x ? n2 : n1;
    int* offs       = blockIdx.x ? offs2 : offs1;
    int* cursor     = blockIdx.x ? cur2 : cur1;
    __shared__ int part[1024];
    int t = threadIdx.x;
    int per = n >> 10;
    int base = t * per;
    int loc[8];
    int s = 0;
    for (int j = 0; j < per; ++j) { loc[j] = s; s += cnt[base + j]; }
    part[t] = s;
    __syncthreads();
    for (int o = 1; o < 1024; o <<= 1) {
        int v = (t >= o) ? part[t - o] : 0;
        __syncthreads();
        part[t] += v;
        __syncthreads();
    }
    int excl = (t == 0) ? 0 : part[t - 1];
    for (int j = 0; j < per; ++j) {
        int v = excl + loc[j];
        offs[base + j] = v;
        cursor[base + j] = v;
    }
    if (t == 1023) offs[n] = part[1023];
}

__global__ void csr_fill2(const int* __restrict__ e1, int E1, int* __restrict__ cur1, int* __restrict__ s1,
                          const int* __restrict__ e2, int E2, int* __restrict__ cur2, int* __restrict__ s2) {
    int i = blockIdx.x * 256 + threadIdx.x;
    if (i < E1) {
        int d = e1[i], s = e1[E1 + i];
        s1[atomicAdd(&cur1[d], 1)] = s;
    } else if (i < E1 + E2) {
        int e = i - E1;
        int d = e2[e], s = e2[E2 + e];
        s2[atomicAdd(&cur2[d], 1)] = s;
    }
}

// ---------------------------------------------------------------------------
// gather for BOTH branches in one dispatch (512 cols, one block per row).
// NO fused stats: 12.6M global atomics cost 170 us/dispatch (round-7 lesson).
// ---------------------------------------------------------------------------
__global__ __launch_bounds__(128) void gather2_bf16(
    const u16x4* __restrict__ Y1, const int* __restrict__ offs1, const int* __restrict__ srcs1,
    u16x4* __restrict__ T1, int n1,
    const u16x4* __restrict__ Y2, const int* __restrict__ offs2, const int* __restrict__ srcs2,
    u16x4* __restrict__ T2,
    const float* __restrict__ epsv, int l)
{
    int i = blockIdx.x;
    const u16x4* Y; u16x4* T; const int *offs, *srcs;
    if (i < n1) { Y = Y1; T = T1; offs = offs1; srcs = srcs1; }
    else        { i -= n1; Y = Y2; T = T2; offs = offs2; srcs = srcs2; }
    int c = threadIdx.x;
    float e = 1.0f + epsv[l];
    int lo = offs[i], hi = offs[i + 1];
    u16x4 hv = Y[(size_t)i * 128 + c];
    f32x4 a0, a1 = {}, a2 = {}, a3 = {};
#pragma unroll
    for (int j = 0; j < 4; ++j) a0[j] = e * bf2f(hv[j]);
    int k = lo;
    for (; k + 4 <= hi; k += 4) {
        int s0 = srcs[k], s1 = srcs[k + 1], s2 = srcs[k + 2], s3 = srcs[k + 3];
        u16x4 v0 = Y[(size_t)s0 * 128 + c];
        u16x4 v1 = Y[(size_t)s1 * 128 + c];
        u16x4 v2 = Y[(size_t)s2 * 128 + c];
        u16x4 v3 = Y[(size_t)s3 * 128 + c];
#pragma unroll
        for (int j = 0; j < 4; ++j) {
            a0[j] += bf2f(v0[j]); a1[j] += bf2f(v1[j]);
            a2[j] += bf2f(v2[j]); a3[j] += bf2f(v3[j]);
        }
    }
    for (; k < hi; ++k) {
        u16x4 v = Y[(size_t)srcs[k] * 128 + c];
#pragma unroll
        for (int j = 0; j < 4; ++j) a0[j] += bf2f(v[j]);
    }
    f32x4 acc = (a0 + a1) + (a2 + a3);
    u16x4 o;
#pragma unroll
    for (int j = 0; j < 4; ++j) o[j] = f2bf(acc[j]);
    T[(size_t)i * 128 + c] = o;
}

// ---------------------------------------------------------------------------
// layer-0 gather on the NARROW inputs (branch1: 128 cols, branch2: 64 cols).
// By linearity A@(X@W1) == (A@X)@W1, so gathering before the W1 GEMM cuts
// gather traffic 4x at layer 0. One wave per row.
// ---------------------------------------------------------------------------
__global__ __launch_bounds__(64) void gather2_l0(
    const u16x4* __restrict__ X1, const int* __restrict__ offs1, const int* __restrict__ srcs1,
    u16x4* __restrict__ T1, int n1,
    const u16x4* __restrict__ X2, const int* __restrict__ offs2, const int* __restrict__ srcs2,
    u16x4* __restrict__ T2,
    const float* __restrict__ epsv)
{
    int i = blockIdx.x;
    const u16x4* X; u16x4* T; const int *offs, *srcs; int nc4;
    if (i < n1) { X = X1; T = T1; offs = offs1; srcs = srcs1; nc4 = 32; }
    else        { i -= n1; X = X2; T = T2; offs = offs2; srcs = srcs2; nc4 = 16; }
    int c = threadIdx.x;
    if (c >= nc4) return;
    float e = 1.0f + epsv[0];
    int lo = offs[i], hi = offs[i + 1];
    u16x4 hv = X[(size_t)i * nc4 + c];
    f32x4 a0, a1 = {}, a2 = {}, a3 = {};
#pragma unroll
    for (int j = 0; j < 4; ++j) a0[j] = e * bf2f(hv[j]);
    int k = lo;
    for (; k + 4 <= hi; k += 4) {
        int s0 = srcs[k], s1 = srcs[k + 1], s2 = srcs[k + 2], s3 = srcs[k + 3];
        u16x4 v0 = X[(size_t)s0 * nc4 + c];
        u16x4 v1 = X[(size_t)s1 * nc4 + c];
        u16x4 v2 = X[(size_t)s2 * nc4 + c];
        u16x4 v3 = X[(size_t)s3 * nc4 + c];
#pragma unroll
        for (int j = 0; j < 4; ++j) {
            a0[j] += bf2f(v0[j]); a1[j] += bf2f(v1[j]);
            a2[j] += bf2f(v2[j]); a3[j] += bf2f(v3[j]);
        }
    }
    for (; k < hi; ++k) {
        u16x4 v = X[(size_t)srcs[k] * nc4 + c];
#pragma unroll
        for (int j = 0; j < 4; ++j) a0[j] += bf2f(v[j]);
    }
    f32x4 acc = (a0 + a1) + (a2 + a3);
    u16x4 o;
#pragma unroll
    for (int j = 0; j < 4; ++j) o[j] = f2bf(acc[j]);
    T[(size_t)i * nc4 + c] = o;
}

// ---------------------------------------------------------------------------
// dual column sum/sumsq over bf16 [M][512]: job0 = 512 blocks x16 rows,
// job1 = 256 blocks x16 rows. ~786K atomics total - cheap (round-6 evidence).
// ---------------------------------------------------------------------------
__global__ void bn_stats2(int nb0,
                          const u16x4* __restrict__ X0, float* __restrict__ ss0,
                          const u16x4* __restrict__ X1, float* __restrict__ ss1) {
    int bx = blockIdx.x;
    const u16x4* X; float* ss;
    if (bx < nb0) { X = X0; ss = ss0; }
    else { bx -= nb0; X = X1; ss = ss1; }
    int c = threadIdx.x;
    int r0 = bx * 16;
    f32x4 s = {}, q = {};
    for (int r = 0; r < 16; ++r) {
        u16x4 v = X[(size_t)(r0 + r) * 128 + c];
        f32x4 f;
#pragma unroll
        for (int j = 0; j < 4; ++j) f[j] = bf2f(v[j]);
        s += f; q += f * f;
    }
#pragma unroll
    for (int j = 0; j < 4; ++j) {
        atomicAdd(&ss[c * 4 + j], s[j]);
        atomicAdd(&ss[512 + c * 4 + j], q[j]);
    }
}

// ---------------------------------------------------------------------------
// dual mid BN apply -> U buffers
// ---------------------------------------------------------------------------
__global__ __launch_bounds__(128) void bn_apply_mid(
    int nb0,
    const u16x4* __restrict__ X0, int M0, const float* __restrict__ ss0,
    const float* __restrict__ g0, const float* __restrict__ b0, unsigned short* __restrict__ o0,
    const u16x4* __restrict__ X1, int M1, const float* __restrict__ ss1,
    const float* __restrict__ g1, const float* __restrict__ b1, unsigned short* __restrict__ o1)
{
    int bx = blockIdx.x;
    const u16x4* X; const float *ss, *g, *b; unsigned short* out; int M;
    if (bx < nb0) { X = X0; M = M0; ss = ss0; g = g0; b = b0; out = o0; }
    else { bx -= nb0; X = X1; M = M1; ss = ss1; g = g1; b = b1; out = o1; }
    int c = threadIdx.x;
    float inv = 1.0f / (float)M;
    float al[4], be[4];
#pragma unroll
    for (int i = 0; i < 4; ++i) {
        float mean = ss[c * 4 + i] * inv;
        float var  = ss[512 + c * 4 + i] * inv - mean * mean;
        al[i] = g[c * 4 + i] * rsqrtf(var + 1e-5f);
        be[i] = b[c * 4 + i] - mean * al[i];
    }
    int r0 = bx * 8;
    for (int r = 0; r < 8; ++r) {
        u16x4 v = X[(size_t)(r0 + r) * 128 + c];
        u16x4 h;
#pragma unroll
        for (int i = 0; i < 4; ++i)
            h[i] = f2bf(fmaxf(al[i] * bf2f(v[i]) + be[i], 0.f));
        *reinterpret_cast<u16x4*>(out + (size_t)(r0 + r) * 512 + c * 4) = h;
    }
}

// ---------------------------------------------------------------------------
// branch-2 final BN apply -> H2b [4096][512] AND (optionally) H2t [512][4096]
// (fused transpose: 8 rows/block => one 16B store per column)
// ---------------------------------------------------------------------------
__global__ __launch_bounds__(128) void bn_apply_b2t(
    const u16x4* __restrict__ X, int M, const float* __restrict__ ss,
    const float* __restrict__ g, const float* __restrict__ b,
    unsigned short* __restrict__ out, unsigned short* __restrict__ outT)
{
    int c = threadIdx.x;
    float inv = 1.0f / (float)M;
    float al[4], be[4];
#pragma unroll
    for (int i = 0; i < 4; ++i) {
        float mean = ss[c * 4 + i] * inv;
        float var  = ss[512 + c * 4 + i] * inv - mean * mean;
        al[i] = g[c * 4 + i] * rsqrtf(var + 1e-5f);
        be[i] = b[c * 4 + i] - mean * al[i];
    }
    int r0 = blockIdx.x * 8;
    u16x8 t8[4];
#pragma unroll
    for (int r = 0; r < 8; ++r) {
        u16x4 v = X[(size_t)(r0 + r) * 128 + c];
        u16x4 h;
#pragma unroll
        for (int i = 0; i < 4; ++i) {
            h[i] = f2bf(fmaxf(al[i] * bf2f(v[i]) + be[i], 0.f));
            t8[i][r] = h[i];
        }
        *reinterpret_cast<u16x4*>(out + (size_t)(r0 + r) * 512 + c * 4) = h;
    }
    if (outT) {
#pragma unroll
        for (int i = 0; i < 4; ++i)
            *reinterpret_cast<u16x8*>(outT + (size_t)(c * 4 + i) * 4096 + r0) = t8[i];
    }
}

// ---------------------------------------------------------------------------
// finale: job0 (blocks < nb0) = branch-1 final BN apply * a0 -> H1b[:, :512]
//         + JK pool; job1 = sum KS split-K partials * a1 -> H1b[:, 512:]
//         + JK pool. gid sorted; pool pre-zeroed. (at l=3 only job0 runs)
// ---------------------------------------------------------------------------
__global__ __launch_bounds__(128) void finale(
    int nb0, const int* __restrict__ gid, const float* __restrict__ aDev,
    float* __restrict__ pool, unsigned short* __restrict__ H1,
    const u16x4* __restrict__ X, const float* __restrict__ ss,
    const float* __restrict__ g, const float* __restrict__ b,
    const f32x4* __restrict__ P, int ks)
{
    int bx = blockIdx.x;
    int c = threadIdx.x;
    int job = bx >= nb0;
    if (job) bx -= nb0;
    int r0 = bx * 8;
    int ooff = job ? 512 : 0;
    float al[4], be[4];
    float sc;
    if (!job) {
        sc = aDev[0];
        float inv = 1.0f / 8192.0f;
#pragma unroll
        for (int i = 0; i < 4; ++i) {
            float mean = ss[c * 4 + i] * inv;
            float var  = ss[512 + c * 4 + i] * inv - mean * mean;
            al[i] = g[c * 4 + i] * rsqrtf(var + 1e-5f);
            be[i] = b[c * 4 + i] - mean * al[i];
        }
    } else {
        sc = aDev[1];
    }
    const int total4 = 8192 * 128;
    int curg = gid[r0];
    f32x4 pacc = {};
    for (int r = 0; r < 8; ++r) {
        int row = r0 + r;
        u16x4 h;
        f32x4 f;
        if (!job) {
            u16x4 v = X[(size_t)row * 128 + c];
#pragma unroll
            for (int i = 0; i < 4; ++i) {
                h[i] = f2bf(fmaxf(al[i] * bf2f(v[i]) + be[i], 0.f) * sc);
                f[i] = bf2f(h[i]);
            }
        } else {
            f32x4 s = P[(size_t)row * 128 + c];
            for (int z = 1; z < ks; ++z) s += P[(size_t)z * total4 + (size_t)row * 128 + c];
#pragma unroll
            for (int i = 0; i < 4; ++i) { h[i] = f2bf(s[i] * sc); f[i] = bf2f(h[i]); }
        }
        *reinterpret_cast<u16x4*>(H1 + (size_t)row * 1024 + ooff + c * 4) = h;
        int gg = gid[row];
        if (gg != curg) {
#pragma unroll
            for (int j = 0; j < 4; ++j)
                atomicAdd(&pool[(size_t)curg * 1024 + ooff + c * 4 + j], pacc[j]);
            pacc = {}; curg = gg;
        }
        pacc += f;
    }
#pragma unroll
    for (int j = 0; j < 4; ++j)
        atomicAdd(&pool[(size_t)curg * 1024 + ooff + c * 4 + j], pacc[j]);
}

// contiguous f32 -> bf16 convert, two tensors in one dispatch
__global__ void cvt2_bf16(const f32x4* __restrict__ X0, u16x4* __restrict__ O0, int n0,
                          const f32x4* __restrict__ X1, u16x4* __restrict__ O1, int n1) {
    for (int i = blockIdx.x * blockDim.x + threadIdx.x; i < n0 + n1; i += gridDim.x * blockDim.x) {
        const f32x4* X; u16x4* O; int k;
        if (i < n0) { X = X0; O = O0; k = i; }
        else { X = X1; O = O1; k = i - n0; }
        f32x4 v = X[k];
        u16x4 h;
#pragma unroll
        for (int j = 0; j < 4; ++j) h[j] = f2bf(v[j]);
        O[k] = h;
    }
}

// ---------------------------------------------------------------------------
// motif transpose: S f32 [4096][8192] -> D bf16 [8192][4096], 64x64 tiles
// ---------------------------------------------------------------------------
__global__ __launch_bounds__(256) void motif_transpose(const float* __restrict__ S,
                                                       unsigned short* __restrict__ D) {
    __shared__ unsigned short tile[64][66];
    int m0 = blockIdx.x * 64;
    int k0 = blockIdx.y * 64;
    int t = threadIdx.x;
    int r = t >> 4, cq = t & 15;
#pragma unroll
    for (int p = 0; p < 4; ++p) {
        int row = r + p * 16;
        f32x4 v = *reinterpret_cast<const f32x4*>(S + (size_t)(k0 + row) * 8192 + m0 + cq * 4);
        u16x4 h;
#pragma unroll
        for (int j = 0; j < 4; ++j) h[j] = f2bf(v[j]);
        *reinterpret_cast<u16x4*>(&tile[row][cq * 4]) = h;
    }
    __syncthreads();
#pragma unroll
    for (int p = 0; p < 4; ++p) {
        int col = r + p * 16;
        u16x4 h;
#pragma unroll
        for (int i = 0; i < 4; ++i) h[i] = tile[cq * 4 + i][col];
        *reinterpret_cast<u16x4*>(D + (size_t)(m0 + col) * 4096 + k0 + cq * 4) = h;
    }
}

// ---------------------------------------------------------------------------
// small transposes (weights), batched
// ---------------------------------------------------------------------------
__global__ void transpose_cvt_b(const float* __restrict__ S, unsigned short* __restrict__ D,
                                int rows, int cols, size_t sstride, size_t dstride) {
    S += blockIdx.z * sstride; D += blockIdx.z * dstride;
    __shared__ unsigned short tile[32][33];
    int x0 = blockIdx.x * 32, y0 = blockIdx.y * 32;
    for (int j = threadIdx.y; j < 32; j += blockDim.y)
        tile[j][threadIdx.x] = f2bf(S[(size_t)(y0 + j) * cols + x0 + threadIdx.x]);
    __syncthreads();
    for (int j = threadIdx.y; j < 32; j += blockDim.y)
        D[(size_t)(x0 + j) * rows + y0 + threadIdx.x] = tile[threadIdx.x][j];
}

// 11 square 512x512 weights in one launch
__global__ void transpose_cvt11(const float* __restrict__ A, unsigned short* __restrict__ Ad,
                                const float* __restrict__ B, unsigned short* __restrict__ Bd,
                                const float* __restrict__ Cs, unsigned short* __restrict__ Cd) {
    int z = blockIdx.z;
    const float* S; unsigned short* D;
    if (z < 4)      { S = A  + (size_t)z * 262144;       D = Ad + (size_t)z * 262144; }
    else if (z < 7) { S = B  + (size_t)(z - 4) * 262144; D = Bd + (size_t)(z - 4) * 262144; }
    else            { S = Cs + (size_t)(z - 7) * 262144; D = Cd + (size_t)(z - 7) * 262144; }
    __shared__ unsigned short tile[32][33];
    int x0 = blockIdx.x * 32, y0 = blockIdx.y * 32;
    for (int j = threadIdx.y; j < 32; j += blockDim.y)
        tile[j][threadIdx.x] = f2bf(S[(size_t)(y0 + j) * 512 + x0 + threadIdx.x]);
    __syncthreads();
    for (int j = threadIdx.y; j < 32; j += blockDim.y)
        D[(size_t)(x0 + j) * 512 + y0 + threadIdx.x] = tile[threadIdx.x][j];
}

// ---------------------------------------------------------------------------
// graph pooling helpers (gid sorted)
// ---------------------------------------------------------------------------
__device__ __forceinline__ int lbound(const int* __restrict__ a, int n, int v) {
    int lo = 0, hi = n;
    while (lo < hi) { int m = (lo + hi) >> 1; if (a[m] < v) lo = m + 1; else hi = m; }
    return lo;
}

__global__ void pool_f32_at(const float* __restrict__ Hm, const int* __restrict__ gid,
                            int n, float* __restrict__ P) {
    int g = blockIdx.x;
    int lo = lbound(gid, n, g), hi = lbound(gid, n, g + 1);
    int cnt = hi - lo;
    int per = (cnt + 3) >> 2;
    int s = lo + blockIdx.y * per;
    int e = min(s + per, hi);
    if (s >= e) return;
    int c = threadIdx.x;
    f32x4 acc = {};
    for (int i = s; i < e; ++i)
        acc += *reinterpret_cast<const f32x4*>(Hm + (size_t)i * 128 + c * 4);
#pragma unroll
    for (int j = 0; j < 4; ++j)
        atomicAdd(&P[(size_t)g * 128 + c * 4 + j], acc[j]);
}

// Pm[g, :] = sum over rows i of graph g of motifT[i, :]   (one-time setup)
// grid (64, 8): block = (graph, 512-col chunk); 128 threads x u16x4.
__global__ __launch_bounds__(128) void pool_pm(const u16x4* __restrict__ Mt,
                                               const int* __restrict__ gid,
                                               float* __restrict__ Pm) {
    int g = blockIdx.x;
    int lo = lbound(gid, 8192, g), hi = lbound(gid, 8192, g + 1);
    int c = blockIdx.y * 128 + threadIdx.x;        // u16x4 index (0..1023)
    f32x4 acc = {};
    for (int i = lo; i < hi; ++i) {
        u16x4 v = Mt[(size_t)i * 1024 + c];
#pragma unroll
        for (int j = 0; j < 4; ++j) acc[j] += bf2f(v[j]);
    }
    *reinterpret_cast<f32x4*>(Pm + (size_t)g * 4096 + (size_t)c * 4) = acc;
}

// V[k, o] = a1 * sum_c H2b[k, c] * Wb[c, o]   (tiny: 4096x10, K=512)
// grid 1024 x 256 threads: wave w handles row k = bx*4 + w.
__global__ __launch_bounds__(256) void v_kernel(
    const unsigned short* __restrict__ H2, const float* __restrict__ Wb,
    const float* __restrict__ aDev, float* __restrict__ V) {
    int w = threadIdx.x >> 6, l = threadIdx.x & 63;
    int k = blockIdx.x * 4 + w;
    float part[10];
#pragma unroll
    for (int o = 0; o < 10; ++o) part[o] = 0.f;
    for (int c = l; c < 512; c += 64) {
        float v = bf2f(H2[(size_t)k * 512 + c]);
#pragma unroll
        for (int o = 0; o < 10; ++o) part[o] += v * Wb[c * 10 + o];
    }
    float a1 = aDev[1];
#pragma unroll
    for (int o = 0; o < 10; ++o) {
        float v = part[o];
        for (int off = 32; off; off >>= 1) v += __shfl_down(v, off, 64);
        if (l == 0) V[(size_t)k * 10 + o] = a1 * v;
    }
}

__global__ void softmax2(const float* __restrict__ atts, float* __restrict__ a) {
    if (threadIdx.x == 0) {
        float m = fmaxf(atts[0], atts[1]);
        float e0 = expf(atts[0] - m), e1 = expf(atts[1] - m);
        float inv = 1.0f / (e0 + e1);
        a[0] = e0 * inv; a[1] = e1 * inv;
    }
}

// score[g,o] = P0[g]@W0 + b0 + sum_l PL[l][g]@W[l] + b[l] + Pm[g]@V
// (Pm@V carries layer-4's h2A-half contribution; PL[3][512:] stays zero)
__global__ __launch_bounds__(256) void score_kernel(
    const float* __restrict__ P0, const float* __restrict__ PL,
    const float* __restrict__ W0, const float* __restrict__ b0,
    const float* __restrict__ W, const float* __restrict__ bb,
    const float* __restrict__ Pm, const float* __restrict__ V,
    float* __restrict__ out)
{
    int g = blockIdx.x;
    int t = threadIdx.x;
    float part[10];
#pragma unroll
    for (int o = 0; o < 10; ++o) part[o] = 0.f;
    if (t < 128) {
        float p = P0[g * 128 + t];
#pragma unroll
        for (int o = 0; o < 10; ++o) part[o] += p * W0[t * 10 + o];
    }
    for (int l = 0; l < 4; ++l) {
        const float* p = PL + (size_t)l * 65536 + (size_t)g * 1024;
        const float* w = W + (size_t)l * 10240;
        for (int k = t; k < 1024; k += 256) {
            float pv = p[k];
#pragma unroll
            for (int o = 0; o < 10; ++o) part[o] += pv * w[k * 10 + o];
        }
    }
    for (int k = t; k < 4096; k += 256) {
        float pv = Pm[(size_t)g * 4096 + k];
#pragma unroll
        for (int o = 0; o < 10; ++o) part[o] += pv * V[(size_t)k * 10 + o];
    }
    __shared__ float red[4][10];
#pragma unroll
    for (int o = 0; o < 10; ++o) {
        float v = part[o];
        for (int off = 32; off; off >>= 1) v += __shfl_down(v, off, 64);
        if ((t & 63) == 0) red[t >> 6][o] = v;
    }
    __syncthreads();
    if (t < 10) {
        float s = b0[t] + red[0][t] + red[1][t] + red[2][t] + red[3][t];
#pragma unroll
        for (int l = 0; l < 4; ++l) s += bb[l * 10 + t];
        out[g * 10 + t] = s;
    }
}

// ---------------------------------------------------------------------------
// host orchestration
// ---------------------------------------------------------------------------
extern "C" void kernel_launch(void* const* d_in, const int* in_sizes, int n_in,
                              void* d_out, int out_size, void* d_ws, size_t ws_size,
                              hipStream_t stream) {
    const float* x1    = (const float*)d_in[0];
    const float* x2    = (const float*)d_in[1];
    const float* motif = (const float*)d_in[2];
    const int*   edge1 = (const int*)d_in[3];
    const int*   edge2 = (const int*)d_in[4];
    const int*   gid   = (const int*)d_in[5];
    const float* epsv  = (const float*)d_in[6];
    const float* atts  = (const float*)d_in[7];
    const float* m1W10 = (const float*)d_in[8];
    const float* m1W1r = (const float*)d_in[9];
    const float* m1bng = (const float*)d_in[11];
    const float* m1bnb = (const float*)d_in[12];
    const float* m1W2  = (const float*)d_in[13];
    const float* bn1g  = (const float*)d_in[15];
    const float* bn1b  = (const float*)d_in[16];
    const float* m2W10 = (const float*)d_in[17];
    const float* m2W1r = (const float*)d_in[18];
    const float* m2bng = (const float*)d_in[20];
    const float* m2bnb = (const float*)d_in[21];
    const float* m2W2  = (const float*)d_in[22];
    const float* bn2g  = (const float*)d_in[24];
    const float* bn2b  = (const float*)d_in[25];
    const float* pW0   = (const float*)d_in[26];
    const float* pb0   = (const float*)d_in[27];
    const float* pW    = (const float*)d_in[28];
    const float* pb    = (const float*)d_in[29];
    float* out = (float*)d_out;

    constexpr int N1 = 8192, N2 = 4096, E1 = 262144, E2 = 65536;

    char* base = (char*)d_ws;
    size_t off = 0;
    auto alloc = [&](size_t bytes) -> void* {
        void* p = base + off;
        off = (off + bytes + 255) & ~(size_t)255;
        return p;
    };

    // bf16 buffers
    unsigned short* motifT  = (unsigned short*)alloc((size_t)8192 * 4096 * 2);
    unsigned short* w1t1_0  = (unsigned short*)alloc((size_t)512 * 128 * 2);
    unsigned short* w1t1_r  = (unsigned short*)alloc((size_t)3 * 512 * 1024 * 2);
    unsigned short* w2t1    = (unsigned short*)alloc((size_t)4 * 512 * 512 * 2);
    unsigned short* w1t2_0  = (unsigned short*)alloc((size_t)512 * 64 * 2);
    unsigned short* w1t2_r  = (unsigned short*)alloc((size_t)3 * 512 * 512 * 2);
    unsigned short* w2t2    = (unsigned short*)alloc((size_t)4 * 512 * 512 * 2);
    unsigned short* x1b     = (unsigned short*)alloc((size_t)N1 * 128 * 2);
    unsigned short* x2b     = (unsigned short*)alloc((size_t)N2 * 64 * 2);
    unsigned short* Tx1     = (unsigned short*)alloc((size_t)N1 * 128 * 2);
    unsigned short* Tx2     = (unsigned short*)alloc((size_t)N2 * 64 * 2);
    unsigned short* H1b     = (unsigned short*)alloc((size_t)N1 * 1024 * 2);
    unsigned short* H2b     = (unsigned short*)alloc((size_t)N2 * 512 * 2);
    unsigned short* H2t     = (unsigned short*)alloc((size_t)512 * 4096 * 2);
    unsigned short* U1b     = (unsigned short*)alloc((size_t)N1 * 512 * 2);
    unsigned short* U2b     = (unsigned short*)alloc((size_t)N2 * 512 * 2);
    unsigned short* Y1b     = (unsigned short*)alloc((size_t)N1 * 512 * 2);
    unsigned short* T1b     = (unsigned short*)alloc((size_t)N1 * 512 * 2);
    unsigned short* Y2b     = (unsigned short*)alloc((size_t)N2 * 512 * 2);
    unsigned short* T2b     = (unsigned short*)alloc((size_t)N2 * 512 * 2);
    // zero-together region: cnt1 | cnt2 | ss | PL | P0
    int*   cnt1 = (int*)alloc((size_t)N1 * 4);
    int*   cnt2 = (int*)alloc((size_t)N2 * 4);
    float* ss   = (float*)alloc((size_t)16 * 1024 * 4);
    float* PL   = (float*)alloc((size_t)4 * 64 * 1024 * 4);
    float* P0   = (float*)alloc((size_t)64 * 128 * 4);
    const size_t zero_bytes = (size_t)N1 * 4 + N2 * 4 + 16 * 1024 * 4 + 4 * 64 * 1024 * 4
                            + 64 * 128 * 4;
    int*   offs1 = (int*)alloc((size_t)(N1 + 1) * 4);
    int*   offs2 = (int*)alloc((size_t)(N2 + 1) * 4);
    int*   cur1  = (int*)alloc((size_t)N1 * 4);
    int*   cur2  = (int*)alloc((size_t)N2 * 4);
    int*   srcs1 = (int*)alloc((size_t)E1 * 4);
    int*   srcs2 = (int*)alloc((size_t)E2 * 4);
    float* Pm    = (float*)alloc((size_t)64 * 4096 * 4);
    float* Vbuf  = (float*)alloc((size_t)4096 * 10 * 4);
    float* aDev  = (float*)alloc(256);

    if (off > ws_size) return;

    // split-K partials for the fusion GEMM
    const size_t part_elems = (size_t)N1 * 512;
    size_t rem = ws_size - off;
    int KS = (rem >= 4 * part_elems * 4) ? 4 : (rem >= 2 * part_elems * 4) ? 2 : 1;
    float* Cpart = (float*)(base + off);

    // ---- setup ----
    hipMemsetAsync(cnt1, 0, zero_bytes, stream);
    softmax2<<<1, 64, 0, stream>>>(atts, aDev);
    cvt2_bf16<<<512, 256, 0, stream>>>((const f32x4*)x1, (u16x4*)x1b, N1 * 128 / 4,
                                       (const f32x4*)x2, (u16x4*)x2b, N2 * 64 / 4);
    motif_transpose<<<dim3(128, 64), 256, 0, stream>>>(motif, motifT);
    pool_pm<<<dim3(64, 8), 128, 0, stream>>>((const u16x4*)motifT, gid, Pm);
    transpose_cvt_b<<<dim3(16, 4, 1), dim3(32, 8), 0, stream>>>(m1W10, w1t1_0, 128, 512, 0, 0);
    transpose_cvt_b<<<dim3(16, 32, 3), dim3(32, 8), 0, stream>>>(m1W1r, w1t1_r, 1024, 512,
                                                                 (size_t)1024 * 512, (size_t)512 * 1024);
    transpose_cvt_b<<<dim3(16, 2, 1), dim3(32, 8), 0, stream>>>(m2W10, w1t2_0, 64, 512, 0, 0);
    transpose_cvt11<<<dim3(16, 16, 11), dim3(32, 8), 0, stream>>>(m1W2, w2t1, m2W1r, w1t2_r, m2W2, w2t2);
    csr_count2<<<(E1 + E2) / 256, 256, 0, stream>>>(edge1, E1, cnt1, edge2, E2, cnt2);
    csr_scan2<<<2, 1024, 0, stream>>>(cnt1, N1, offs1, cur1, cnt2, N2, offs2, cur2);
    csr_fill2<<<(E1 + E2) / 256, 256, 0, stream>>>(edge1, E1, cur1, srcs1, edge2, E2, cur2, srcs2);
    pool_f32_at<<<dim3(64, 4), 32, 0, stream>>>(x1, gid, N1, P0);

    // ---- layers ----
    for (int l = 0; l < 4; ++l) {
        float* ssl = ss + (size_t)l * 4096;   // [0]=b1 gather, [1]=b1 W2, [2]=b2 gather, [3]=b2 W2
        float* PLl = PL + (size_t)l * 65536;
        if (l == 0) {
            // layer 0: gather on the narrow inputs first (A@(X@W1) == (A@X)@W1),
            // then W1 GEMM with fused BN stats (replaces gather-on-Y + bn_stats2)
            gather2_l0<<<N1 + N2, 64, 0, stream>>>(
                (const u16x4*)x1b, offs1, srcs1, (u16x4*)Tx1, N1,
                (const u16x4*)x2b, offs2, srcs2, (u16x4*)Tx2, epsv);
            gemm_dual<<<dim3(192, 4), 256, 0, stream>>>(
                128,
                Tx1, w1t1_0, 128, T1b, ssl + 0 * 1024,
                Tx2, w1t2_0, 64,  T2b, ssl + 2 * 1024);
        } else {
            // W1 GEMMs, both branches, one dispatch
            gemm_dual<<<dim3(192, 4), 256, 0, stream>>>(
                128,
                H1b, w1t1_r + (size_t)(l - 1) * 512 * 1024, 1024, Y1b, nullptr,
                H2b, w1t2_r + (size_t)(l - 1) * 512 * 512,  512,  Y2b, nullptr);
            // both gathers in one dispatch (no stats fusion - round-7 lesson)
            gather2_bf16<<<N1 + N2, 128, 0, stream>>>(
                (const u16x4*)Y1b, offs1, srcs1, (u16x4*)T1b, N1,
                (const u16x4*)Y2b, offs2, srcs2, (u16x4*)T2b, epsv, l);
            // BN stats for both gather outputs
            bn_stats2<<<768, 128, 0, stream>>>(512, (const u16x4*)T1b, ssl + 0 * 1024,
                                               (const u16x4*)T2b, ssl + 2 * 1024);
        }
        // mid BN apply, both branches
        bn_apply_mid<<<1536, 128, 0, stream>>>(
            1024,
            (const u16x4*)T1b, N1, ssl + 0 * 1024, m1bng + l * 512, m1bnb + l * 512, U1b,
            (const u16x4*)T2b, N2, ssl + 2 * 1024, m2bng + l * 512, m2bnb + l * 512, U2b);
        // W2 GEMMs with fused column stats, both branches
        gemm_dual<<<dim3(192, 4), 256, 0, stream>>>(
            128,
            U1b, w2t1 + (size_t)l * 512 * 512, 512, Y1b, ssl + 1 * 1024,
            U2b, w2t2 + (size_t)l * 512 * 512, 512, Y2b, ssl + 3 * 1024);
        if (l < 3) {
            // branch-2 final apply -> H2b + fused-transposed H2t
            bn_apply_b2t<<<512, 128, 0, stream>>>(
                (const u16x4*)Y2b, N2, ssl + 3 * 1024, bn2g + l * 512, bn2b + l * 512, H2b, H2t);
            // fusion: h2A = motif2A^T @ h2 (split-K partials, XCD-L2-swizzled)
            gemm_splitk<<<dim3(64, 4, KS), 256, 0, stream>>>(motifT, H2t, N1, 512, 4096, Cpart);
            // finale: branch-1 apply*a0 + pool (job0) || sumk*a1 + pool (job1)
            finale<<<2048, 128, 0, stream>>>(
                1024, gid, aDev, PLl, H1b,
                (const u16x4*)Y1b, ssl + 1 * 1024, bn1g + l * 512, bn1b + l * 512,
                (const f32x4*)Cpart, KS);
        } else {
            // last layer: hidden[4] is only pooled. h2A-half contribution to the
            // score folds to a1 * Pm @ (h2 @ predW_bot) - skip the 34 GF GEMM.
            bn_apply_b2t<<<512, 128, 0, stream>>>(
                (const u16x4*)Y2b, N2, ssl + 3 * 1024, bn2g + l * 512, bn2b + l * 512,
                H2b, nullptr);
            v_kernel<<<1024, 256, 0, stream>>>(H2b, pW + 3 * 10240 + 512 * 10, aDev, Vbuf);
            // only job0: branch-1 apply*a0 + pool (PL[3][512:] stays zero)
            finale<<<1024, 128, 0, stream>>>(
                1024, gid, aDev, PLl, H1b,
                (const u16x4*)Y1b, ssl + 1 * 1024, bn1g + l * 512, bn1b + l * 512,
                (const f32x4*)Cpart, KS);
        }
    }

    score_kernel<<<64, 256, 0, stream>>>(P0, PL, pW0, pb0, pW, pb, Pm, Vbuf, out);
}

// Round 11
// 887.102 us; speedup vs baseline: 1.8207x; 1.0177x over previous
//
#include <hip/hip_runtime.h>

// ---------------------------------------------------------------------------
// types & helpers
// ---------------------------------------------------------------------------
using bf16x8 = __attribute__((ext_vector_type(8))) short;
using f32x4  = __attribute__((ext_vector_type(4))) float;
using u16x4  = __attribute__((ext_vector_type(4))) unsigned short;
using u16x8  = __attribute__((ext_vector_type(8))) unsigned short;
using as3_void  = __attribute__((address_space(3))) void;
using as1_cvoid = const __attribute__((address_space(1))) void;

__device__ __forceinline__ unsigned short f2bf(float x) {
    union { float f; unsigned u; } v; v.f = x;
    unsigned r = v.u + 0x7FFFu + ((v.u >> 16) & 1u);   // RNE
    return (unsigned short)(r >> 16);
}
__device__ __forceinline__ float bf2f(unsigned short h) {
    union { unsigned u; float f; } v; v.u = ((unsigned)h) << 16;
    return v.f;
}

// XCD swizzle: consecutive HW ids round-robin the 8 XCDs; remap so each XCD
// owns contiguous row-panels with the 4 col-blocks adjacent (A-panel L2 reuse).
// Requires total % 8 == 0 (768 and 1024 here). col = swz & 3 (4 col-blocks).
__device__ __forceinline__ void xcd_remap(int& bx, int& n0) {
    int flat  = blockIdx.x + gridDim.x * blockIdx.y;
    int total = gridDim.x * gridDim.y;
    int swz   = (flat & 7) * (total >> 3) + (flat >> 3);
    bx = swz >> 2;
    n0 = (swz & 3) * 128;
}

// ---------------------------------------------------------------------------
// GEMM tile body: BM x 128, BK=64, 4 waves (2x2). LDS XOR-swizzle applied on
// the GLOBAL source (global_load_lds needs linear dest); ds_read re-applies it.
// ---------------------------------------------------------------------------
#define GEMM_BODY(BM, A, Bt, K, KBEG, KEND)                                          \
    constexpr int WROWS = (BM) / 2;                                                  \
    constexpr int MI = WROWS / 16;                                                   \
    __shared__ __align__(16) unsigned short As[(BM) * 64];                           \
    __shared__ __align__(16) unsigned short Bs[128 * 64];                            \
    const int tid  = threadIdx.x;                                                    \
    const int lane = tid & 63, wave = tid >> 6;                                      \
    const int wr = wave >> 1, wc = wave & 1;                                         \
    const int rl = lane & 15, kg = lane >> 4;                                        \
    f32x4 acc[MI][4] = {};                                                           \
    for (int kt = (KBEG); kt < (KEND); kt += 64) {                                   \
        _Pragma("unroll")                                                            \
        for (int it = 0; it < (BM) / 32; ++it) {                                     \
            int slot = it * 256 + tid;                                               \
            int r = slot >> 3, c = slot & 7;                                         \
            int cg = c ^ (r & 7);                                                    \
            const unsigned short* ga = (A) + (size_t)(m0 + r) * (K) + (kt + cg * 8); \
            __builtin_amdgcn_global_load_lds((as1_cvoid*)ga, (as3_void*)(As + slot * 8), 16, 0, 0); \
        }                                                                            \
        _Pragma("unroll")                                                            \
        for (int it = 0; it < 4; ++it) {                                             \
            int slot = it * 256 + tid;                                               \
            int r = slot >> 3, c = slot & 7;                                         \
            int cg = c ^ (r & 7);                                                    \
            const unsigned short* gb = (Bt) + (size_t)(n0 + r) * (K) + (kt + cg * 8);\
            __builtin_amdgcn_global_load_lds((as1_cvoid*)gb, (as3_void*)(Bs + slot * 8), 16, 0, 0); \
        }                                                                            \
        __syncthreads();                                                             \
        _Pragma("unroll")                                                            \
        for (int kh = 0; kh < 2; ++kh) {                                             \
            bf16x8 a_[MI], b_[4];                                                    \
            _Pragma("unroll")                                                        \
            for (int i = 0; i < MI; ++i) {                                           \
                int ra = wr * WROWS + i * 16 + rl;                                   \
                int ca = (kh * 4 + kg) ^ (ra & 7);                                   \
                a_[i] = *reinterpret_cast<const bf16x8*>(&As[ra * 64 + ca * 8]);     \
            }                                                                        \
            _Pragma("unroll")                                                        \
            for (int j = 0; j < 4; ++j) {                                            \
                int rb = wc * 64 + j * 16 + rl;                                      \
                int cb = (kh * 4 + kg) ^ (rb & 7);                                   \
                b_[j] = *reinterpret_cast<const bf16x8*>(&Bs[rb * 64 + cb * 8]);     \
            }                                                                        \
            _Pragma("unroll")                                                        \
            for (int i = 0; i < MI; ++i)                                             \
                _Pragma("unroll")                                                    \
                for (int j = 0; j < 4; ++j)                                          \
                    acc[i][j] = __builtin_amdgcn_mfma_f32_16x16x32_bf16(a_[i], b_[j], acc[i][j], 0, 0, 0); \
        }                                                                            \
        __syncthreads();                                                             \
    }

// ---------------------------------------------------------------------------
// dual-job GEMM (BM=64): job-split over row-blocks after XCD remap. bf16 out,
// optional fused BN column stats (sum/sumsq atomicAdd into statp[1024]).
// ---------------------------------------------------------------------------
__global__ __launch_bounds__(256) void gemm_dual(
    int nb0,
    const unsigned short* __restrict__ A0, const unsigned short* __restrict__ B0,
    int K0, unsigned short* __restrict__ C0, float* __restrict__ st0,
    const unsigned short* __restrict__ A1, const unsigned short* __restrict__ B1,
    int K1, unsigned short* __restrict__ C1, float* __restrict__ st1)
{
    int bx, n0;
    xcd_remap(bx, n0);
    const unsigned short *A, *Bt; unsigned short* Cb; float* statp;
    int K;
    if (bx < nb0) { A = A0; Bt = B0; K = K0; Cb = C0; statp = st0; }
    else { bx -= nb0; A = A1; Bt = B1; K = K1; Cb = C1; statp = st1; }
    const int m0 = bx * 64;

    GEMM_BODY(64, A, Bt, K, 0, K)

#pragma unroll
    for (int i = 0; i < MI; ++i)
#pragma unroll
        for (int j = 0; j < 4; ++j)
#pragma unroll
            for (int e = 0; e < 4; ++e) {
                int rr = m0 + wr * WROWS + i * 16 + kg * 4 + e;
                int cc = n0 + wc * 64 + j * 16 + rl;
                Cb[(size_t)rr * 512 + cc] = f2bf(acc[i][j][e]);
            }
    if (statp) {
#pragma unroll
        for (int j = 0; j < 4; ++j) {
            float s = 0.f, q = 0.f;
#pragma unroll
            for (int i = 0; i < MI; ++i)
#pragma unroll
                for (int e = 0; e < 4; ++e) {
                    float x = acc[i][j][e];
                    s += x; q += x * x;
                }
            s += __shfl_xor(s, 16); s += __shfl_xor(s, 32);
            q += __shfl_xor(q, 16); q += __shfl_xor(q, 32);
            if (kg == 0) {
                int cc = n0 + wc * 64 + j * 16 + rl;
                atomicAdd(&statp[cc], s);
                atomicAdd(&statp[512 + cc], q);
            }
        }
    }
}

// ---------------------------------------------------------------------------
// fusion GEMM (BM=128), split-K over grid.z: bf16 partials (consumer rounds
// to bf16 anyway; halves partial traffic vs f32). XCD remap -> A-panel reuse.
// ---------------------------------------------------------------------------
__global__ __launch_bounds__(256) void gemm_splitk(
    const unsigned short* __restrict__ A, const unsigned short* __restrict__ Bt,
    int M, int N, int K, unsigned short* __restrict__ Cp)
{
    int bx, n0;
    xcd_remap(bx, n0);
    const int m0 = bx * 128;
    const int kn = K / gridDim.z, kbeg = blockIdx.z * kn;

    GEMM_BODY(128, A, Bt, K, kbeg, kbeg + kn)

    unsigned short* dst = Cp + (size_t)blockIdx.z * M * N;
#pragma unroll
    for (int i = 0; i < MI; ++i)
#pragma unroll
        for (int j = 0; j < 4; ++j)
#pragma unroll
            for (int e = 0; e < 4; ++e) {
                int rr = m0 + wr * WROWS + i * 16 + kg * 4 + e;
                int cc = n0 + wc * 64 + j * 16 + rl;
                dst[(size_t)rr * N + cc] = f2bf(acc[i][j][e]);
            }
}

// ---------------------------------------------------------------------------
// CSR build
// ---------------------------------------------------------------------------
__global__ void csr_count2(const int* __restrict__ e1, int E1, int* __restrict__ c1,
                           const int* __restrict__ e2, int E2, int* __restrict__ c2) {
    int i = blockIdx.x * 256 + threadIdx.x;
    if (i < E1) atomicAdd(&c1[e1[i]], 1);
    else if (i < E1 + E2) atomicAdd(&c2[e2[i - E1]], 1);
}

__global__ void csr_scan2(const int* __restrict__ cnt1, int n1, int* __restrict__ offs1, int* __restrict__ cur1,
                          const int* __restrict__ cnt2, int n2, int* __restrict__ offs2, int* __restrict__ cur2) {
    const int* cnt = blockIdx.x ? cnt2 : cnt1;
    int n           = blockIdx.x ? n2 : n1;
    int* offs       = blockIdx.x ? offs2 : offs1;
    int* cursor     = blockIdx.x ? cur2 : cur1;
    __shared__ int part[1024];
    int t = threadIdx.x;
    int per = n >> 10;
    int base = t * per;
    int loc[8];
    int s = 0;
    for (int j = 0; j < per; ++j) { loc[j] = s; s += cnt[base + j]; }
    part[t] = s;
    __syncthreads();
    for (int o = 1; o < 1024; o <<= 1) {
        int v = (t >= o) ? part[t - o] : 0;
        __syncthreads();
        part[t] += v;
        __syncthreads();
    }
    int excl = (t == 0) ? 0 : part[t - 1];
    for (int j = 0; j < per; ++j) {
        int v = excl + loc[j];
        offs[base + j] = v;
        cursor[base + j] = v;
    }
    if (t == 1023) offs[n] = part[1023];
}

__global__ void csr_fill2(const int* __restrict__ e1, int E1, int* __restrict__ cur1, int* __restrict__ s1,
                          const int* __restrict__ e2, int E2, int* __restrict__ cur2, int* __restrict__ s2) {
    int i = blockIdx.x * 256 + threadIdx.x;
    if (i < E1) {
        int d = e1[i], s = e1[E1 + i];
        s1[atomicAdd(&cur1[d], 1)] = s;
    } else if (i < E1 + E2) {
        int e = i - E1;
        int d = e2[e], s = e2[E2 + e];
        s2[atomicAdd(&cur2[d], 1)] = s;
    }
}

// ---------------------------------------------------------------------------
// gather for BOTH branches in one dispatch (512 cols, one block per row).
// NO fused stats: 12.6M global atomics cost 170 us/dispatch (round-7 lesson).
// ---------------------------------------------------------------------------
__global__ __launch_bounds__(128) void gather2_bf16(
    const u16x4* __restrict__ Y1, const int* __restrict__ offs1, const int* __restrict__ srcs1,
    u16x4* __restrict__ T1, int n1,
    const u16x4* __restrict__ Y2, const int* __restrict__ offs2, const int* __restrict__ srcs2,
    u16x4* __restrict__ T2,
    const float* __restrict__ epsv, int l)
{
    int i = blockIdx.x;
    const u16x4* Y; u16x4* T; const int *offs, *srcs;
    if (i < n1) { Y = Y1; T = T1; offs = offs1; srcs = srcs1; }
    else        { i -= n1; Y = Y2; T = T2; offs = offs2; srcs = srcs2; }
    int c = threadIdx.x;
    float e = 1.0f + epsv[l];
    int lo = offs[i], hi = offs[i + 1];
    u16x4 hv = Y[(size_t)i * 128 + c];
    f32x4 a0, a1 = {}, a2 = {}, a3 = {};
#pragma unroll
    for (int j = 0; j < 4; ++j) a0[j] = e * bf2f(hv[j]);
    int k = lo;
    for (; k + 4 <= hi; k += 4) {
        int s0 = srcs[k], s1 = srcs[k + 1], s2 = srcs[k + 2], s3 = srcs[k + 3];
        u16x4 v0 = Y[(size_t)s0 * 128 + c];
        u16x4 v1 = Y[(size_t)s1 * 128 + c];
        u16x4 v2 = Y[(size_t)s2 * 128 + c];
        u16x4 v3 = Y[(size_t)s3 * 128 + c];
#pragma unroll
        for (int j = 0; j < 4; ++j) {
            a0[j] += bf2f(v0[j]); a1[j] += bf2f(v1[j]);
            a2[j] += bf2f(v2[j]); a3[j] += bf2f(v3[j]);
        }
    }
    for (; k < hi; ++k) {
        u16x4 v = Y[(size_t)srcs[k] * 128 + c];
#pragma unroll
        for (int j = 0; j < 4; ++j) a0[j] += bf2f(v[j]);
    }
    f32x4 acc = (a0 + a1) + (a2 + a3);
    u16x4 o;
#pragma unroll
    for (int j = 0; j < 4; ++j) o[j] = f2bf(acc[j]);
    T[(size_t)i * 128 + c] = o;
}

// ---------------------------------------------------------------------------
// layer-0 gather on the NARROW inputs (branch1: 128 cols, branch2: 64 cols).
// By linearity A@(X@W1) == (A@X)@W1. One wave per row.
// ---------------------------------------------------------------------------
__global__ __launch_bounds__(64) void gather2_l0(
    const u16x4* __restrict__ X1, const int* __restrict__ offs1, const int* __restrict__ srcs1,
    u16x4* __restrict__ T1, int n1,
    const u16x4* __restrict__ X2, const int* __restrict__ offs2, const int* __restrict__ srcs2,
    u16x4* __restrict__ T2,
    const float* __restrict__ epsv)
{
    int i = blockIdx.x;
    const u16x4* X; u16x4* T; const int *offs, *srcs; int nc4;
    if (i < n1) { X = X1; T = T1; offs = offs1; srcs = srcs1; nc4 = 32; }
    else        { i -= n1; X = X2; T = T2; offs = offs2; srcs = srcs2; nc4 = 16; }
    int c = threadIdx.x;
    if (c >= nc4) return;
    float e = 1.0f + epsv[0];
    int lo = offs[i], hi = offs[i + 1];
    u16x4 hv = X[(size_t)i * nc4 + c];
    f32x4 a0, a1 = {}, a2 = {}, a3 = {};
#pragma unroll
    for (int j = 0; j < 4; ++j) a0[j] = e * bf2f(hv[j]);
    int k = lo;
    for (; k + 4 <= hi; k += 4) {
        int s0 = srcs[k], s1 = srcs[k + 1], s2 = srcs[k + 2], s3 = srcs[k + 3];
        u16x4 v0 = X[(size_t)s0 * nc4 + c];
        u16x4 v1 = X[(size_t)s1 * nc4 + c];
        u16x4 v2 = X[(size_t)s2 * nc4 + c];
        u16x4 v3 = X[(size_t)s3 * nc4 + c];
#pragma unroll
        for (int j = 0; j < 4; ++j) {
            a0[j] += bf2f(v0[j]); a1[j] += bf2f(v1[j]);
            a2[j] += bf2f(v2[j]); a3[j] += bf2f(v3[j]);
        }
    }
    for (; k < hi; ++k) {
        u16x4 v = X[(size_t)srcs[k] * nc4 + c];
#pragma unroll
        for (int j = 0; j < 4; ++j) a0[j] += bf2f(v[j]);
    }
    f32x4 acc = (a0 + a1) + (a2 + a3);
    u16x4 o;
#pragma unroll
    for (int j = 0; j < 4; ++j) o[j] = f2bf(acc[j]);
    T[(size_t)i * nc4 + c] = o;
}

// ---------------------------------------------------------------------------
// dual column sum/sumsq over bf16 [M][512]
// ---------------------------------------------------------------------------
__global__ void bn_stats2(int nb0,
                          const u16x4* __restrict__ X0, float* __restrict__ ss0,
                          const u16x4* __restrict__ X1, float* __restrict__ ss1) {
    int bx = blockIdx.x;
    const u16x4* X; float* ss;
    if (bx < nb0) { X = X0; ss = ss0; }
    else { bx -= nb0; X = X1; ss = ss1; }
    int c = threadIdx.x;
    int r0 = bx * 16;
    f32x4 s = {}, q = {};
    for (int r = 0; r < 16; ++r) {
        u16x4 v = X[(size_t)(r0 + r) * 128 + c];
        f32x4 f;
#pragma unroll
        for (int j = 0; j < 4; ++j) f[j] = bf2f(v[j]);
        s += f; q += f * f;
    }
#pragma unroll
    for (int j = 0; j < 4; ++j) {
        atomicAdd(&ss[c * 4 + j], s[j]);
        atomicAdd(&ss[512 + c * 4 + j], q[j]);
    }
}

// ---------------------------------------------------------------------------
// dual mid BN apply -> U buffers
// ---------------------------------------------------------------------------
__global__ __launch_bounds__(128) void bn_apply_mid(
    int nb0,
    const u16x4* __restrict__ X0, int M0, const float* __restrict__ ss0,
    const float* __restrict__ g0, const float* __restrict__ b0, unsigned short* __restrict__ o0,
    const u16x4* __restrict__ X1, int M1, const float* __restrict__ ss1,
    const float* __restrict__ g1, const float* __restrict__ b1, unsigned short* __restrict__ o1)
{
    int bx = blockIdx.x;
    const u16x4* X; const float *ss, *g, *b; unsigned short* out; int M;
    if (bx < nb0) { X = X0; M = M0; ss = ss0; g = g0; b = b0; out = o0; }
    else { bx -= nb0; X = X1; M = M1; ss = ss1; g = g1; b = b1; out = o1; }
    int c = threadIdx.x;
    float inv = 1.0f / (float)M;
    float al[4], be[4];
#pragma unroll
    for (int i = 0; i < 4; ++i) {
        float mean = ss[c * 4 + i] * inv;
        float var  = ss[512 + c * 4 + i] * inv - mean * mean;
        al[i] = g[c * 4 + i] * rsqrtf(var + 1e-5f);
        be[i] = b[c * 4 + i] - mean * al[i];
    }
    int r0 = bx * 8;
    for (int r = 0; r < 8; ++r) {
        u16x4 v = X[(size_t)(r0 + r) * 128 + c];
        u16x4 h;
#pragma unroll
        for (int i = 0; i < 4; ++i)
            h[i] = f2bf(fmaxf(al[i] * bf2f(v[i]) + be[i], 0.f));
        *reinterpret_cast<u16x4*>(out + (size_t)(r0 + r) * 512 + c * 4) = h;
    }
}

// ---------------------------------------------------------------------------
// branch-2 final BN apply -> H2b [4096][512] AND (optionally) H2t [512][4096]
// ---------------------------------------------------------------------------
__global__ __launch_bounds__(128) void bn_apply_b2t(
    const u16x4* __restrict__ X, int M, const float* __restrict__ ss,
    const float* __restrict__ g, const float* __restrict__ b,
    unsigned short* __restrict__ out, unsigned short* __restrict__ outT)
{
    int c = threadIdx.x;
    float inv = 1.0f / (float)M;
    float al[4], be[4];
#pragma unroll
    for (int i = 0; i < 4; ++i) {
        float mean = ss[c * 4 + i] * inv;
        float var  = ss[512 + c * 4 + i] * inv - mean * mean;
        al[i] = g[c * 4 + i] * rsqrtf(var + 1e-5f);
        be[i] = b[c * 4 + i] - mean * al[i];
    }
    int r0 = blockIdx.x * 8;
    u16x8 t8[4];
#pragma unroll
    for (int r = 0; r < 8; ++r) {
        u16x4 v = X[(size_t)(r0 + r) * 128 + c];
        u16x4 h;
#pragma unroll
        for (int i = 0; i < 4; ++i) {
            h[i] = f2bf(fmaxf(al[i] * bf2f(v[i]) + be[i], 0.f));
            t8[i][r] = h[i];
        }
        *reinterpret_cast<u16x4*>(out + (size_t)(r0 + r) * 512 + c * 4) = h;
    }
    if (outT) {
#pragma unroll
        for (int i = 0; i < 4; ++i)
            *reinterpret_cast<u16x8*>(outT + (size_t)(c * 4 + i) * 4096 + r0) = t8[i];
    }
}

// ---------------------------------------------------------------------------
// finale: job0 (blocks < nb0) = branch-1 final BN apply * a0 -> H1b[:, :512]
//         + JK pool; job1 = sum KS bf16 split-K partials * a1 -> H1b[:, 512:]
//         + JK pool. gid sorted; pool pre-zeroed. (at l=3 only job0 runs)
// ---------------------------------------------------------------------------
__global__ __launch_bounds__(128) void finale(
    int nb0, const int* __restrict__ gid, const float* __restrict__ aDev,
    float* __restrict__ pool, unsigned short* __restrict__ H1,
    const u16x4* __restrict__ X, const float* __restrict__ ss,
    const float* __restrict__ g, const float* __restrict__ b,
    const u16x4* __restrict__ P, int ks)
{
    int bx = blockIdx.x;
    int c = threadIdx.x;
    int job = bx >= nb0;
    if (job) bx -= nb0;
    int r0 = bx * 8;
    int ooff = job ? 512 : 0;
    float al[4], be[4];
    float sc;
    if (!job) {
        sc = aDev[0];
        float inv = 1.0f / 8192.0f;
#pragma unroll
        for (int i = 0; i < 4; ++i) {
            float mean = ss[c * 4 + i] * inv;
            float var  = ss[512 + c * 4 + i] * inv - mean * mean;
            al[i] = g[c * 4 + i] * rsqrtf(var + 1e-5f);
            be[i] = b[c * 4 + i] - mean * al[i];
        }
    } else {
        sc = aDev[1];
    }
    const int total4 = 8192 * 128;
    int curg = gid[r0];
    f32x4 pacc = {};
    for (int r = 0; r < 8; ++r) {
        int row = r0 + r;
        u16x4 h;
        f32x4 f;
        if (!job) {
            u16x4 v = X[(size_t)row * 128 + c];
#pragma unroll
            for (int i = 0; i < 4; ++i) {
                h[i] = f2bf(fmaxf(al[i] * bf2f(v[i]) + be[i], 0.f) * sc);
                f[i] = bf2f(h[i]);
            }
        } else {
            f32x4 s = {};
            for (int z = 0; z < ks; ++z) {
                u16x4 p = P[(size_t)z * total4 + (size_t)row * 128 + c];
#pragma unroll
                for (int i = 0; i < 4; ++i) s[i] += bf2f(p[i]);
            }
#pragma unroll
            for (int i = 0; i < 4; ++i) { h[i] = f2bf(s[i] * sc); f[i] = bf2f(h[i]); }
        }
        *reinterpret_cast<u16x4*>(H1 + (size_t)row * 1024 + ooff + c * 4) = h;
        int gg = gid[row];
        if (gg != curg) {
#pragma unroll
            for (int j = 0; j < 4; ++j)
                atomicAdd(&pool[(size_t)curg * 1024 + ooff + c * 4 + j], pacc[j]);
            pacc = {}; curg = gg;
        }
        pacc += f;
    }
#pragma unroll
    for (int j = 0; j < 4; ++j)
        atomicAdd(&pool[(size_t)curg * 1024 + ooff + c * 4 + j], pacc[j]);
}

// contiguous f32 -> bf16 convert, two tensors in one dispatch
__global__ void cvt2_bf16(const f32x4* __restrict__ X0, u16x4* __restrict__ O0, int n0,
                          const f32x4* __restrict__ X1, u16x4* __restrict__ O1, int n1) {
    for (int i = blockIdx.x * blockDim.x + threadIdx.x; i < n0 + n1; i += gridDim.x * blockDim.x) {
        const f32x4* X; u16x4* O; int k;
        if (i < n0) { X = X0; O = O0; k = i; }
        else { X = X1; O = O1; k = i - n0; }
        f32x4 v = X[k];
        u16x4 h;
#pragma unroll
        for (int j = 0; j < 4; ++j) h[j] = f2bf(v[j]);
        O[k] = h;
    }
}

// ---------------------------------------------------------------------------
// motif transpose: S f32 [4096][8192] -> D bf16 [8192][4096], 64x64 tiles
// ---------------------------------------------------------------------------
__global__ __launch_bounds__(256) void motif_transpose(const float* __restrict__ S,
                                                       unsigned short* __restrict__ D) {
    __shared__ unsigned short tile[64][66];
    int m0 = blockIdx.x * 64;
    int k0 = blockIdx.y * 64;
    int t = threadIdx.x;
    int r = t >> 4, cq = t & 15;
#pragma unroll
    for (int p = 0; p < 4; ++p) {
        int row = r + p * 16;
        f32x4 v = *reinterpret_cast<const f32x4*>(S + (size_t)(k0 + row) * 8192 + m0 + cq * 4);
        u16x4 h;
#pragma unroll
        for (int j = 0; j < 4; ++j) h[j] = f2bf(v[j]);
        *reinterpret_cast<u16x4*>(&tile[row][cq * 4]) = h;
    }
    __syncthreads();
#pragma unroll
    for (int p = 0; p < 4; ++p) {
        int col = r + p * 16;
        u16x4 h;
#pragma unroll
        for (int i = 0; i < 4; ++i) h[i] = tile[cq * 4 + i][col];
        *reinterpret_cast<u16x4*>(D + (size_t)(m0 + col) * 4096 + k0 + cq * 4) = h;
    }
}

// ---------------------------------------------------------------------------
// ALL 16 weight matrices transposed+converted in ONE dispatch.
// z selects the matrix; blocks with y*32 >= rows exit. cols = 512 for all.
// ---------------------------------------------------------------------------
__global__ void transpose_all(
    const float* __restrict__ m1W10, unsigned short* __restrict__ w1t1_0,
    const float* __restrict__ m1W1r, unsigned short* __restrict__ w1t1_r,
    const float* __restrict__ m2W10, unsigned short* __restrict__ w1t2_0,
    const float* __restrict__ m1W2,  unsigned short* __restrict__ w2t1,
    const float* __restrict__ m2W1r, unsigned short* __restrict__ w1t2_r,
    const float* __restrict__ m2W2,  unsigned short* __restrict__ w2t2)
{
    int z = blockIdx.z;
    const float* S; unsigned short* D; int rows;
    if (z == 0)      { S = m1W10; D = w1t1_0; rows = 128; }
    else if (z < 4)  { S = m1W1r + (size_t)(z - 1) * 524288; D = w1t1_r + (size_t)(z - 1) * 524288; rows = 1024; }
    else if (z == 4) { S = m2W10; D = w1t2_0; rows = 64; }
    else if (z < 9)  { S = m1W2  + (size_t)(z - 5) * 262144; D = w2t1   + (size_t)(z - 5) * 262144; rows = 512; }
    else if (z < 12) { S = m2W1r + (size_t)(z - 9) * 262144; D = w1t2_r + (size_t)(z - 9) * 262144; rows = 512; }
    else             { S = m2W2 + (size_t)(z - 12) * 262144; D = w2t2   + (size_t)(z - 12) * 262144; rows = 512; }
    int y0 = blockIdx.y * 32;
    if (y0 >= rows) return;
    __shared__ unsigned short tile[32][33];
    int x0 = blockIdx.x * 32;
    for (int j = threadIdx.y; j < 32; j += blockDim.y)
        tile[j][threadIdx.x] = f2bf(S[(size_t)(y0 + j) * 512 + x0 + threadIdx.x]);
    __syncthreads();
    for (int j = threadIdx.y; j < 32; j += blockDim.y)
        D[(size_t)(x0 + j) * rows + y0 + threadIdx.x] = tile[threadIdx.x][j];
}

// ---------------------------------------------------------------------------
// graph pooling helpers (gid sorted)
// ---------------------------------------------------------------------------
__device__ __forceinline__ int lbound(const int* __restrict__ a, int n, int v) {
    int lo = 0, hi = n;
    while (lo < hi) { int m = (lo + hi) >> 1; if (a[m] < v) lo = m + 1; else hi = m; }
    return lo;
}

__global__ void pool_f32_at(const float* __restrict__ Hm, const int* __restrict__ gid,
                            int n, float* __restrict__ P) {
    int g = blockIdx.x;
    int lo = lbound(gid, n, g), hi = lbound(gid, n, g + 1);
    int cnt = hi - lo;
    int per = (cnt + 3) >> 2;
    int s = lo + blockIdx.y * per;
    int e = min(s + per, hi);
    if (s >= e) return;
    int c = threadIdx.x;
    f32x4 acc = {};
    for (int i = s; i < e; ++i)
        acc += *reinterpret_cast<const f32x4*>(Hm + (size_t)i * 128 + c * 4);
#pragma unroll
    for (int j = 0; j < 4; ++j)
        atomicAdd(&P[(size_t)g * 128 + c * 4 + j], acc[j]);
}

// Pm[g, :] = sum over rows i of graph g of motifT[i, :]   (one-time setup)
__global__ __launch_bounds__(128) void pool_pm(const u16x4* __restrict__ Mt,
                                               const int* __restrict__ gid,
                                               float* __restrict__ Pm) {
    int g = blockIdx.x;
    int lo = lbound(gid, 8192, g), hi = lbound(gid, 8192, g + 1);
    int c = blockIdx.y * 128 + threadIdx.x;
    f32x4 acc = {};
    for (int i = lo; i < hi; ++i) {
        u16x4 v = Mt[(size_t)i * 1024 + c];
#pragma unroll
        for (int j = 0; j < 4; ++j) acc[j] += bf2f(v[j]);
    }
    *reinterpret_cast<f32x4*>(Pm + (size_t)g * 4096 + (size_t)c * 4) = acc;
}

// V[k, o] = a1 * sum_c H2b[k, c] * Wb[c, o]   (tiny: 4096x10, K=512)
__global__ __launch_bounds__(256) void v_kernel(
    const unsigned short* __restrict__ H2, const float* __restrict__ Wb,
    const float* __restrict__ aDev, float* __restrict__ V) {
    int w = threadIdx.x >> 6, l = threadIdx.x & 63;
    int k = blockIdx.x * 4 + w;
    float part[10];
#pragma unroll
    for (int o = 0; o < 10; ++o) part[o] = 0.f;
    for (int c = l; c < 512; c += 64) {
        float v = bf2f(H2[(size_t)k * 512 + c]);
#pragma unroll
        for (int o = 0; o < 10; ++o) part[o] += v * Wb[c * 10 + o];
    }
    float a1 = aDev[1];
#pragma unroll
    for (int o = 0; o < 10; ++o) {
        float v = part[o];
        for (int off = 32; off; off >>= 1) v += __shfl_down(v, off, 64);
        if (l == 0) V[(size_t)k * 10 + o] = a1 * v;
    }
}

__global__ void softmax2(const float* __restrict__ atts, float* __restrict__ a) {
    if (threadIdx.x == 0) {
        float m = fmaxf(atts[0], atts[1]);
        float e0 = expf(atts[0] - m), e1 = expf(atts[1] - m);
        float inv = 1.0f / (e0 + e1);
        a[0] = e0 * inv; a[1] = e1 * inv;
    }
}

// score[g,o] = P0[g]@W0 + b0 + sum_l PL[l][g]@W[l] + b[l] + Pm[g]@V
__global__ __launch_bounds__(256) void score_kernel(
    const float* __restrict__ P0, const float* __restrict__ PL,
    const float* __restrict__ W0, const float* __restrict__ b0,
    const float* __restrict__ W, const float* __restrict__ bb,
    const float* __restrict__ Pm, const float* __restrict__ V,
    float* __restrict__ out)
{
    int g = blockIdx.x;
    int t = threadIdx.x;
    float part[10];
#pragma unroll
    for (int o = 0; o < 10; ++o) part[o] = 0.f;
    if (t < 128) {
        float p = P0[g * 128 + t];
#pragma unroll
        for (int o = 0; o < 10; ++o) part[o] += p * W0[t * 10 + o];
    }
    for (int l = 0; l < 4; ++l) {
        const float* p = PL + (size_t)l * 65536 + (size_t)g * 1024;
        const float* w = W + (size_t)l * 10240;
        for (int k = t; k < 1024; k += 256) {
            float pv = p[k];
#pragma unroll
            for (int o = 0; o < 10; ++o) part[o] += pv * w[k * 10 + o];
        }
    }
    for (int k = t; k < 4096; k += 256) {
        float pv = Pm[(size_t)g * 4096 + k];
#pragma unroll
        for (int o = 0; o < 10; ++o) part[o] += pv * V[(size_t)k * 10 + o];
    }
    __shared__ float red[4][10];
#pragma unroll
    for (int o = 0; o < 10; ++o) {
        float v = part[o];
        for (int off = 32; off; off >>= 1) v += __shfl_down(v, off, 64);
        if ((t & 63) == 0) red[t >> 6][o] = v;
    }
    __syncthreads();
    if (t < 10) {
        float s = b0[t] + red[0][t] + red[1][t] + red[2][t] + red[3][t];
#pragma unroll
        for (int l = 0; l < 4; ++l) s += bb[l * 10 + t];
        out[g * 10 + t] = s;
    }
}

// ---------------------------------------------------------------------------
// host orchestration
// ---------------------------------------------------------------------------
extern "C" void kernel_launch(void* const* d_in, const int* in_sizes, int n_in,
                              void* d_out, int out_size, void* d_ws, size_t ws_size,
                              hipStream_t stream) {
    const float* x1    = (const float*)d_in[0];
    const float* x2    = (const float*)d_in[1];
    const float* motif = (const float*)d_in[2];
    const int*   edge1 = (const int*)d_in[3];
    const int*   edge2 = (const int*)d_in[4];
    const int*   gid   = (const int*)d_in[5];
    const float* epsv  = (const float*)d_in[6];
    const float* atts  = (const float*)d_in[7];
    const float* m1W10 = (const float*)d_in[8];
    const float* m1W1r = (const float*)d_in[9];
    const float* m1bng = (const float*)d_in[11];
    const float* m1bnb = (const float*)d_in[12];
    const float* m1W2  = (const float*)d_in[13];
    const float* bn1g  = (const float*)d_in[15];
    const float* bn1b  = (const float*)d_in[16];
    const float* m2W10 = (const float*)d_in[17];
    const float* m2W1r = (const float*)d_in[18];
    const float* m2bng = (const float*)d_in[20];
    const float* m2bnb = (const float*)d_in[21];
    const float* m2W2  = (const float*)d_in[22];
    const float* bn2g  = (const float*)d_in[24];
    const float* bn2b  = (const float*)d_in[25];
    const float* pW0   = (const float*)d_in[26];
    const float* pb0   = (const float*)d_in[27];
    const float* pW    = (const float*)d_in[28];
    const float* pb    = (const float*)d_in[29];
    float* out = (float*)d_out;

    constexpr int N1 = 8192, N2 = 4096, E1 = 262144, E2 = 65536;

    char* base = (char*)d_ws;
    size_t off = 0;
    auto alloc = [&](size_t bytes) -> void* {
        void* p = base + off;
        off = (off + bytes + 255) & ~(size_t)255;
        return p;
    };

    // bf16 buffers
    unsigned short* motifT  = (unsigned short*)alloc((size_t)8192 * 4096 * 2);
    unsigned short* w1t1_0  = (unsigned short*)alloc((size_t)512 * 128 * 2);
    unsigned short* w1t1_r  = (unsigned short*)alloc((size_t)3 * 512 * 1024 * 2);
    unsigned short* w2t1    = (unsigned short*)alloc((size_t)4 * 512 * 512 * 2);
    unsigned short* w1t2_0  = (unsigned short*)alloc((size_t)512 * 64 * 2);
    unsigned short* w1t2_r  = (unsigned short*)alloc((size_t)3 * 512 * 512 * 2);
    unsigned short* w2t2    = (unsigned short*)alloc((size_t)4 * 512 * 512 * 2);
    unsigned short* x1b     = (unsigned short*)alloc((size_t)N1 * 128 * 2);
    unsigned short* x2b     = (unsigned short*)alloc((size_t)N2 * 64 * 2);
    unsigned short* Tx1     = (unsigned short*)alloc((size_t)N1 * 128 * 2);
    unsigned short* Tx2     = (unsigned short*)alloc((size_t)N2 * 64 * 2);
    unsigned short* H1b     = (unsigned short*)alloc((size_t)N1 * 1024 * 2);
    unsigned short* H2b     = (unsigned short*)alloc((size_t)N2 * 512 * 2);
    unsigned short* H2t     = (unsigned short*)alloc((size_t)512 * 4096 * 2);
    unsigned short* U1b     = (unsigned short*)alloc((size_t)N1 * 512 * 2);
    unsigned short* U2b     = (unsigned short*)alloc((size_t)N2 * 512 * 2);
    unsigned short* Y1b     = (unsigned short*)alloc((size_t)N1 * 512 * 2);
    unsigned short* T1b     = (unsigned short*)alloc((size_t)N1 * 512 * 2);
    unsigned short* Y2b     = (unsigned short*)alloc((size_t)N2 * 512 * 2);
    unsigned short* T2b     = (unsigned short*)alloc((size_t)N2 * 512 * 2);
    // zero-together region: cnt1 | cnt2 | ss | PL | P0
    int*   cnt1 = (int*)alloc((size_t)N1 * 4);
    int*   cnt2 = (int*)alloc((size_t)N2 * 4);
    float* ss   = (float*)alloc((size_t)16 * 1024 * 4);
    float* PL   = (float*)alloc((size_t)4 * 64 * 1024 * 4);
    float* P0   = (float*)alloc((size_t)64 * 128 * 4);
    const size_t zero_bytes = (size_t)N1 * 4 + N2 * 4 + 16 * 1024 * 4 + 4 * 64 * 1024 * 4
                            + 64 * 128 * 4;
    int*   offs1 = (int*)alloc((size_t)(N1 + 1) * 4);
    int*   offs2 = (int*)alloc((size_t)(N2 + 1) * 4);
    int*   cur1  = (int*)alloc((size_t)N1 * 4);
    int*   cur2  = (int*)alloc((size_t)N2 * 4);
    int*   srcs1 = (int*)alloc((size_t)E1 * 4);
    int*   srcs2 = (int*)alloc((size_t)E2 * 4);
    float* Pm    = (float*)alloc((size_t)64 * 4096 * 4);
    float* Vbuf  = (float*)alloc((size_t)4096 * 10 * 4);
    float* aDev  = (float*)alloc(256);

    if (off > ws_size) return;

    // bf16 split-K partials for the fusion GEMM
    const size_t part_bytes = (size_t)N1 * 512 * 2;
    size_t rem = ws_size - off;
    int KS = (rem >= 4 * part_bytes) ? 4 : (rem >= 2 * part_bytes) ? 2 : 1;
    unsigned short* Cpart = (unsigned short*)(base + off);

    // ---- setup ----
    hipMemsetAsync(cnt1, 0, zero_bytes, stream);
    softmax2<<<1, 64, 0, stream>>>(atts, aDev);
    cvt2_bf16<<<512, 256, 0, stream>>>((const f32x4*)x1, (u16x4*)x1b, N1 * 128 / 4,
                                       (const f32x4*)x2, (u16x4*)x2b, N2 * 64 / 4);
    motif_transpose<<<dim3(128, 64), 256, 0, stream>>>(motif, motifT);
    pool_pm<<<dim3(64, 8), 128, 0, stream>>>((const u16x4*)motifT, gid, Pm);
    transpose_all<<<dim3(16, 32, 16), dim3(32, 8), 0, stream>>>(
        m1W10, w1t1_0, m1W1r, w1t1_r, m2W10, w1t2_0, m1W2, w2t1, m2W1r, w1t2_r, m2W2, w2t2);
    csr_count2<<<(E1 + E2) / 256, 256, 0, stream>>>(edge1, E1, cnt1, edge2, E2, cnt2);
    csr_scan2<<<2, 1024, 0, stream>>>(cnt1, N1, offs1, cur1, cnt2, N2, offs2, cur2);
    csr_fill2<<<(E1 + E2) / 256, 256, 0, stream>>>(edge1, E1, cur1, srcs1, edge2, E2, cur2, srcs2);
    pool_f32_at<<<dim3(64, 4), 32, 0, stream>>>(x1, gid, N1, P0);

    // ---- layers ----
    for (int l = 0; l < 4; ++l) {
        float* ssl = ss + (size_t)l * 4096;   // [0]=b1 gather, [1]=b1 W2, [2]=b2 gather, [3]=b2 W2
        float* PLl = PL + (size_t)l * 65536;
        if (l == 0) {
            gather2_l0<<<N1 + N2, 64, 0, stream>>>(
                (const u16x4*)x1b, offs1, srcs1, (u16x4*)Tx1, N1,
                (const u16x4*)x2b, offs2, srcs2, (u16x4*)Tx2, epsv);
            gemm_dual<<<dim3(192, 4), 256, 0, stream>>>(
                128,
                Tx1, w1t1_0, 128, T1b, ssl + 0 * 1024,
                Tx2, w1t2_0, 64,  T2b, ssl + 2 * 1024);
        } else {
            gemm_dual<<<dim3(192, 4), 256, 0, stream>>>(
                128,
                H1b, w1t1_r + (size_t)(l - 1) * 512 * 1024, 1024, Y1b, nullptr,
                H2b, w1t2_r + (size_t)(l - 1) * 512 * 512,  512,  Y2b, nullptr);
            gather2_bf16<<<N1 + N2, 128, 0, stream>>>(
                (const u16x4*)Y1b, offs1, srcs1, (u16x4*)T1b, N1,
                (const u16x4*)Y2b, offs2, srcs2, (u16x4*)T2b, epsv, l);
            bn_stats2<<<768, 128, 0, stream>>>(512, (const u16x4*)T1b, ssl + 0 * 1024,
                                               (const u16x4*)T2b, ssl + 2 * 1024);
        }
        bn_apply_mid<<<1536, 128, 0, stream>>>(
            1024,
            (const u16x4*)T1b, N1, ssl + 0 * 1024, m1bng + l * 512, m1bnb + l * 512, U1b,
            (const u16x4*)T2b, N2, ssl + 2 * 1024, m2bng + l * 512, m2bnb + l * 512, U2b);
        gemm_dual<<<dim3(192, 4), 256, 0, stream>>>(
            128,
            U1b, w2t1 + (size_t)l * 512 * 512, 512, Y1b, ssl + 1 * 1024,
            U2b, w2t2 + (size_t)l * 512 * 512, 512, Y2b, ssl + 3 * 1024);
        if (l < 3) {
            bn_apply_b2t<<<512, 128, 0, stream>>>(
                (const u16x4*)Y2b, N2, ssl + 3 * 1024, bn2g + l * 512, bn2b + l * 512, H2b, H2t);
            gemm_splitk<<<dim3(64, 4, KS), 256, 0, stream>>>(motifT, H2t, N1, 512, 4096, Cpart);
            finale<<<2048, 128, 0, stream>>>(
                1024, gid, aDev, PLl, H1b,
                (const u16x4*)Y1b, ssl + 1 * 1024, bn1g + l * 512, bn1b + l * 512,
                (const u16x4*)Cpart, KS);
        } else {
            bn_apply_b2t<<<512, 128, 0, stream>>>(
                (const u16x4*)Y2b, N2, ssl + 3 * 1024, bn2g + l * 512, bn2b + l * 512,
                H2b, nullptr);
            v_kernel<<<1024, 256, 0, stream>>>(H2b, pW + 3 * 10240 + 512 * 10, aDev, Vbuf);
            finale<<<1024, 128, 0, stream>>>(
                1024, gid, aDev, PLl, H1b,
                (const u16x4*)Y1b, ssl + 1 * 1024, bn1g + l * 512, bn1b + l * 512,
                (const u16x4*)Cpart, KS);
        }
    }

    score_kernel<<<64, 256, 0, stream>>>(P0, PL, pW0, pb0, pW, pb, Pm, Vbuf, out);
}